// Round 13
// baseline (295.482 us; speedup 1.0000x reference)
//
#include <hip/hip_runtime.h>
#include <hip/hip_bf16.h>

#define B_SZ 4096
#define NHID_ 2048

typedef __bf16 bf16x8 __attribute__((ext_vector_type(8)));
typedef float f32x4 __attribute__((ext_vector_type(4)));

__device__ __forceinline__ float sigmoidf_(float x) { return 1.f / (1.f + expf(-x)); }

#define GLDS16(gp, lp) __builtin_amdgcn_global_load_lds( \
    (const __attribute__((address_space(1))) void*)(gp), \
    (__attribute__((address_space(3))) void*)(lp), 16, 0, 0)

// ---------------------------------------------------------------------------
// Merged prep: [0,6144) wih_prep | [6144,10240) f2b3 | [10240,11264) fcT tconv
// | [11264,11648) WmT tconv | [11648,11776) fcg_prep.
// ---------------------------------------------------------------------------
__global__ __launch_bounds__(256) void prep_all(
    const float* __restrict__ Wih, const float* __restrict__ fc_i_b,
    const float* __restrict__ bih, __hip_bfloat16* __restrict__ Wihb,
    float* __restrict__ cb,
    const float* __restrict__ inp, __hip_bfloat16* __restrict__ inpb,
    const float* __restrict__ Whh, __hip_bfloat16* __restrict__ Whhb,
    const float* __restrict__ WvBsrc, __hip_bfloat16* __restrict__ WvB,
    const float* __restrict__ fc_i_w, __hip_bfloat16* __restrict__ fcT,
    const float* __restrict__ Wq_m, const float* __restrict__ Wk_m,
    const float* __restrict__ Wv_m, __hip_bfloat16* __restrict__ WmT,
    const float* __restrict__ fc_m_w, const float* __restrict__ gate_m_w,
    __hip_bfloat16* __restrict__ fcgT)
{
    __shared__ float smem[32 * 33];
    const int bid = blockIdx.x;
    const int tid = threadIdx.x;

    if (bid < 6144) {
        // ---- wih_prep ----
        long j = bid;
        const float* row = Wih + j * 1024;
        __hip_bfloat16* drow = Wihb + j * 1024;
        int i = tid * 4;
        float4 v = *(const float4*)(row + i);
        __hip_bfloat16 b0 = __float2bfloat16(v.x);
        __hip_bfloat16 b1 = __float2bfloat16(v.y);
        __hip_bfloat16 b2 = __float2bfloat16(v.z);
        __hip_bfloat16 b3 = __float2bfloat16(v.w);
        ushort4 u;
        u.x = *(unsigned short*)&b0; u.y = *(unsigned short*)&b1;
        u.z = *(unsigned short*)&b2; u.w = *(unsigned short*)&b3;
        *(ushort4*)(drow + i) = u;
        float s = fc_i_b[i] * v.x + fc_i_b[i + 1] * v.y +
                  fc_i_b[i + 2] * v.z + fc_i_b[i + 3] * v.w;
#pragma unroll
        for (int off = 32; off > 0; off >>= 1) s += __shfl_xor(s, off, 64);
        if ((tid & 63) == 0) smem[tid >> 6] = s;
        __syncthreads();
        if (tid == 0) cb[j] = smem[0] + smem[1] + smem[2] + smem[3] + bih[j];
    } else if (bid < 10240) {
        // ---- f2b3: inp | Whh | WvB ----
        long i = (long)(bid - 6144) * 256 + tid;   // [0, 1048576)
        const float* src; __hip_bfloat16* dst; long off;
        if (i < 524288)       { src = inp;    dst = inpb; off = i; }
        else if (i < 917504)  { src = Whh;    dst = Whhb; off = i - 524288; }
        else                  { src = WvBsrc; dst = WvB;  off = i - 917504; }
        float4 v = ((const float4*)src)[off];
        __hip_bfloat16 b0 = __float2bfloat16(v.x);
        __hip_bfloat16 b1 = __float2bfloat16(v.y);
        __hip_bfloat16 b2 = __float2bfloat16(v.z);
        __hip_bfloat16 b3 = __float2bfloat16(v.w);
        ushort4 u;
        u.x = *(unsigned short*)&b0; u.y = *(unsigned short*)&b1;
        u.z = *(unsigned short*)&b2; u.w = *(unsigned short*)&b3;
        ((ushort4*)dst)[off] = u;
    } else if (bid < 11264) {
        // ---- tconv fc_i_w (1024x1024) -> fcT ----
        int lb = bid - 10240;                 // [0,1024)
        int r0 = (lb >> 5) * 32, c0 = (lb & 31) * 32;
        int tx = tid & 31, ty = tid >> 5;
        float (*tile)[33] = (float(*)[33])smem;
#pragma unroll
        for (int i = 0; i < 4; ++i)
            tile[ty + i * 8][tx] = fc_i_w[(long)(r0 + ty + i * 8) * 1024 + c0 + tx];
        __syncthreads();
#pragma unroll
        for (int i = 0; i < 4; ++i)
            fcT[(long)(c0 + ty + i * 8) * 1024 + r0 + tx] =
                __float2bfloat16(tile[tx][ty + i * 8]);
    } else if (bid < 11648) {
        // ---- tconv_wm: z in [0,24) ----
        int lb = bid - 11264;                 // [0,384)
        int z = lb >> 4, rem = lb & 15;
        int by = rem >> 1, bx = rem & 1;
        int which = z >> 3, nb = z & 7;
        const float* src = (which == 0) ? Wq_m : (which == 1) ? Wk_m : Wv_m;
        src += (long)nb * 16384;
        __hip_bfloat16* dst = WmT + (long)nb * 49152 + which * 64 * 256;
        int r0 = by * 32, c0 = bx * 32;
        int tx = tid & 31, ty = tid >> 5;
        float (*tile)[33] = (float(*)[33])smem;
#pragma unroll
        for (int i = 0; i < 4; ++i)
            tile[ty + i * 8][tx] = src[(long)(r0 + ty + i * 8) * 64 + c0 + tx];
        __syncthreads();
#pragma unroll
        for (int i = 0; i < 4; ++i)
            dst[(long)(c0 + ty + i * 8) * 256 + r0 + tx] =
                __float2bfloat16(tile[tx][ty + i * 8]);
    } else {
        // ---- fcg_prep ----
        int t = (bid - 11648) * 256 + tid;    // [0,32768)
        int np = t >> 6, k = t & 63;
        int o = (np >> 5) * 16 + (np & 15);
        const float* src = ((np >> 4) & 1) ? gate_m_w : fc_m_w;
        fcgT[t] = __float2bfloat16(src[k * 256 + o]);
    }
}

// ---------------------------------------------------------------------------
// Generic fp32 tiled GEMM (krow only)
// ---------------------------------------------------------------------------
#define GM_BM 64
#define GM_BN 64
#define GM_BK 16

__global__ __launch_bounds__(256) void gemm_nn(
    const float* __restrict__ A, const float* __restrict__ Bm, float* __restrict__ C,
    int M, int N, int K, int lda, int ldb, int ldc,
    long sA, long sB, long sC)
{
    const int z = blockIdx.z;
    A += (long)z * sA; Bm += (long)z * sB; C += (long)z * sC;
    const int m0 = blockIdx.y * GM_BM;
    const int n0 = blockIdx.x * GM_BN;
    const int tid = threadIdx.x;
    const int tx = tid & 15;
    const int ty = tid >> 4;

    __shared__ float As[GM_BK][GM_BM + 4];
    __shared__ float Bs[GM_BK][GM_BN + 4];

    float acc[4][4] = {};

    for (int k0 = 0; k0 < K; k0 += GM_BK) {
#pragma unroll
        for (int i = 0; i < 4; ++i) {
            int idx = tid + i * 256;
            int r = idx >> 4, c = idx & 15;
            As[c][r] = A[(long)(m0 + r) * lda + k0 + c];
        }
#pragma unroll
        for (int i = 0; i < 4; ++i) {
            int idx = tid + i * 256;
            int r = idx >> 6, c = idx & 63;
            Bs[r][c] = Bm[(long)(k0 + r) * ldb + n0 + c];
        }
        __syncthreads();
#pragma unroll
        for (int kk = 0; kk < GM_BK; ++kk) {
            float4 a4 = *(const float4*)&As[kk][ty * 4];
            float4 b4 = *(const float4*)&Bs[kk][tx * 4];
            float av[4] = {a4.x, a4.y, a4.z, a4.w};
            float bv[4] = {b4.x, b4.y, b4.z, b4.w};
#pragma unroll
            for (int i = 0; i < 4; ++i)
#pragma unroll
                for (int j = 0; j < 4; ++j)
                    acc[i][j] += av[i] * bv[j];
        }
        __syncthreads();
    }
#pragma unroll
    for (int i = 0; i < 4; ++i) {
        long m = m0 + ty * 4 + i;
#pragma unroll
        for (int j = 0; j < 4; ++j) {
            int n = n0 + tx * 4 + j;
            C[m * ldc + n] = acc[i][j];
        }
    }
}

// ---------------------------------------------------------------------------
// fp32 GEMM with N-major B: C(MxN) = A(MxK) @ BT(NxK)^T, batched z over BT/C.
// ---------------------------------------------------------------------------
__global__ __launch_bounds__(256) void gemm_nt_f32(
    const float* __restrict__ A, int lda,
    const float* __restrict__ BT, int ldb,
    float* __restrict__ C, int ldc, int K, long sB, long sC)
{
    BT += (long)blockIdx.z * sB;
    C  += (long)blockIdx.z * sC;
    const int m0 = blockIdx.y * 64;
    const int n0 = blockIdx.x * 64;
    const int tid = threadIdx.x;
    const int tx = tid & 15;
    const int ty = tid >> 4;

    __shared__ float As[16][68];
    __shared__ float Bs[64][17];

    float acc[4][4] = {};

    for (int k0 = 0; k0 < K; k0 += 16) {
#pragma unroll
        for (int i = 0; i < 4; ++i) {
            int idx = tid + i * 256;
            int r = idx >> 4, c = idx & 15;
            As[c][r] = A[(long)(m0 + r) * lda + k0 + c];
        }
#pragma unroll
        for (int i = 0; i < 4; ++i) {
            int idx = tid + i * 256;
            int r = idx >> 4, c = idx & 15;
            Bs[r][c] = BT[(long)(n0 + r) * ldb + k0 + c];
        }
        __syncthreads();
#pragma unroll
        for (int kk = 0; kk < 16; ++kk) {
            float4 a4 = *(const float4*)&As[kk][ty * 4];
            float av[4] = {a4.x, a4.y, a4.z, a4.w};
            float bv[4];
#pragma unroll
            for (int j = 0; j < 4; ++j) bv[j] = Bs[tx * 4 + j][kk];
#pragma unroll
            for (int i = 0; i < 4; ++i)
#pragma unroll
                for (int j = 0; j < 4; ++j)
                    acc[i][j] += av[i] * bv[j];
        }
        __syncthreads();
    }
#pragma unroll
    for (int i = 0; i < 4; ++i) {
        long m = m0 + ty * 4 + i;
#pragma unroll
        for (int j = 0; j < 4; ++j) {
            int n = n0 + tx * 4 + j;
            C[m * ldc + n] = acc[i][j];
        }
    }
}

// ---------------------------------------------------------------------------
// Fused s1 / sigmoid / top-k mask + hx->bf16 emit.
// ---------------------------------------------------------------------------
__global__ __launch_bounds__(256) void s1_mask_fused(
    const float* __restrict__ hx,   // (B,2048)
    const float* __restrict__ p,    // (B,2048)  p[b, n*256+i]
    float* __restrict__ a_buf, float* __restrict__ mask_buf,
    __hip_bfloat16* __restrict__ hxb)   // (B,2048) bf16 out
{
    const int wave = threadIdx.x >> 6;
    const int lane = threadIdx.x & 63;
    const long b = (long)blockIdx.x * 4 + wave;
    const long base = b * 2048 + lane * 4;
    float s1v[8];
#pragma unroll
    for (int n = 0; n < 8; ++n) {
        float4 hv = *(const float4*)(hx + base + n * 256);
        float4 pv = *(const float4*)(p + base + n * 256);
        __hip_bfloat16 c0 = __float2bfloat16(hv.x);
        __hip_bfloat16 c1 = __float2bfloat16(hv.y);
        __hip_bfloat16 c2 = __float2bfloat16(hv.z);
        __hip_bfloat16 c3 = __float2bfloat16(hv.w);
        ushort4 u;
        u.x = *(unsigned short*)&c0; u.y = *(unsigned short*)&c1;
        u.z = *(unsigned short*)&c2; u.w = *(unsigned short*)&c3;
        *(ushort4*)(hxb + base + n * 256) = u;
        float s = hv.x * pv.x + hv.y * pv.y + hv.z * pv.z + hv.w * pv.w;
#pragma unroll
        for (int off = 32; off > 0; off >>= 1) s += __shfl_xor(s, off, 64);
        s1v[n] = s * 0.125f;
    }
    unsigned maskbits = 0;
#pragma unroll
    for (int n = 0; n < 8; ++n) {
        int rank = 0;
#pragma unroll
        for (int m = 0; m < 8; ++m) {
            if (m == n) continue;
            if (s1v[m] < s1v[n] || (s1v[m] == s1v[n] && m < n)) rank++;
        }
        if (rank >= 4) maskbits |= (1u << n);
    }
    if (lane < 8) {
        float sv = s1v[0];
#pragma unroll
        for (int n = 1; n < 8; ++n)
            if (lane == n) sv = s1v[n];
        a_buf[b * 8 + lane] = sigmoidf_(sv);
        mask_buf[b * 8 + lane] = ((maskbits >> lane) & 1u) ? 1.0f : 0.0f;
    }
}

// ---------------------------------------------------------------------------
// MFMA GEMM: C(bf16, MxN) = A(bf16, MxK, lda) @ BT(bf16, NxK, ldb)^T
// ---------------------------------------------------------------------------
__global__ __launch_bounds__(256) void gemm_mfma_obf16(
    const __hip_bfloat16* __restrict__ A, int lda,
    const __hip_bfloat16* __restrict__ BT, int ldb,
    __hip_bfloat16* __restrict__ C, int ldc, int K)
{
    const int m0 = blockIdx.y * 128;
    const int n0 = blockIdx.x * 64;
    const int tid = threadIdx.x;
    const int lane = tid & 63, wid = tid >> 6;
    const int wr = wid >> 1, wc = wid & 1;
    const int l15 = lane & 15, l4 = lane >> 4;

    __shared__ __align__(16) char lds_raw[16384 + 8192];
    char* Alds = lds_raw;
    char* Blds = lds_raw + 16384;

    f32x4 acc[4][2] = {};

    for (int k0 = 0; k0 < K; k0 += 64) {
#pragma unroll
        for (int ii = 0; ii < 4; ++ii) {
            int issue = ii * 4 + wid;
            int chunk = issue * 64 + lane;
            int r = chunk >> 3, cs = chunk & 7;
            int cl = cs ^ (r & 7);
            const __hip_bfloat16* g = A + (long)(m0 + r) * lda + k0 + cl * 8;
            GLDS16(g, Alds + issue * 1024);
        }
#pragma unroll
        for (int jj = 0; jj < 2; ++jj) {
            int issue = jj * 4 + wid;
            int chunk = issue * 64 + lane;
            int r = chunk >> 3, cs = chunk & 7;
            int cl = cs ^ (r & 7);
            const __hip_bfloat16* g = BT + (long)(n0 + r) * ldb + k0 + cl * 8;
            GLDS16(g, Blds + issue * 1024);
        }
        __syncthreads();
#pragma unroll
        for (int kk = 0; kk < 2; ++kk) {
            bf16x8 af[4], bfr[2];
#pragma unroll
            for (int im = 0; im < 4; ++im) {
                int r = wr * 64 + im * 16 + l15;
                int cl = (kk * 4 + l4) ^ (l15 & 7);
                af[im] = *(const bf16x8*)(Alds + r * 128 + cl * 16);
            }
#pragma unroll
            for (int jn = 0; jn < 2; ++jn) {
                int r = wc * 32 + jn * 16 + l15;
                int cl = (kk * 4 + l4) ^ (l15 & 7);
                bfr[jn] = *(const bf16x8*)(Blds + r * 128 + cl * 16);
            }
#pragma unroll
            for (int im = 0; im < 4; ++im)
#pragma unroll
                for (int jn = 0; jn < 2; ++jn)
                    acc[im][jn] = __builtin_amdgcn_mfma_f32_16x16x32_bf16(
                        af[im], bfr[jn], acc[im][jn], 0, 0, 0);
        }
        __syncthreads();
    }
#pragma unroll
    for (int im = 0; im < 4; ++im)
#pragma unroll
        for (int reg = 0; reg < 4; ++reg) {
            long m = m0 + wr * 64 + im * 16 + l4 * 4 + reg;
#pragma unroll
            for (int jn = 0; jn < 2; ++jn) {
                int n = n0 + wc * 32 + jn * 16 + l15;
                C[m * ldc + n] = __float2bfloat16(acc[im][jn][reg]);
            }
        }
}

// ---------------------------------------------------------------------------
// Fused q/k/v_m projections (bf16 out).
// ---------------------------------------------------------------------------
__global__ __launch_bounds__(256) void gemm_mfma_qkv(
    const __hip_bfloat16* __restrict__ hnewb,  // (B,2048)
    const __hip_bfloat16* __restrict__ WmT,    // (8,192,256)
    __hip_bfloat16* __restrict__ qout)         // q|k|v, each 2097152 bf16
{
    const int z = blockIdx.z;
    const int m0 = blockIdx.y * 128;
    const int n0 = blockIdx.x * 64;
    const int tid = threadIdx.x;
    const int lane = tid & 63, wid = tid >> 6;
    const int wr = wid >> 1, wc = wid & 1;
    const int l15 = lane & 15, l4 = lane >> 4;

    const __hip_bfloat16* A = hnewb + z * 256;
    const __hip_bfloat16* BT = WmT + (long)z * 192 * 256;

    __shared__ __align__(16) char lds_raw[16384 + 8192];
    char* Alds = lds_raw;
    char* Blds = lds_raw + 16384;

    f32x4 acc[4][2] = {};

    for (int k0 = 0; k0 < 256; k0 += 64) {
#pragma unroll
        for (int ii = 0; ii < 4; ++ii) {
            int issue = ii * 4 + wid;
            int chunk = issue * 64 + lane;
            int r = chunk >> 3, cs = chunk & 7;
            int cl = cs ^ (r & 7);
            const __hip_bfloat16* g = A + (long)(m0 + r) * 2048 + k0 + cl * 8;
            GLDS16(g, Alds + issue * 1024);
        }
#pragma unroll
        for (int jj = 0; jj < 2; ++jj) {
            int issue = jj * 4 + wid;
            int chunk = issue * 64 + lane;
            int r = chunk >> 3, cs = chunk & 7;
            int cl = cs ^ (r & 7);
            const __hip_bfloat16* g = BT + (long)(n0 + r) * 256 + k0 + cl * 8;
            GLDS16(g, Blds + issue * 1024);
        }
        __syncthreads();
#pragma unroll
        for (int kk = 0; kk < 2; ++kk) {
            bf16x8 af[4], bfr[2];
#pragma unroll
            for (int im = 0; im < 4; ++im) {
                int r = wr * 64 + im * 16 + l15;
                int cl = (kk * 4 + l4) ^ (l15 & 7);
                af[im] = *(const bf16x8*)(Alds + r * 128 + cl * 16);
            }
#pragma unroll
            for (int jn = 0; jn < 2; ++jn) {
                int r = wc * 32 + jn * 16 + l15;
                int cl = (kk * 4 + l4) ^ (l15 & 7);
                bfr[jn] = *(const bf16x8*)(Blds + r * 128 + cl * 16);
            }
#pragma unroll
            for (int im = 0; im < 4; ++im)
#pragma unroll
                for (int jn = 0; jn < 2; ++jn)
                    acc[im][jn] = __builtin_amdgcn_mfma_f32_16x16x32_bf16(
                        af[im], bfr[jn], acc[im][jn], 0, 0, 0);
        }
        __syncthreads();
    }
#pragma unroll
    for (int jn = 0; jn < 2; ++jn) {
        int j = n0 + wc * 32 + jn * 16 + l15;   // [0,192)
        int g = j >> 6, d = j & 63;
        __hip_bfloat16* outp = qout + (long)g * 2097152 + (long)z * 64 + d;
#pragma unroll
        for (int im = 0; im < 4; ++im)
#pragma unroll
            for (int reg = 0; reg < 4; ++reg) {
                long m = m0 + wr * 64 + im * 16 + l4 * 4 + reg;
                outp[m * 512] = __float2bfloat16(acc[im][jn][reg]);
            }
    }
}

// ---------------------------------------------------------------------------
// MFMA big GEMM + fused GRU epilogue — counted-vmcnt pipeline (T4):
// 2 LDS buffers, 2 tiles in flight; raw s_barrier (no implicit drain);
// wait vmcnt(Nw) = this wave's loads-per-stage so the newest stage stays in
// flight across the barrier; vmcnt(0) only on the last iteration.
// 512 thr / 8 waves, wave 32m x 48n, XCD-pinned kblk = bid&7.
// ---------------------------------------------------------------------------
__global__ __launch_bounds__(512) void gru_fused_mfma(
    const __hip_bfloat16* __restrict__ wfcb,   // (B,1024)
    const __hip_bfloat16* __restrict__ hxb,    // (B,2048)
    const float* __restrict__ a_buf,           // (B,8)
    const float* __restrict__ cb,              // (8,768)
    const __hip_bfloat16* __restrict__ Wihb,   // (8,768,1024)
    const __hip_bfloat16* __restrict__ Whhb,   // (8,768,256)
    const float* __restrict__ bhh,             // (8,768)
    __hip_bfloat16* __restrict__ hnewb)        // (B,2048)
{
    const int bid = blockIdx.x;
    const int kblk = bid & 7;
    const int r_ = bid >> 3;
    const int ol0 = (r_ & 7) * 32;
    const int m0 = (r_ >> 3) * 128;
    const int tid = threadIdx.x;
    const int lane = tid & 63, wid = tid >> 6;
    const int wr = wid >> 1;
    const int wc = wid & 1;
    const int l15 = lane & 15, l4 = lane >> 4;

    __shared__ __align__(16) char lds_raw[2 * 28672];

    f32x4 accx[2][3] = {};
    f32x4 acch[2][3] = {};

    const __hip_bfloat16* Wk = Wihb + (long)kblk * 768 * 1024;
    const __hip_bfloat16* Wh = Whhb + (long)kblk * 768 * 256;
    const __hip_bfloat16* hxk = hxb + kblk * 256;

    const int iiA0 = wid, iiA1 = wid + 8;
    const int cA0 = iiA0 * 64 + lane, rA0 = cA0 >> 3, clA0 = (cA0 & 7) ^ (rA0 & 7);
    const int cA1 = iiA1 * 64 + lane, rA1 = cA1 >> 3, clA1 = (cA1 & 7) ^ (rA1 & 7);
    const int jjB0 = wid, jjB1 = wid + 8;
    const int cB0 = jjB0 * 64 + lane, rB0 = cB0 >> 3, clB0 = (cB0 & 7) ^ (rB0 & 7);
    const int cB1 = jjB1 * 64 + lane, rB1 = cB1 >> 3, clB1 = (cB1 & 7) ^ (rB1 & 7);
    const bool hasB1 = (wid < 4);
    const int gg0 = rB0 >> 5, oll0 = rB0 & 31;
    const int gg1 = (rB1 >> 5) & 3, oll1 = rB1 & 31;
    const int dA0 = iiA0 * 1024, dA1 = iiA1 * 1024;
    const int dB0 = 16384 + jjB0 * 1024, dB1 = 16384 + jjB1 * 1024;

    const __hip_bfloat16* pA0 = wfcb + (long)(m0 + rA0) * 1024 + clA0 * 8;
    const __hip_bfloat16* pA1 = wfcb + (long)(m0 + rA1) * 1024 + clA1 * 8;
    const __hip_bfloat16* pB0 = Wk + (long)(gg0 * 256 + ol0 + oll0) * 1024 + clB0 * 8;
    const __hip_bfloat16* pB1 = Wk + (long)(gg1 * 256 + ol0 + oll1) * 1024 + clB1 * 8;

#define STAGE4(buf) do {                                                       \
    char* L = lds_raw + (buf) * 28672;                                         \
    GLDS16(pA0, L + dA0);                                                      \
    GLDS16(pA1, L + dA1);                                                      \
    GLDS16(pB0, L + dB0);                                                      \
    if (hasB1) GLDS16(pB1, L + dB1);                                           \
    pA0 += 64; pA1 += 64; pB0 += 64; pB1 += 64;                                \
} while (0)

    int offA[2][2], offB[2][3];
#pragma unroll
    for (int kk = 0; kk < 2; ++kk) {
        int cl = (kk * 4 + l4) ^ (l15 & 7);
#pragma unroll
        for (int im = 0; im < 2; ++im)
            offA[kk][im] = (wr * 32 + im * 16 + l15) * 128 + cl * 16;
#pragma unroll
        for (int g = 0; g < 3; ++g)
            offB[kk][g] = 16384 + (g * 32 + wc * 16 + l15) * 128 + cl * 16;
    }

#define COMPUTE(acc, buf) do {                                                 \
    char* L = lds_raw + (buf) * 28672;                                         \
    _Pragma("unroll") for (int kk = 0; kk < 2; ++kk) {                         \
        bf16x8 af[2], bfr[3];                                                  \
        _Pragma("unroll") for (int im = 0; im < 2; ++im)                       \
            af[im] = *(const bf16x8*)(L + offA[kk][im]);                       \
        _Pragma("unroll") for (int g = 0; g < 3; ++g)                          \
            bfr[g] = *(const bf16x8*)(L + offB[kk][g]);                        \
        _Pragma("unroll") for (int im = 0; im < 2; ++im)                       \
            _Pragma("unroll") for (int g = 0; g < 3; ++g)                      \
                acc[im][g] = __builtin_amdgcn_mfma_f32_16x16x32_bf16(          \
                    af[im], bfr[g], acc[im][g], 0, 0, 0);                      \
    }                                                                          \
} while (0)

    // Prologue: stage tiles 0 and 1 (2 tiles in flight)
    STAGE4(0);
    STAGE4(1);

    int cur = 0;
    for (int t = 0; t < 20; ++t) {
        // Wait for the OLDEST in-flight stage (tile t); the newest stays in flight.
        if (t == 19)      asm volatile("s_waitcnt vmcnt(0)" ::: "memory");
        else if (hasB1)   asm volatile("s_waitcnt vmcnt(4)" ::: "memory");
        else              asm volatile("s_waitcnt vmcnt(3)" ::: "memory");
        __builtin_amdgcn_s_barrier();          // all waves' tile-t data in LDS
        __builtin_amdgcn_sched_barrier(0);
        __builtin_amdgcn_s_setprio(1);
        if (t < 16) COMPUTE(accx, cur);
        else        COMPUTE(acch, cur);
        __builtin_amdgcn_s_setprio(0);
        __builtin_amdgcn_sched_barrier(0);
        __builtin_amdgcn_s_barrier();          // all waves done reading buf[cur]
        if (t < 18) {
            if (t == 14) {                     // tile 16 = phase 2 start
                pA0 = hxk + (long)(m0 + rA0) * 2048 + clA0 * 8;
                pA1 = hxk + (long)(m0 + rA1) * 2048 + clA1 * 8;
                pB0 = Wh + (long)(gg0 * 256 + ol0 + oll0) * 256 + clB0 * 8;
                pB1 = Wh + (long)(gg1 * 256 + ol0 + oll1) * 256 + clB1 * 8;
            }
            STAGE4(cur);                       // tile t+2 into the buffer just freed
        }
        cur ^= 1;
    }
#undef STAGE4
#undef COMPUTE

    const int ol = ol0 + wc * 16 + l15;
    const float* cbk = cb + kblk * 768;
    const float cb0 = cbk[ol], cb1 = cbk[256 + ol], cb2 = cbk[512 + ol];
    const float* bhk = bhh + kblk * 768;
    const float bh0 = bhk[ol], bh1 = bhk[256 + ol], bh2 = bhk[512 + ol];
#pragma unroll
    for (int im = 0; im < 2; ++im) {
#pragma unroll
        for (int reg = 0; reg < 4; ++reg) {
            long m = m0 + wr * 32 + im * 16 + l4 * 4 + reg;
            float av = a_buf[m * 8 + kblk];
            float gx0 = av * accx[im][0][reg] + cb0;
            float gx1 = av * accx[im][1][reg] + cb1;
            float gx2 = av * accx[im][2][reg] + cb2;
            float gh0 = acch[im][0][reg] + bh0;
            float gh1 = acch[im][1][reg] + bh1;
            float gh2 = acch[im][2][reg] + bh2;
            float rr = sigmoidf_(gx0 + gh0);
            float zz = sigmoidf_(gx1 + gh1);
            float nn = tanhf(gx2 + rr * gh2);
            long idx = m * 2048 + kblk * 256 + ol;
            float hxv = __bfloat162float(hxb[idx]);
            hnewb[idx] = __float2bfloat16((1.f - zz) * nn + zz * hxv);
        }
    }
}

// ---------------------------------------------------------------------------
// Memory attention (bf16 in/out)
// ---------------------------------------------------------------------------
__global__ __launch_bounds__(256) void mattn_kernel(
    const __hip_bfloat16* __restrict__ qm, const __hip_bfloat16* __restrict__ km,
    const __hip_bfloat16* __restrict__ vm, __hip_bfloat16* __restrict__ omb)
{
    const int t = threadIdx.x;
    const int local = t & 31;
    const long b = (long)blockIdx.x * 8 + (t >> 5);
    const int h = local >> 3, qn = local & 7;
    const long base = b * 512 + h * 16;

    float qv[16];
#pragma unroll
    for (int i = 0; i < 2; ++i) {
        bf16x8 v = *(const bf16x8*)(qm + base + qn * 64 + i * 8);
#pragma unroll
        for (int j = 0; j < 8; ++j) qv[i * 8 + j] = (float)v[j];
    }
    float sc[8];
#pragma unroll
    for (int kn = 0; kn < 8; ++kn) {
        float s = 0.f;
#pragma unroll
        for (int i = 0; i < 2; ++i) {
            bf16x8 v = *(const bf16x8*)(km + base + kn * 64 + i * 8);
#pragma unroll
            for (int j = 0; j < 8; ++j) s += qv[i * 8 + j] * (float)v[j];
        }
        sc[kn] = s * 0.25f;
    }
    float mx = sc[0];
#pragma unroll
    for (int kn = 1; kn < 8; ++kn) mx = fmaxf(mx, sc[kn]);
    float ssum = 0.f;
#pragma unroll
    for (int kn = 0; kn < 8; ++kn) { sc[kn] = expf(sc[kn] - mx); ssum += sc[kn]; }
    float inv = 1.f / ssum;

    float acc[16] = {};
#pragma unroll
    for (int kn = 0; kn < 8; ++kn) {
        float w = sc[kn] * inv;
#pragma unroll
        for (int i = 0; i < 2; ++i) {
            bf16x8 v = *(const bf16x8*)(vm + base + kn * 64 + i * 8);
#pragma unroll
            for (int j = 0; j < 8; ++j) acc[i * 8 + j] += w * (float)v[j];
        }
    }
#pragma unroll
    for (int i = 0; i < 2; ++i) {
        bf16x8 o;
#pragma unroll
        for (int j = 0; j < 8; ++j) o[j] = (__bf16)acc[i * 8 + j];
        *(bf16x8*)(omb + base + qn * 64 + i * 8) = o;
    }
}

// ---------------------------------------------------------------------------
// Fused att GEMM + final (R12-verified).
// ---------------------------------------------------------------------------
__global__ __launch_bounds__(256) void att_final(
    const __hip_bfloat16* __restrict__ omb,    // (32768,64)
    const __hip_bfloat16* __restrict__ fcgT,   // (512,64)
    const float* __restrict__ fc_b, const float* __restrict__ gate_b,
    const __hip_bfloat16* __restrict__ hnewb,  // (32768,256)
    const float* __restrict__ maskb,           // (32768)
    const float* __restrict__ hx, const float* __restrict__ cx,
    float* __restrict__ hx_out, float* __restrict__ cx_out,
    float* __restrict__ mask_w)
{
    const int m0 = blockIdx.y * 128;
    const int n0 = blockIdx.x * 64;
    const int tid = threadIdx.x;
    const int lane = tid & 63, wid = tid >> 6;
    const int wr = wid >> 1, wc = wid & 1;
    const int l15 = lane & 15, l4 = lane >> 4;

    __shared__ __align__(16) char lds_raw[16384 + 8192];
    char* Alds = lds_raw;
    char* Blds = lds_raw + 16384;

    f32x4 acc[4][2] = {};
#pragma unroll
    for (int ii = 0; ii < 4; ++ii) {
        int issue = ii * 4 + wid;
        int chunk = issue * 64 + lane;
        int r = chunk >> 3, cs = chunk & 7;
        int cl = cs ^ (r & 7);
        const __hip_bfloat16* g = omb + (long)(m0 + r) * 64 + cl * 8;
        GLDS16(g, Alds + issue * 1024);
    }
#pragma unroll
    for (int jj = 0; jj < 2; ++jj) {
        int issue = jj * 4 + wid;
        int chunk = issue * 64 + lane;
        int r = chunk >> 3, cs = chunk & 7;
        int cl = cs ^ (r & 7);
        const __hip_bfloat16* g = fcgT + (long)(n0 + r) * 64 + cl * 8;
        GLDS16(g, Blds + issue * 1024);
    }
    __syncthreads();
#pragma unroll
    for (int kk = 0; kk < 2; ++kk) {
        bf16x8 af[4], bfr[2];
#pragma unroll
        for (int im = 0; im < 4; ++im) {
            int r = wr * 64 + im * 16 + l15;
            int cl = (kk * 4 + l4) ^ (l15 & 7);
            af[im] = *(const bf16x8*)(Alds + r * 128 + cl * 16);
        }
#pragma unroll
        for (int jn = 0; jn < 2; ++jn) {
            int r = wc * 32 + jn * 16 + l15;
            int cl = (kk * 4 + l4) ^ (l15 & 7);
            bfr[jn] = *(const bf16x8*)(Blds + r * 128 + cl * 16);
        }
#pragma unroll
        for (int im = 0; im < 4; ++im)
#pragma unroll
            for (int jn = 0; jn < 2; ++jn)
                acc[im][jn] = __builtin_amdgcn_mfma_f32_16x16x32_bf16(
                    af[im], bfr[jn], acc[im][jn], 0, 0, 0);
    }
    const int o = ((n0 + wc * 32) >> 1) + l15;
    const float fb = fc_b[o], gb = gate_b[o];
#pragma unroll
    for (int im = 0; im < 4; ++im)
#pragma unroll
        for (int reg = 0; reg < 4; ++reg) {
            long m = m0 + wr * 64 + im * 16 + l4 * 4 + reg;
            long idx = m * 256 + o;
            float mv = maskb[m];
            float att = sigmoidf_(acc[im][1][reg] + gb) * tanhf(acc[im][0][reg] + fb);
            float ho, co;
            if (mv != 0.f) {
                float h2 = __bfloat162float(hnewb[idx]) + att;
                ho = h2; co = h2;
            } else {
                ho = hx[idx]; co = cx[idx];
            }
            hx_out[idx] = ho;
            cx_out[idx] = co;
            mask_w[idx] = mv;
        }
}

// ---------------------------------------------------------------------------
extern "C" void kernel_launch(void* const* d_in, const int* in_sizes, int n_in,
                              void* d_out, int out_size, void* d_ws, size_t ws_size,
                              hipStream_t stream)
{
    const float* inp     = (const float*)d_in[0];
    const float* hx      = (const float*)d_in[1];
    const float* cx      = (const float*)d_in[2];
    const float* Wq_i    = (const float*)d_in[4];
    const float* Wk_i    = (const float*)d_in[5];
    const float* Wv_i    = (const float*)d_in[6];
    const float* fc_i_w  = (const float*)d_in[7];
    const float* fc_i_b  = (const float*)d_in[8];
    const float* Wq_m    = (const float*)d_in[9];
    const float* Wk_m    = (const float*)d_in[10];
    const float* Wv_m    = (const float*)d_in[11];
    const float* fc_m_w  = (const float*)d_in[12];
    const float* fc_m_b  = (const float*)d_in[13];
    const float* gate_m_w= (const float*)d_in[14];
    const float* gate_m_b= (const float*)d_in[15];
    const float* Wih     = (const float*)d_in[16];
    const float* Whh     = (const float*)d_in[17];
    const float* bih     = (const float*)d_in[18];
    const float* bhh     = (const float*)d_in[19];

    float* out = (float*)d_out;
    const long BH = (long)B_SZ * NHID_;   // 8388608
    float* hx_out = out;
    float* cx_out = out + BH;
    float* mask_w = out + 2 * BH;
    __hip_bfloat16* hxb = (__hip_bfloat16*)out;   // bf16 hx in hx_out region (dead after gru)
    __hip_bfloat16* qkvb = (__hip_bfloat16*)out;  // q|k|v bf16, written post-gru
    float* pbuf = cx_out;                         // (B,2048) f32 p, dead before att_final

    float* w = (float*)d_ws;
    float* a_buf = w;                                        // [0, 32768)
    float* maskb = w + 32768;                                // [32768, 65536)
    float* cbuf  = w + 65536;                                // [65536, 71680)
    __hip_bfloat16* fcgT = (__hip_bfloat16*)(w + 73728);     // [73728, 90112)
    __hip_bfloat16* WmT  = (__hip_bfloat16*)(w + 90112);     // [90112, 286720)
    __hip_bfloat16* Wihb = (__hip_bfloat16*)(w + 286720);    // [286720, 3432448)
    __hip_bfloat16* Whhb = (__hip_bfloat16*)(w + 3432448);   // [3432448, 4218880)
    __hip_bfloat16* wfcb = (__hip_bfloat16*)(w + 4218880);   // [4218880, 6316032)
    __hip_bfloat16* hnewb= (__hip_bfloat16*)(w + 6316032);   // [6316032, 10510336)
    float* krow = w + 8413184;                               // [8413184, 8675328)
    __hip_bfloat16* inpb = (__hip_bfloat16*)(w + 8675328);   // [8675328, 9723904)
    __hip_bfloat16* WvB  = (__hip_bfloat16*)(w + 9723904);   // [9723904, 9986048)
    __hip_bfloat16* fcT  = (__hip_bfloat16*)(w + 9986048);   // [9986048, 10510336)
    __hip_bfloat16* WvFT = (__hip_bfloat16*)(w + 10510336);  // [10510336, 10772480)
    __hip_bfloat16* omb  = (__hip_bfloat16*)(w + 286720);    // post-gru overlay

    // ---- Phase A: merged prep ----
    prep_all<<<dim3(11776), dim3(256), 0, stream>>>(
        Wih, fc_i_b, bih, Wihb, cbuf,
        inp, inpb, Whh, Whhb, Wv_i + 512 * 1024, WvB,
        fc_i_w, fcT, Wq_m, Wk_m, Wv_m, WmT, fc_m_w, gate_m_w, fcgT);
    // ---- Phase B: mask path (fp32) + hxb emit ----
    gemm_nn<<<dim3(1, 64, 1), dim3(256), 0, stream>>>(
        inp, Wk_i + 512 * 64, krow, 4096, 64, 512, 512, 64, 64, 0, 0, 0);
    gemm_nt_f32<<<dim3(4, 64, 8), dim3(256), 0, stream>>>(
        krow, 64, Wq_i, 64, pbuf, 2048, 64, 16384, 256);
    s1_mask_fused<<<dim3(1024), dim3(256), 0, stream>>>(hx, pbuf, a_buf, maskb, hxb);
    // WvFT(1024x512) = fcT @ WvB^T
    gemm_mfma_obf16<<<dim3(8, 8, 1), dim3(256), 0, stream>>>(
        fcT, 1024, WvB, 1024, WvFT, 512, 1024);
    // wfcb = inpb @ WvFT^T
    gemm_mfma_obf16<<<dim3(16, 32, 1), dim3(256), 0, stream>>>(
        inpb, 512, WvFT, 512, wfcb, 1024, 512);
    // ---- Phase C: fused MFMA GEMM + GRU (counted-vmcnt pipeline) ----
    gru_fused_mfma<<<dim3(2048), dim3(512), 0, stream>>>(
        wfcb, hxb, a_buf, cbuf, Wihb, Whhb, bhh, hnewb);
    // ---- Phase D: q/k/v_m projections ----
    gemm_mfma_qkv<<<dim3(3, 32, 8), dim3(256), 0, stream>>>(hnewb, WmT, qkvb);
    // ---- Phase E: memory attention + fused att/final ----
    mattn_kernel<<<dim3(512), dim3(256), 0, stream>>>(
        qkvb, qkvb + 2097152, qkvb + 4194304, omb);
    att_final<<<dim3(8, 256, 1), dim3(256), 0, stream>>>(
        omb, fcgT, fc_m_b, gate_m_b, hnewb, maskb, hx, cx, hx_out, cx_out, mask_w);
}

// Round 14
// 254.960 us; speedup vs baseline: 1.1589x; 1.1589x over previous
//
#include <hip/hip_runtime.h>
#include <hip/hip_bf16.h>

#define B_SZ 4096
#define NHID_ 2048

typedef __bf16 bf16x8 __attribute__((ext_vector_type(8)));
typedef float f32x4 __attribute__((ext_vector_type(4)));

__device__ __forceinline__ float sigmoidf_(float x) { return 1.f / (1.f + expf(-x)); }

#define GLDS16(gp, lp) __builtin_amdgcn_global_load_lds( \
    (const __attribute__((address_space(1))) void*)(gp), \
    (__attribute__((address_space(3))) void*)(lp), 16, 0, 0)

// ---------------------------------------------------------------------------
// Merged prep: [0,6144) wih_prep | [6144,10240) f2b3 | [10240,11264) fcT tconv
// | [11264,11648) WmT tconv | [11648,11776) fcg_prep.
// ---------------------------------------------------------------------------
__global__ __launch_bounds__(256) void prep_all(
    const float* __restrict__ Wih, const float* __restrict__ fc_i_b,
    const float* __restrict__ bih, __hip_bfloat16* __restrict__ Wihb,
    float* __restrict__ cb,
    const float* __restrict__ inp, __hip_bfloat16* __restrict__ inpb,
    const float* __restrict__ Whh, __hip_bfloat16* __restrict__ Whhb,
    const float* __restrict__ WvBsrc, __hip_bfloat16* __restrict__ WvB,
    const float* __restrict__ fc_i_w, __hip_bfloat16* __restrict__ fcT,
    const float* __restrict__ Wq_m, const float* __restrict__ Wk_m,
    const float* __restrict__ Wv_m, __hip_bfloat16* __restrict__ WmT,
    const float* __restrict__ fc_m_w, const float* __restrict__ gate_m_w,
    __hip_bfloat16* __restrict__ fcgT)
{
    __shared__ float smem[32 * 33];
    const int bid = blockIdx.x;
    const int tid = threadIdx.x;

    if (bid < 6144) {
        long j = bid;
        const float* row = Wih + j * 1024;
        __hip_bfloat16* drow = Wihb + j * 1024;
        int i = tid * 4;
        float4 v = *(const float4*)(row + i);
        __hip_bfloat16 b0 = __float2bfloat16(v.x);
        __hip_bfloat16 b1 = __float2bfloat16(v.y);
        __hip_bfloat16 b2 = __float2bfloat16(v.z);
        __hip_bfloat16 b3 = __float2bfloat16(v.w);
        ushort4 u;
        u.x = *(unsigned short*)&b0; u.y = *(unsigned short*)&b1;
        u.z = *(unsigned short*)&b2; u.w = *(unsigned short*)&b3;
        *(ushort4*)(drow + i) = u;
        float s = fc_i_b[i] * v.x + fc_i_b[i + 1] * v.y +
                  fc_i_b[i + 2] * v.z + fc_i_b[i + 3] * v.w;
#pragma unroll
        for (int off = 32; off > 0; off >>= 1) s += __shfl_xor(s, off, 64);
        if ((tid & 63) == 0) smem[tid >> 6] = s;
        __syncthreads();
        if (tid == 0) cb[j] = smem[0] + smem[1] + smem[2] + smem[3] + bih[j];
    } else if (bid < 10240) {
        long i = (long)(bid - 6144) * 256 + tid;   // [0, 1048576)
        const float* src; __hip_bfloat16* dst; long off;
        if (i < 524288)       { src = inp;    dst = inpb; off = i; }
        else if (i < 917504)  { src = Whh;    dst = Whhb; off = i - 524288; }
        else                  { src = WvBsrc; dst = WvB;  off = i - 917504; }
        float4 v = ((const float4*)src)[off];
        __hip_bfloat16 b0 = __float2bfloat16(v.x);
        __hip_bfloat16 b1 = __float2bfloat16(v.y);
        __hip_bfloat16 b2 = __float2bfloat16(v.z);
        __hip_bfloat16 b3 = __float2bfloat16(v.w);
        ushort4 u;
        u.x = *(unsigned short*)&b0; u.y = *(unsigned short*)&b1;
        u.z = *(unsigned short*)&b2; u.w = *(unsigned short*)&b3;
        ((ushort4*)dst)[off] = u;
    } else if (bid < 11264) {
        int lb = bid - 10240;                 // [0,1024)
        int r0 = (lb >> 5) * 32, c0 = (lb & 31) * 32;
        int tx = tid & 31, ty = tid >> 5;
        float (*tile)[33] = (float(*)[33])smem;
#pragma unroll
        for (int i = 0; i < 4; ++i)
            tile[ty + i * 8][tx] = fc_i_w[(long)(r0 + ty + i * 8) * 1024 + c0 + tx];
        __syncthreads();
#pragma unroll
        for (int i = 0; i < 4; ++i)
            fcT[(long)(c0 + ty + i * 8) * 1024 + r0 + tx] =
                __float2bfloat16(tile[tx][ty + i * 8]);
    } else if (bid < 11648) {
        int lb = bid - 11264;                 // [0,384)
        int z = lb >> 4, rem = lb & 15;
        int by = rem >> 1, bx = rem & 1;
        int which = z >> 3, nb = z & 7;
        const float* src = (which == 0) ? Wq_m : (which == 1) ? Wk_m : Wv_m;
        src += (long)nb * 16384;
        __hip_bfloat16* dst = WmT + (long)nb * 49152 + which * 64 * 256;
        int r0 = by * 32, c0 = bx * 32;
        int tx = tid & 31, ty = tid >> 5;
        float (*tile)[33] = (float(*)[33])smem;
#pragma unroll
        for (int i = 0; i < 4; ++i)
            tile[ty + i * 8][tx] = src[(long)(r0 + ty + i * 8) * 64 + c0 + tx];
        __syncthreads();
#pragma unroll
        for (int i = 0; i < 4; ++i)
            dst[(long)(c0 + ty + i * 8) * 256 + r0 + tx] =
                __float2bfloat16(tile[tx][ty + i * 8]);
    } else {
        int t = (bid - 11648) * 256 + tid;    // [0,32768)
        int np = t >> 6, k = t & 63;
        int o = (np >> 5) * 16 + (np & 15);
        const float* src = ((np >> 4) & 1) ? gate_m_w : fc_m_w;
        fcgT[t] = __float2bfloat16(src[k * 256 + o]);
    }
}

// ---------------------------------------------------------------------------
// Generic fp32 tiled GEMM (krow only)
// ---------------------------------------------------------------------------
#define GM_BM 64
#define GM_BN 64
#define GM_BK 16

__global__ __launch_bounds__(256) void gemm_nn(
    const float* __restrict__ A, const float* __restrict__ Bm, float* __restrict__ C,
    int M, int N, int K, int lda, int ldb, int ldc,
    long sA, long sB, long sC)
{
    const int z = blockIdx.z;
    A += (long)z * sA; Bm += (long)z * sB; C += (long)z * sC;
    const int m0 = blockIdx.y * GM_BM;
    const int n0 = blockIdx.x * GM_BN;
    const int tid = threadIdx.x;
    const int tx = tid & 15;
    const int ty = tid >> 4;

    __shared__ float As[GM_BK][GM_BM + 4];
    __shared__ float Bs[GM_BK][GM_BN + 4];

    float acc[4][4] = {};

    for (int k0 = 0; k0 < K; k0 += GM_BK) {
#pragma unroll
        for (int i = 0; i < 4; ++i) {
            int idx = tid + i * 256;
            int r = idx >> 4, c = idx & 15;
            As[c][r] = A[(long)(m0 + r) * lda + k0 + c];
        }
#pragma unroll
        for (int i = 0; i < 4; ++i) {
            int idx = tid + i * 256;
            int r = idx >> 6, c = idx & 63;
            Bs[r][c] = Bm[(long)(k0 + r) * ldb + n0 + c];
        }
        __syncthreads();
#pragma unroll
        for (int kk = 0; kk < GM_BK; ++kk) {
            float4 a4 = *(const float4*)&As[kk][ty * 4];
            float4 b4 = *(const float4*)&Bs[kk][tx * 4];
            float av[4] = {a4.x, a4.y, a4.z, a4.w};
            float bv[4] = {b4.x, b4.y, b4.z, b4.w};
#pragma unroll
            for (int i = 0; i < 4; ++i)
#pragma unroll
                for (int j = 0; j < 4; ++j)
                    acc[i][j] += av[i] * bv[j];
        }
        __syncthreads();
    }
#pragma unroll
    for (int i = 0; i < 4; ++i) {
        long m = m0 + ty * 4 + i;
#pragma unroll
        for (int j = 0; j < 4; ++j) {
            int n = n0 + tx * 4 + j;
            C[m * ldc + n] = acc[i][j];
        }
    }
}

// ---------------------------------------------------------------------------
// fp32 GEMM with N-major B: C(MxN) = A(MxK) @ BT(NxK)^T, batched z over BT/C.
// ---------------------------------------------------------------------------
__global__ __launch_bounds__(256) void gemm_nt_f32(
    const float* __restrict__ A, int lda,
    const float* __restrict__ BT, int ldb,
    float* __restrict__ C, int ldc, int K, long sB, long sC)
{
    BT += (long)blockIdx.z * sB;
    C  += (long)blockIdx.z * sC;
    const int m0 = blockIdx.y * 64;
    const int n0 = blockIdx.x * 64;
    const int tid = threadIdx.x;
    const int tx = tid & 15;
    const int ty = tid >> 4;

    __shared__ float As[16][68];
    __shared__ float Bs[64][17];

    float acc[4][4] = {};

    for (int k0 = 0; k0 < K; k0 += 16) {
#pragma unroll
        for (int i = 0; i < 4; ++i) {
            int idx = tid + i * 256;
            int r = idx >> 4, c = idx & 15;
            As[c][r] = A[(long)(m0 + r) * lda + k0 + c];
        }
#pragma unroll
        for (int i = 0; i < 4; ++i) {
            int idx = tid + i * 256;
            int r = idx >> 4, c = idx & 15;
            Bs[r][c] = BT[(long)(n0 + r) * ldb + k0 + c];
        }
        __syncthreads();
#pragma unroll
        for (int kk = 0; kk < 16; ++kk) {
            float4 a4 = *(const float4*)&As[kk][ty * 4];
            float av[4] = {a4.x, a4.y, a4.z, a4.w};
            float bv[4];
#pragma unroll
            for (int j = 0; j < 4; ++j) bv[j] = Bs[tx * 4 + j][kk];
#pragma unroll
            for (int i = 0; i < 4; ++i)
#pragma unroll
                for (int j = 0; j < 4; ++j)
                    acc[i][j] += av[i] * bv[j];
        }
        __syncthreads();
    }
#pragma unroll
    for (int i = 0; i < 4; ++i) {
        long m = m0 + ty * 4 + i;
#pragma unroll
        for (int j = 0; j < 4; ++j) {
            int n = n0 + tx * 4 + j;
            C[m * ldc + n] = acc[i][j];
        }
    }
}

// ---------------------------------------------------------------------------
// Fused s1 / sigmoid / top-k mask + hx->bf16 emit.
// ---------------------------------------------------------------------------
__global__ __launch_bounds__(256) void s1_mask_fused(
    const float* __restrict__ hx,   // (B,2048)
    const float* __restrict__ p,    // (B,2048)  p[b, n*256+i]
    float* __restrict__ a_buf, float* __restrict__ mask_buf,
    __hip_bfloat16* __restrict__ hxb)   // (B,2048) bf16 out
{
    const int wave = threadIdx.x >> 6;
    const int lane = threadIdx.x & 63;
    const long b = (long)blockIdx.x * 4 + wave;
    const long base = b * 2048 + lane * 4;
    float s1v[8];
#pragma unroll
    for (int n = 0; n < 8; ++n) {
        float4 hv = *(const float4*)(hx + base + n * 256);
        float4 pv = *(const float4*)(p + base + n * 256);
        __hip_bfloat16 c0 = __float2bfloat16(hv.x);
        __hip_bfloat16 c1 = __float2bfloat16(hv.y);
        __hip_bfloat16 c2 = __float2bfloat16(hv.z);
        __hip_bfloat16 c3 = __float2bfloat16(hv.w);
        ushort4 u;
        u.x = *(unsigned short*)&c0; u.y = *(unsigned short*)&c1;
        u.z = *(unsigned short*)&c2; u.w = *(unsigned short*)&c3;
        *(ushort4*)(hxb + base + n * 256) = u;
        float s = hv.x * pv.x + hv.y * pv.y + hv.z * pv.z + hv.w * pv.w;
#pragma unroll
        for (int off = 32; off > 0; off >>= 1) s += __shfl_xor(s, off, 64);
        s1v[n] = s * 0.125f;
    }
    unsigned maskbits = 0;
#pragma unroll
    for (int n = 0; n < 8; ++n) {
        int rank = 0;
#pragma unroll
        for (int m = 0; m < 8; ++m) {
            if (m == n) continue;
            if (s1v[m] < s1v[n] || (s1v[m] == s1v[n] && m < n)) rank++;
        }
        if (rank >= 4) maskbits |= (1u << n);
    }
    if (lane < 8) {
        float sv = s1v[0];
#pragma unroll
        for (int n = 1; n < 8; ++n)
            if (lane == n) sv = s1v[n];
        a_buf[b * 8 + lane] = sigmoidf_(sv);
        mask_buf[b * 8 + lane] = ((maskbits >> lane) & 1u) ? 1.0f : 0.0f;
    }
}

// ---------------------------------------------------------------------------
// MFMA GEMM: C(bf16, MxN) = A(bf16, MxK, lda) @ BT(bf16, NxK, ldb)^T
// ---------------------------------------------------------------------------
__global__ __launch_bounds__(256) void gemm_mfma_obf16(
    const __hip_bfloat16* __restrict__ A, int lda,
    const __hip_bfloat16* __restrict__ BT, int ldb,
    __hip_bfloat16* __restrict__ C, int ldc, int K)
{
    const int m0 = blockIdx.y * 128;
    const int n0 = blockIdx.x * 64;
    const int tid = threadIdx.x;
    const int lane = tid & 63, wid = tid >> 6;
    const int wr = wid >> 1, wc = wid & 1;
    const int l15 = lane & 15, l4 = lane >> 4;

    __shared__ __align__(16) char lds_raw[16384 + 8192];
    char* Alds = lds_raw;
    char* Blds = lds_raw + 16384;

    f32x4 acc[4][2] = {};

    for (int k0 = 0; k0 < K; k0 += 64) {
#pragma unroll
        for (int ii = 0; ii < 4; ++ii) {
            int issue = ii * 4 + wid;
            int chunk = issue * 64 + lane;
            int r = chunk >> 3, cs = chunk & 7;
            int cl = cs ^ (r & 7);
            const __hip_bfloat16* g = A + (long)(m0 + r) * lda + k0 + cl * 8;
            GLDS16(g, Alds + issue * 1024);
        }
#pragma unroll
        for (int jj = 0; jj < 2; ++jj) {
            int issue = jj * 4 + wid;
            int chunk = issue * 64 + lane;
            int r = chunk >> 3, cs = chunk & 7;
            int cl = cs ^ (r & 7);
            const __hip_bfloat16* g = BT + (long)(n0 + r) * ldb + k0 + cl * 8;
            GLDS16(g, Blds + issue * 1024);
        }
        __syncthreads();
#pragma unroll
        for (int kk = 0; kk < 2; ++kk) {
            bf16x8 af[4], bfr[2];
#pragma unroll
            for (int im = 0; im < 4; ++im) {
                int r = wr * 64 + im * 16 + l15;
                int cl = (kk * 4 + l4) ^ (l15 & 7);
                af[im] = *(const bf16x8*)(Alds + r * 128 + cl * 16);
            }
#pragma unroll
            for (int jn = 0; jn < 2; ++jn) {
                int r = wc * 32 + jn * 16 + l15;
                int cl = (kk * 4 + l4) ^ (l15 & 7);
                bfr[jn] = *(const bf16x8*)(Blds + r * 128 + cl * 16);
            }
#pragma unroll
            for (int im = 0; im < 4; ++im)
#pragma unroll
                for (int jn = 0; jn < 2; ++jn)
                    acc[im][jn] = __builtin_amdgcn_mfma_f32_16x16x32_bf16(
                        af[im], bfr[jn], acc[im][jn], 0, 0, 0);
        }
        __syncthreads();
    }
#pragma unroll
    for (int im = 0; im < 4; ++im)
#pragma unroll
        for (int reg = 0; reg < 4; ++reg) {
            long m = m0 + wr * 64 + im * 16 + l4 * 4 + reg;
#pragma unroll
            for (int jn = 0; jn < 2; ++jn) {
                int n = n0 + wc * 32 + jn * 16 + l15;
                C[m * ldc + n] = __float2bfloat16(acc[im][jn][reg]);
            }
        }
}

// ---------------------------------------------------------------------------
// Fused q/k/v_m projections (bf16 out).
// ---------------------------------------------------------------------------
__global__ __launch_bounds__(256) void gemm_mfma_qkv(
    const __hip_bfloat16* __restrict__ hnewb,  // (B,2048)
    const __hip_bfloat16* __restrict__ WmT,    // (8,192,256)
    __hip_bfloat16* __restrict__ qout)         // q|k|v, each 2097152 bf16
{
    const int z = blockIdx.z;
    const int m0 = blockIdx.y * 128;
    const int n0 = blockIdx.x * 64;
    const int tid = threadIdx.x;
    const int lane = tid & 63, wid = tid >> 6;
    const int wr = wid >> 1, wc = wid & 1;
    const int l15 = lane & 15, l4 = lane >> 4;

    const __hip_bfloat16* A = hnewb + z * 256;
    const __hip_bfloat16* BT = WmT + (long)z * 192 * 256;

    __shared__ __align__(16) char lds_raw[16384 + 8192];
    char* Alds = lds_raw;
    char* Blds = lds_raw + 16384;

    f32x4 acc[4][2] = {};

    for (int k0 = 0; k0 < 256; k0 += 64) {
#pragma unroll
        for (int ii = 0; ii < 4; ++ii) {
            int issue = ii * 4 + wid;
            int chunk = issue * 64 + lane;
            int r = chunk >> 3, cs = chunk & 7;
            int cl = cs ^ (r & 7);
            const __hip_bfloat16* g = A + (long)(m0 + r) * 2048 + k0 + cl * 8;
            GLDS16(g, Alds + issue * 1024);
        }
#pragma unroll
        for (int jj = 0; jj < 2; ++jj) {
            int issue = jj * 4 + wid;
            int chunk = issue * 64 + lane;
            int r = chunk >> 3, cs = chunk & 7;
            int cl = cs ^ (r & 7);
            const __hip_bfloat16* g = BT + (long)(n0 + r) * 256 + k0 + cl * 8;
            GLDS16(g, Blds + issue * 1024);
        }
        __syncthreads();
#pragma unroll
        for (int kk = 0; kk < 2; ++kk) {
            bf16x8 af[4], bfr[2];
#pragma unroll
            for (int im = 0; im < 4; ++im) {
                int r = wr * 64 + im * 16 + l15;
                int cl = (kk * 4 + l4) ^ (l15 & 7);
                af[im] = *(const bf16x8*)(Alds + r * 128 + cl * 16);
            }
#pragma unroll
            for (int jn = 0; jn < 2; ++jn) {
                int r = wc * 32 + jn * 16 + l15;
                int cl = (kk * 4 + l4) ^ (l15 & 7);
                bfr[jn] = *(const bf16x8*)(Blds + r * 128 + cl * 16);
            }
#pragma unroll
            for (int im = 0; im < 4; ++im)
#pragma unroll
                for (int jn = 0; jn < 2; ++jn)
                    acc[im][jn] = __builtin_amdgcn_mfma_f32_16x16x32_bf16(
                        af[im], bfr[jn], acc[im][jn], 0, 0, 0);
        }
        __syncthreads();
    }
#pragma unroll
    for (int jn = 0; jn < 2; ++jn) {
        int j = n0 + wc * 32 + jn * 16 + l15;   // [0,192)
        int g = j >> 6, d = j & 63;
        __hip_bfloat16* outp = qout + (long)g * 2097152 + (long)z * 64 + d;
#pragma unroll
        for (int im = 0; im < 4; ++im)
#pragma unroll
            for (int reg = 0; reg < 4; ++reg) {
                long m = m0 + wr * 64 + im * 16 + l4 * 4 + reg;
                outp[m * 512] = __float2bfloat16(acc[im][jn][reg]);
            }
    }
}

// ---------------------------------------------------------------------------
// MFMA big GEMM + fused GRU epilogue — R11/R12-verified 2-phase dbuf with
// hoisted addressing. 512 thr / 8 waves, wave 32m x 48n, XCD-pinned kblk.
// ---------------------------------------------------------------------------
__global__ __launch_bounds__(512) void gru_fused_mfma(
    const __hip_bfloat16* __restrict__ wfcb,   // (B,1024)
    const __hip_bfloat16* __restrict__ hxb,    // (B,2048)
    const float* __restrict__ a_buf,           // (B,8)
    const float* __restrict__ cb,              // (8,768)
    const __hip_bfloat16* __restrict__ Wihb,   // (8,768,1024)
    const __hip_bfloat16* __restrict__ Whhb,   // (8,768,256)
    const float* __restrict__ bhh,             // (8,768)
    __hip_bfloat16* __restrict__ hnewb)        // (B,2048)
{
    const int bid = blockIdx.x;
    const int kblk = bid & 7;
    const int r_ = bid >> 3;
    const int ol0 = (r_ & 7) * 32;
    const int m0 = (r_ >> 3) * 128;
    const int tid = threadIdx.x;
    const int lane = tid & 63, wid = tid >> 6;
    const int wr = wid >> 1;
    const int wc = wid & 1;
    const int l15 = lane & 15, l4 = lane >> 4;

    __shared__ __align__(16) char lds_raw[2 * 28672];

    f32x4 accx[2][3] = {};
    f32x4 acch[2][3] = {};

    const __hip_bfloat16* Wk = Wihb + (long)kblk * 768 * 1024;
    const __hip_bfloat16* Wh = Whhb + (long)kblk * 768 * 256;
    const __hip_bfloat16* hxk = hxb + kblk * 256;

    const int iiA0 = wid, iiA1 = wid + 8;
    const int cA0 = iiA0 * 64 + lane, rA0 = cA0 >> 3, clA0 = (cA0 & 7) ^ (rA0 & 7);
    const int cA1 = iiA1 * 64 + lane, rA1 = cA1 >> 3, clA1 = (cA1 & 7) ^ (rA1 & 7);
    const int jjB0 = wid, jjB1 = wid + 8;
    const int cB0 = jjB0 * 64 + lane, rB0 = cB0 >> 3, clB0 = (cB0 & 7) ^ (rB0 & 7);
    const int cB1 = jjB1 * 64 + lane, rB1 = cB1 >> 3, clB1 = (cB1 & 7) ^ (rB1 & 7);
    const bool hasB1 = (wid < 4);
    const int gg0 = rB0 >> 5, oll0 = rB0 & 31;
    const int gg1 = (rB1 >> 5) & 3, oll1 = rB1 & 31;
    const int dA0 = iiA0 * 1024, dA1 = iiA1 * 1024;
    const int dB0 = 16384 + jjB0 * 1024, dB1 = 16384 + jjB1 * 1024;

    const __hip_bfloat16* pA0 = wfcb + (long)(m0 + rA0) * 1024 + clA0 * 8;
    const __hip_bfloat16* pA1 = wfcb + (long)(m0 + rA1) * 1024 + clA1 * 8;
    const __hip_bfloat16* pB0 = Wk + (long)(gg0 * 256 + ol0 + oll0) * 1024 + clB0 * 8;
    const __hip_bfloat16* pB1 = Wk + (long)(gg1 * 256 + ol0 + oll1) * 1024 + clB1 * 8;

#define STAGE4(buf) do {                                                       \
    char* L = lds_raw + (buf) * 28672;                                         \
    GLDS16(pA0, L + dA0);                                                      \
    GLDS16(pA1, L + dA1);                                                      \
    GLDS16(pB0, L + dB0);                                                      \
    if (hasB1) GLDS16(pB1, L + dB1);                                           \
    pA0 += 64; pA1 += 64; pB0 += 64; pB1 += 64;                                \
} while (0)

    int offA[2][2], offB[2][3];
#pragma unroll
    for (int kk = 0; kk < 2; ++kk) {
        int cl = (kk * 4 + l4) ^ (l15 & 7);
#pragma unroll
        for (int im = 0; im < 2; ++im)
            offA[kk][im] = (wr * 32 + im * 16 + l15) * 128 + cl * 16;
#pragma unroll
        for (int g = 0; g < 3; ++g)
            offB[kk][g] = 16384 + (g * 32 + wc * 16 + l15) * 128 + cl * 16;
    }

#define COMPUTE(acc, buf) do {                                                 \
    char* L = lds_raw + (buf) * 28672;                                         \
    _Pragma("unroll") for (int kk = 0; kk < 2; ++kk) {                         \
        bf16x8 af[2], bfr[3];                                                  \
        _Pragma("unroll") for (int im = 0; im < 2; ++im)                       \
            af[im] = *(const bf16x8*)(L + offA[kk][im]);                       \
        _Pragma("unroll") for (int g = 0; g < 3; ++g)                          \
            bfr[g] = *(const bf16x8*)(L + offB[kk][g]);                        \
        _Pragma("unroll") for (int im = 0; im < 2; ++im)                       \
            _Pragma("unroll") for (int g = 0; g < 3; ++g)                      \
                acc[im][g] = __builtin_amdgcn_mfma_f32_16x16x32_bf16(          \
                    af[im], bfr[g], acc[im][g], 0, 0, 0);                      \
    }                                                                          \
} while (0)

    STAGE4(0);
    asm volatile("s_waitcnt vmcnt(0)" ::: "memory");
    __syncthreads();

    int cur = 0;
    for (int t = 0; t < 16; ++t) {
        if (t < 15) {
            STAGE4(cur ^ 1);
        } else {
            pA0 = hxk + (long)(m0 + rA0) * 2048 + clA0 * 8;
            pA1 = hxk + (long)(m0 + rA1) * 2048 + clA1 * 8;
            pB0 = Wh + (long)(gg0 * 256 + ol0 + oll0) * 256 + clB0 * 8;
            pB1 = Wh + (long)(gg1 * 256 + ol0 + oll1) * 256 + clB1 * 8;
            STAGE4(cur ^ 1);
        }
        __builtin_amdgcn_s_setprio(1);
        COMPUTE(accx, cur);
        __builtin_amdgcn_s_setprio(0);
        asm volatile("s_waitcnt vmcnt(0)" ::: "memory");
        __syncthreads();
        cur ^= 1;
    }
    for (int t = 0; t < 4; ++t) {
        if (t < 3) STAGE4(cur ^ 1);
        __builtin_amdgcn_s_setprio(1);
        COMPUTE(acch, cur);
        __builtin_amdgcn_s_setprio(0);
        asm volatile("s_waitcnt vmcnt(0)" ::: "memory");
        __syncthreads();
        cur ^= 1;
    }
#undef STAGE4
#undef COMPUTE

    const int ol = ol0 + wc * 16 + l15;
    const float* cbk = cb + kblk * 768;
    const float cb0 = cbk[ol], cb1 = cbk[256 + ol], cb2 = cbk[512 + ol];
    const float* bhk = bhh + kblk * 768;
    const float bh0 = bhk[ol], bh1 = bhk[256 + ol], bh2 = bhk[512 + ol];
#pragma unroll
    for (int im = 0; im < 2; ++im) {
#pragma unroll
        for (int reg = 0; reg < 4; ++reg) {
            long m = m0 + wr * 32 + im * 16 + l4 * 4 + reg;
            float av = a_buf[m * 8 + kblk];
            float gx0 = av * accx[im][0][reg] + cb0;
            float gx1 = av * accx[im][1][reg] + cb1;
            float gx2 = av * accx[im][2][reg] + cb2;
            float gh0 = acch[im][0][reg] + bh0;
            float gh1 = acch[im][1][reg] + bh1;
            float gh2 = acch[im][2][reg] + bh2;
            float rr = sigmoidf_(gx0 + gh0);
            float zz = sigmoidf_(gx1 + gh1);
            float nn = tanhf(gx2 + rr * gh2);
            long idx = m * 2048 + kblk * 256 + ol;
            float hxv = __bfloat162float(hxb[idx]);
            hnewb[idx] = __float2bfloat16((1.f - zz) * nn + zz * hxv);
        }
    }
}

// ---------------------------------------------------------------------------
// Memory attention (bf16 in/out)
// ---------------------------------------------------------------------------
__global__ __launch_bounds__(256) void mattn_kernel(
    const __hip_bfloat16* __restrict__ qm, const __hip_bfloat16* __restrict__ km,
    const __hip_bfloat16* __restrict__ vm, __hip_bfloat16* __restrict__ omb)
{
    const int t = threadIdx.x;
    const int local = t & 31;
    const long b = (long)blockIdx.x * 8 + (t >> 5);
    const int h = local >> 3, qn = local & 7;
    const long base = b * 512 + h * 16;

    float qv[16];
#pragma unroll
    for (int i = 0; i < 2; ++i) {
        bf16x8 v = *(const bf16x8*)(qm + base + qn * 64 + i * 8);
#pragma unroll
        for (int j = 0; j < 8; ++j) qv[i * 8 + j] = (float)v[j];
    }
    float sc[8];
#pragma unroll
    for (int kn = 0; kn < 8; ++kn) {
        float s = 0.f;
#pragma unroll
        for (int i = 0; i < 2; ++i) {
            bf16x8 v = *(const bf16x8*)(km + base + kn * 64 + i * 8);
#pragma unroll
            for (int j = 0; j < 8; ++j) s += qv[i * 8 + j] * (float)v[j];
        }
        sc[kn] = s * 0.25f;
    }
    float mx = sc[0];
#pragma unroll
    for (int kn = 1; kn < 8; ++kn) mx = fmaxf(mx, sc[kn]);
    float ssum = 0.f;
#pragma unroll
    for (int kn = 0; kn < 8; ++kn) { sc[kn] = expf(sc[kn] - mx); ssum += sc[kn]; }
    float inv = 1.f / ssum;

    float acc[16] = {};
#pragma unroll
    for (int kn = 0; kn < 8; ++kn) {
        float w = sc[kn] * inv;
#pragma unroll
        for (int i = 0; i < 2; ++i) {
            bf16x8 v = *(const bf16x8*)(vm + base + kn * 64 + i * 8);
#pragma unroll
            for (int j = 0; j < 8; ++j) acc[i * 8 + j] += w * (float)v[j];
        }
    }
#pragma unroll
    for (int i = 0; i < 2; ++i) {
        bf16x8 o;
#pragma unroll
        for (int j = 0; j < 8; ++j) o[j] = (__bf16)acc[i * 8 + j];
        *(bf16x8*)(omb + base + qn * 64 + i * 8) = o;
    }
}

// ---------------------------------------------------------------------------
// Fused att GEMM + final (R12-verified).
// ---------------------------------------------------------------------------
__global__ __launch_bounds__(256) void att_final(
    const __hip_bfloat16* __restrict__ omb,    // (32768,64)
    const __hip_bfloat16* __restrict__ fcgT,   // (512,64)
    const float* __restrict__ fc_b, const float* __restrict__ gate_b,
    const __hip_bfloat16* __restrict__ hnewb,  // (32768,256)
    const float* __restrict__ maskb,           // (32768)
    const float* __restrict__ hx, const float* __restrict__ cx,
    float* __restrict__ hx_out, float* __restrict__ cx_out,
    float* __restrict__ mask_w)
{
    const int m0 = blockIdx.y * 128;
    const int n0 = blockIdx.x * 64;
    const int tid = threadIdx.x;
    const int lane = tid & 63, wid = tid >> 6;
    const int wr = wid >> 1, wc = wid & 1;
    const int l15 = lane & 15, l4 = lane >> 4;

    __shared__ __align__(16) char lds_raw[16384 + 8192];
    char* Alds = lds_raw;
    char* Blds = lds_raw + 16384;

    f32x4 acc[4][2] = {};
#pragma unroll
    for (int ii = 0; ii < 4; ++ii) {
        int issue = ii * 4 + wid;
        int chunk = issue * 64 + lane;
        int r = chunk >> 3, cs = chunk & 7;
        int cl = cs ^ (r & 7);
        const __hip_bfloat16* g = omb + (long)(m0 + r) * 64 + cl * 8;
        GLDS16(g, Alds + issue * 1024);
    }
#pragma unroll
    for (int jj = 0; jj < 2; ++jj) {
        int issue = jj * 4 + wid;
        int chunk = issue * 64 + lane;
        int r = chunk >> 3, cs = chunk & 7;
        int cl = cs ^ (r & 7);
        const __hip_bfloat16* g = fcgT + (long)(n0 + r) * 64 + cl * 8;
        GLDS16(g, Blds + issue * 1024);
    }
    __syncthreads();
#pragma unroll
    for (int kk = 0; kk < 2; ++kk) {
        bf16x8 af[4], bfr[2];
#pragma unroll
        for (int im = 0; im < 4; ++im) {
            int r = wr * 64 + im * 16 + l15;
            int cl = (kk * 4 + l4) ^ (l15 & 7);
            af[im] = *(const bf16x8*)(Alds + r * 128 + cl * 16);
        }
#pragma unroll
        for (int jn = 0; jn < 2; ++jn) {
            int r = wc * 32 + jn * 16 + l15;
            int cl = (kk * 4 + l4) ^ (l15 & 7);
            bfr[jn] = *(const bf16x8*)(Blds + r * 128 + cl * 16);
        }
#pragma unroll
        for (int im = 0; im < 4; ++im)
#pragma unroll
            for (int jn = 0; jn < 2; ++jn)
                acc[im][jn] = __builtin_amdgcn_mfma_f32_16x16x32_bf16(
                    af[im], bfr[jn], acc[im][jn], 0, 0, 0);
    }
    const int o = ((n0 + wc * 32) >> 1) + l15;
    const float fb = fc_b[o], gb = gate_b[o];
#pragma unroll
    for (int im = 0; im < 4; ++im)
#pragma unroll
        for (int reg = 0; reg < 4; ++reg) {
            long m = m0 + wr * 64 + im * 16 + l4 * 4 + reg;
            long idx = m * 256 + o;
            float mv = maskb[m];
            float att = sigmoidf_(acc[im][1][reg] + gb) * tanhf(acc[im][0][reg] + fb);
            float ho, co;
            if (mv != 0.f) {
                float h2 = __bfloat162float(hnewb[idx]) + att;
                ho = h2; co = h2;
            } else {
                ho = hx[idx]; co = cx[idx];
            }
            hx_out[idx] = ho;
            cx_out[idx] = co;
            mask_w[idx] = mv;
        }
}

// ---------------------------------------------------------------------------
extern "C" void kernel_launch(void* const* d_in, const int* in_sizes, int n_in,
                              void* d_out, int out_size, void* d_ws, size_t ws_size,
                              hipStream_t stream)
{
    const float* inp     = (const float*)d_in[0];
    const float* hx      = (const float*)d_in[1];
    const float* cx      = (const float*)d_in[2];
    const float* Wq_i    = (const float*)d_in[4];
    const float* Wk_i    = (const float*)d_in[5];
    const float* Wv_i    = (const float*)d_in[6];
    const float* fc_i_w  = (const float*)d_in[7];
    const float* fc_i_b  = (const float*)d_in[8];
    const float* Wq_m    = (const float*)d_in[9];
    const float* Wk_m    = (const float*)d_in[10];
    const float* Wv_m    = (const float*)d_in[11];
    const float* fc_m_w  = (const float*)d_in[12];
    const float* fc_m_b  = (const float*)d_in[13];
    const float* gate_m_w= (const float*)d_in[14];
    const float* gate_m_b= (const float*)d_in[15];
    const float* Wih     = (const float*)d_in[16];
    const float* Whh     = (const float*)d_in[17];
    const float* bih     = (const float*)d_in[18];
    const float* bhh     = (const float*)d_in[19];

    float* out = (float*)d_out;
    const long BH = (long)B_SZ * NHID_;   // 8388608
    float* hx_out = out;
    float* cx_out = out + BH;
    float* mask_w = out + 2 * BH;
    __hip_bfloat16* hxb = (__hip_bfloat16*)out;   // bf16 hx in hx_out region (dead after gru)
    __hip_bfloat16* qkvb = (__hip_bfloat16*)out;  // q|k|v bf16, written post-gru
    float* pbuf = cx_out;                         // (B,2048) f32 p, dead before att_final

    float* w = (float*)d_ws;
    float* a_buf = w;                                        // [0, 32768)
    float* maskb = w + 32768;                                // [32768, 65536)
    float* cbuf  = w + 65536;                                // [65536, 71680)
    __hip_bfloat16* fcgT = (__hip_bfloat16*)(w + 73728);     // [73728, 90112)
    __hip_bfloat16* WmT  = (__hip_bfloat16*)(w + 90112);     // [90112, 286720)
    __hip_bfloat16* Wihb = (__hip_bfloat16*)(w + 286720);    // [286720, 3432448)
    __hip_bfloat16* Whhb = (__hip_bfloat16*)(w + 3432448);   // [3432448, 4218880)
    __hip_bfloat16* wfcb = (__hip_bfloat16*)(w + 4218880);   // [4218880, 6316032)
    __hip_bfloat16* hnewb= (__hip_bfloat16*)(w + 6316032);   // [6316032, 10510336)
    float* krow = w + 8413184;                               // [8413184, 8675328)
    __hip_bfloat16* inpb = (__hip_bfloat16*)(w + 8675328);   // [8675328, 9723904)
    __hip_bfloat16* WvB  = (__hip_bfloat16*)(w + 9723904);   // [9723904, 9986048)
    __hip_bfloat16* fcT  = (__hip_bfloat16*)(w + 9986048);   // [9986048, 10510336)
    __hip_bfloat16* WvFT = (__hip_bfloat16*)(w + 10510336);  // [10510336, 10772480)
    __hip_bfloat16* omb  = (__hip_bfloat16*)(w + 286720);    // post-gru overlay

    // ---- Phase A: merged prep ----
    prep_all<<<dim3(11776), dim3(256), 0, stream>>>(
        Wih, fc_i_b, bih, Wihb, cbuf,
        inp, inpb, Whh, Whhb, Wv_i + 512 * 1024, WvB,
        fc_i_w, fcT, Wq_m, Wk_m, Wv_m, WmT, fc_m_w, gate_m_w, fcgT);
    // ---- Phase B: mask path (fp32) + hxb emit ----
    gemm_nn<<<dim3(1, 64, 1), dim3(256), 0, stream>>>(
        inp, Wk_i + 512 * 64, krow, 4096, 64, 512, 512, 64, 64, 0, 0, 0);
    gemm_nt_f32<<<dim3(4, 64, 8), dim3(256), 0, stream>>>(
        krow, 64, Wq_i, 64, pbuf, 2048, 64, 16384, 256);
    s1_mask_fused<<<dim3(1024), dim3(256), 0, stream>>>(hx, pbuf, a_buf, maskb, hxb);
    // WvFT(1024x512) = fcT @ WvB^T
    gemm_mfma_obf16<<<dim3(8, 8, 1), dim3(256), 0, stream>>>(
        fcT, 1024, WvB, 1024, WvFT, 512, 1024);
    // wfcb = inpb @ WvFT^T
    gemm_mfma_obf16<<<dim3(16, 32, 1), dim3(256), 0, stream>>>(
        inpb, 512, WvFT, 512, wfcb, 1024, 512);
    // ---- Phase C: fused MFMA GEMM + GRU (R12-verified 2-phase dbuf) ----
    gru_fused_mfma<<<dim3(2048), dim3(512), 0, stream>>>(
        wfcb, hxb, a_buf, cbuf, Wihb, Whhb, bhh, hnewb);
    // ---- Phase D: q/k/v_m projections ----
    gemm_mfma_qkv<<<dim3(3, 32, 8), dim3(256), 0, stream>>>(hnewb, WmT, qkvb);
    // ---- Phase E: memory attention + fused att/final ----
    mattn_kernel<<<dim3(512), dim3(256), 0, stream>>>(
        qkvb, qkvb + 2097152, qkvb + 4194304, omb);
    att_final<<<dim3(8, 256, 1), dim3(256), 0, stream>>>(
        omb, fcgT, fc_m_b, gate_m_b, hnewb, maskb, hx, cx, hx_out, cx_out, mask_w);
}

// Round 15
// 231.644 us; speedup vs baseline: 1.2756x; 1.1007x over previous
//
#include <hip/hip_runtime.h>
#include <hip/hip_bf16.h>

#define B_SZ 4096
#define NHID_ 2048

typedef __bf16 bf16x8 __attribute__((ext_vector_type(8)));
typedef float f32x4 __attribute__((ext_vector_type(4)));

__device__ __forceinline__ float sigmoidf_(float x) { return 1.f / (1.f + expf(-x)); }

#define GLDS16(gp, lp) __builtin_amdgcn_global_load_lds( \
    (const __attribute__((address_space(1))) void*)(gp), \
    (__attribute__((address_space(3))) void*)(lp), 16, 0, 0)

// ---------------------------------------------------------------------------
// Merged prep: [0,6144) wih_prep | [6144,10240) f2b3 | [10240,11264) fcT tconv
// | [11264,11648) WmT tconv | [11648,11776) fcg_prep.
// ---------------------------------------------------------------------------
__global__ __launch_bounds__(256) void prep_all(
    const float* __restrict__ Wih, const float* __restrict__ fc_i_b,
    const float* __restrict__ bih, __hip_bfloat16* __restrict__ Wihb,
    float* __restrict__ cb,
    const float* __restrict__ inp, __hip_bfloat16* __restrict__ inpb,
    const float* __restrict__ Whh, __hip_bfloat16* __restrict__ Whhb,
    const float* __restrict__ WvBsrc, __hip_bfloat16* __restrict__ WvB,
    const float* __restrict__ fc_i_w, __hip_bfloat16* __restrict__ fcT,
    const float* __restrict__ Wq_m, const float* __restrict__ Wk_m,
    const float* __restrict__ Wv_m, __hip_bfloat16* __restrict__ WmT,
    const float* __restrict__ fc_m_w, const float* __restrict__ gate_m_w,
    __hip_bfloat16* __restrict__ fcgT)
{
    __shared__ float smem[32 * 33];
    const int bid = blockIdx.x;
    const int tid = threadIdx.x;

    if (bid < 6144) {
        long j = bid;
        const float* row = Wih + j * 1024;
        __hip_bfloat16* drow = Wihb + j * 1024;
        int i = tid * 4;
        float4 v = *(const float4*)(row + i);
        __hip_bfloat16 b0 = __float2bfloat16(v.x);
        __hip_bfloat16 b1 = __float2bfloat16(v.y);
        __hip_bfloat16 b2 = __float2bfloat16(v.z);
        __hip_bfloat16 b3 = __float2bfloat16(v.w);
        ushort4 u;
        u.x = *(unsigned short*)&b0; u.y = *(unsigned short*)&b1;
        u.z = *(unsigned short*)&b2; u.w = *(unsigned short*)&b3;
        *(ushort4*)(drow + i) = u;
        float s = fc_i_b[i] * v.x + fc_i_b[i + 1] * v.y +
                  fc_i_b[i + 2] * v.z + fc_i_b[i + 3] * v.w;
#pragma unroll
        for (int off = 32; off > 0; off >>= 1) s += __shfl_xor(s, off, 64);
        if ((tid & 63) == 0) smem[tid >> 6] = s;
        __syncthreads();
        if (tid == 0) cb[j] = smem[0] + smem[1] + smem[2] + smem[3] + bih[j];
    } else if (bid < 10240) {
        long i = (long)(bid - 6144) * 256 + tid;   // [0, 1048576)
        const float* src; __hip_bfloat16* dst; long off;
        if (i < 524288)       { src = inp;    dst = inpb; off = i; }
        else if (i < 917504)  { src = Whh;    dst = Whhb; off = i - 524288; }
        else                  { src = WvBsrc; dst = WvB;  off = i - 917504; }
        float4 v = ((const float4*)src)[off];
        __hip_bfloat16 b0 = __float2bfloat16(v.x);
        __hip_bfloat16 b1 = __float2bfloat16(v.y);
        __hip_bfloat16 b2 = __float2bfloat16(v.z);
        __hip_bfloat16 b3 = __float2bfloat16(v.w);
        ushort4 u;
        u.x = *(unsigned short*)&b0; u.y = *(unsigned short*)&b1;
        u.z = *(unsigned short*)&b2; u.w = *(unsigned short*)&b3;
        ((ushort4*)dst)[off] = u;
    } else if (bid < 11264) {
        int lb = bid - 10240;                 // [0,1024)
        int r0 = (lb >> 5) * 32, c0 = (lb & 31) * 32;
        int tx = tid & 31, ty = tid >> 5;
        float (*tile)[33] = (float(*)[33])smem;
#pragma unroll
        for (int i = 0; i < 4; ++i)
            tile[ty + i * 8][tx] = fc_i_w[(long)(r0 + ty + i * 8) * 1024 + c0 + tx];
        __syncthreads();
#pragma unroll
        for (int i = 0; i < 4; ++i)
            fcT[(long)(c0 + ty + i * 8) * 1024 + r0 + tx] =
                __float2bfloat16(tile[tx][ty + i * 8]);
    } else if (bid < 11648) {
        int lb = bid - 11264;                 // [0,384)
        int z = lb >> 4, rem = lb & 15;
        int by = rem >> 1, bx = rem & 1;
        int which = z >> 3, nb = z & 7;
        const float* src = (which == 0) ? Wq_m : (which == 1) ? Wk_m : Wv_m;
        src += (long)nb * 16384;
        __hip_bfloat16* dst = WmT + (long)nb * 49152 + which * 64 * 256;
        int r0 = by * 32, c0 = bx * 32;
        int tx = tid & 31, ty = tid >> 5;
        float (*tile)[33] = (float(*)[33])smem;
#pragma unroll
        for (int i = 0; i < 4; ++i)
            tile[ty + i * 8][tx] = src[(long)(r0 + ty + i * 8) * 64 + c0 + tx];
        __syncthreads();
#pragma unroll
        for (int i = 0; i < 4; ++i)
            dst[(long)(c0 + ty + i * 8) * 256 + r0 + tx] =
                __float2bfloat16(tile[tx][ty + i * 8]);
    } else {
        int t = (bid - 11648) * 256 + tid;    // [0,32768)
        int np = t >> 6, k = t & 63;
        int o = (np >> 5) * 16 + (np & 15);
        const float* src = ((np >> 4) & 1) ? gate_m_w : fc_m_w;
        fcgT[t] = __float2bfloat16(src[k * 256 + o]);
    }
}

// ---------------------------------------------------------------------------
// Generic fp32 tiled GEMM (krow only)
// ---------------------------------------------------------------------------
#define GM_BM 64
#define GM_BN 64
#define GM_BK 16

__global__ __launch_bounds__(256) void gemm_nn(
    const float* __restrict__ A, const float* __restrict__ Bm, float* __restrict__ C,
    int M, int N, int K, int lda, int ldb, int ldc,
    long sA, long sB, long sC)
{
    const int z = blockIdx.z;
    A += (long)z * sA; Bm += (long)z * sB; C += (long)z * sC;
    const int m0 = blockIdx.y * GM_BM;
    const int n0 = blockIdx.x * GM_BN;
    const int tid = threadIdx.x;
    const int tx = tid & 15;
    const int ty = tid >> 4;

    __shared__ float As[GM_BK][GM_BM + 4];
    __shared__ float Bs[GM_BK][GM_BN + 4];

    float acc[4][4] = {};

    for (int k0 = 0; k0 < K; k0 += GM_BK) {
#pragma unroll
        for (int i = 0; i < 4; ++i) {
            int idx = tid + i * 256;
            int r = idx >> 4, c = idx & 15;
            As[c][r] = A[(long)(m0 + r) * lda + k0 + c];
        }
#pragma unroll
        for (int i = 0; i < 4; ++i) {
            int idx = tid + i * 256;
            int r = idx >> 6, c = idx & 63;
            Bs[r][c] = Bm[(long)(k0 + r) * ldb + n0 + c];
        }
        __syncthreads();
#pragma unroll
        for (int kk = 0; kk < GM_BK; ++kk) {
            float4 a4 = *(const float4*)&As[kk][ty * 4];
            float4 b4 = *(const float4*)&Bs[kk][tx * 4];
            float av[4] = {a4.x, a4.y, a4.z, a4.w};
            float bv[4] = {b4.x, b4.y, b4.z, b4.w};
#pragma unroll
            for (int i = 0; i < 4; ++i)
#pragma unroll
                for (int j = 0; j < 4; ++j)
                    acc[i][j] += av[i] * bv[j];
        }
        __syncthreads();
    }
#pragma unroll
    for (int i = 0; i < 4; ++i) {
        long m = m0 + ty * 4 + i;
#pragma unroll
        for (int j = 0; j < 4; ++j) {
            int n = n0 + tx * 4 + j;
            C[m * ldc + n] = acc[i][j];
        }
    }
}

// ---------------------------------------------------------------------------
// fp32 GEMM with N-major B: C(MxN) = A(MxK) @ BT(NxK)^T, batched z over BT/C.
// ---------------------------------------------------------------------------
__global__ __launch_bounds__(256) void gemm_nt_f32(
    const float* __restrict__ A, int lda,
    const float* __restrict__ BT, int ldb,
    float* __restrict__ C, int ldc, int K, long sB, long sC)
{
    BT += (long)blockIdx.z * sB;
    C  += (long)blockIdx.z * sC;
    const int m0 = blockIdx.y * 64;
    const int n0 = blockIdx.x * 64;
    const int tid = threadIdx.x;
    const int tx = tid & 15;
    const int ty = tid >> 4;

    __shared__ float As[16][68];
    __shared__ float Bs[64][17];

    float acc[4][4] = {};

    for (int k0 = 0; k0 < K; k0 += 16) {
#pragma unroll
        for (int i = 0; i < 4; ++i) {
            int idx = tid + i * 256;
            int r = idx >> 4, c = idx & 15;
            As[c][r] = A[(long)(m0 + r) * lda + k0 + c];
        }
#pragma unroll
        for (int i = 0; i < 4; ++i) {
            int idx = tid + i * 256;
            int r = idx >> 4, c = idx & 15;
            Bs[r][c] = BT[(long)(n0 + r) * ldb + k0 + c];
        }
        __syncthreads();
#pragma unroll
        for (int kk = 0; kk < 16; ++kk) {
            float4 a4 = *(const float4*)&As[kk][ty * 4];
            float av[4] = {a4.x, a4.y, a4.z, a4.w};
            float bv[4];
#pragma unroll
            for (int j = 0; j < 4; ++j) bv[j] = Bs[tx * 4 + j][kk];
#pragma unroll
            for (int i = 0; i < 4; ++i)
#pragma unroll
                for (int j = 0; j < 4; ++j)
                    acc[i][j] += av[i] * bv[j];
        }
        __syncthreads();
    }
#pragma unroll
    for (int i = 0; i < 4; ++i) {
        long m = m0 + ty * 4 + i;
#pragma unroll
        for (int j = 0; j < 4; ++j) {
            int n = n0 + tx * 4 + j;
            C[m * ldc + n] = acc[i][j];
        }
    }
}

// ---------------------------------------------------------------------------
// Fused s1 / sigmoid / top-k mask + hx->bf16 emit.
// ---------------------------------------------------------------------------
__global__ __launch_bounds__(256) void s1_mask_fused(
    const float* __restrict__ hx,   // (B,2048)
    const float* __restrict__ p,    // (B,2048)  p[b, n*256+i]
    float* __restrict__ a_buf, float* __restrict__ mask_buf,
    __hip_bfloat16* __restrict__ hxb)   // (B,2048) bf16 out
{
    const int wave = threadIdx.x >> 6;
    const int lane = threadIdx.x & 63;
    const long b = (long)blockIdx.x * 4 + wave;
    const long base = b * 2048 + lane * 4;
    float s1v[8];
#pragma unroll
    for (int n = 0; n < 8; ++n) {
        float4 hv = *(const float4*)(hx + base + n * 256);
        float4 pv = *(const float4*)(p + base + n * 256);
        __hip_bfloat16 c0 = __float2bfloat16(hv.x);
        __hip_bfloat16 c1 = __float2bfloat16(hv.y);
        __hip_bfloat16 c2 = __float2bfloat16(hv.z);
        __hip_bfloat16 c3 = __float2bfloat16(hv.w);
        ushort4 u;
        u.x = *(unsigned short*)&c0; u.y = *(unsigned short*)&c1;
        u.z = *(unsigned short*)&c2; u.w = *(unsigned short*)&c3;
        *(ushort4*)(hxb + base + n * 256) = u;
        float s = hv.x * pv.x + hv.y * pv.y + hv.z * pv.z + hv.w * pv.w;
#pragma unroll
        for (int off = 32; off > 0; off >>= 1) s += __shfl_xor(s, off, 64);
        s1v[n] = s * 0.125f;
    }
    unsigned maskbits = 0;
#pragma unroll
    for (int n = 0; n < 8; ++n) {
        int rank = 0;
#pragma unroll
        for (int m = 0; m < 8; ++m) {
            if (m == n) continue;
            if (s1v[m] < s1v[n] || (s1v[m] == s1v[n] && m < n)) rank++;
        }
        if (rank >= 4) maskbits |= (1u << n);
    }
    if (lane < 8) {
        float sv = s1v[0];
#pragma unroll
        for (int n = 1; n < 8; ++n)
            if (lane == n) sv = s1v[n];
        a_buf[b * 8 + lane] = sigmoidf_(sv);
        mask_buf[b * 8 + lane] = ((maskbits >> lane) & 1u) ? 1.0f : 0.0f;
    }
}

// ---------------------------------------------------------------------------
// MFMA GEMM: C(bf16, MxN) = A(bf16, MxK, lda) @ BT(bf16, NxK, ldb)^T
// z-batched with strides sA, sB, sC (element counts).
// ---------------------------------------------------------------------------
__global__ __launch_bounds__(256) void gemm_mfma_obf16(
    const __hip_bfloat16* __restrict__ A, int lda,
    const __hip_bfloat16* __restrict__ BT, int ldb,
    __hip_bfloat16* __restrict__ C, int ldc, int K,
    long sA, long sB, long sC)
{
    A  += (long)blockIdx.z * sA;
    BT += (long)blockIdx.z * sB;
    C  += (long)blockIdx.z * sC;
    const int m0 = blockIdx.y * 128;
    const int n0 = blockIdx.x * 64;
    const int tid = threadIdx.x;
    const int lane = tid & 63, wid = tid >> 6;
    const int wr = wid >> 1, wc = wid & 1;
    const int l15 = lane & 15, l4 = lane >> 4;

    __shared__ __align__(16) char lds_raw[16384 + 8192];
    char* Alds = lds_raw;
    char* Blds = lds_raw + 16384;

    f32x4 acc[4][2] = {};

    for (int k0 = 0; k0 < K; k0 += 64) {
#pragma unroll
        for (int ii = 0; ii < 4; ++ii) {
            int issue = ii * 4 + wid;
            int chunk = issue * 64 + lane;
            int r = chunk >> 3, cs = chunk & 7;
            int cl = cs ^ (r & 7);
            const __hip_bfloat16* g = A + (long)(m0 + r) * lda + k0 + cl * 8;
            GLDS16(g, Alds + issue * 1024);
        }
#pragma unroll
        for (int jj = 0; jj < 2; ++jj) {
            int issue = jj * 4 + wid;
            int chunk = issue * 64 + lane;
            int r = chunk >> 3, cs = chunk & 7;
            int cl = cs ^ (r & 7);
            const __hip_bfloat16* g = BT + (long)(n0 + r) * ldb + k0 + cl * 8;
            GLDS16(g, Blds + issue * 1024);
        }
        __syncthreads();
#pragma unroll
        for (int kk = 0; kk < 2; ++kk) {
            bf16x8 af[4], bfr[2];
#pragma unroll
            for (int im = 0; im < 4; ++im) {
                int r = wr * 64 + im * 16 + l15;
                int cl = (kk * 4 + l4) ^ (l15 & 7);
                af[im] = *(const bf16x8*)(Alds + r * 128 + cl * 16);
            }
#pragma unroll
            for (int jn = 0; jn < 2; ++jn) {
                int r = wc * 32 + jn * 16 + l15;
                int cl = (kk * 4 + l4) ^ (l15 & 7);
                bfr[jn] = *(const bf16x8*)(Blds + r * 128 + cl * 16);
            }
#pragma unroll
            for (int im = 0; im < 4; ++im)
#pragma unroll
                for (int jn = 0; jn < 2; ++jn)
                    acc[im][jn] = __builtin_amdgcn_mfma_f32_16x16x32_bf16(
                        af[im], bfr[jn], acc[im][jn], 0, 0, 0);
        }
        __syncthreads();
    }
#pragma unroll
    for (int im = 0; im < 4; ++im)
#pragma unroll
        for (int reg = 0; reg < 4; ++reg) {
            long m = m0 + wr * 64 + im * 16 + l4 * 4 + reg;
#pragma unroll
            for (int jn = 0; jn < 2; ++jn) {
                int n = n0 + wc * 32 + jn * 16 + l15;
                C[m * ldc + n] = __float2bfloat16(acc[im][jn][reg]);
            }
        }
}

// ---------------------------------------------------------------------------
// Fused q/k/v_m projections (bf16 out).
// ---------------------------------------------------------------------------
__global__ __launch_bounds__(256) void gemm_mfma_qkv(
    const __hip_bfloat16* __restrict__ hnewb,  // (B,2048)
    const __hip_bfloat16* __restrict__ WmT,    // (8,192,256)
    __hip_bfloat16* __restrict__ qout)         // q|k|v, each 2097152 bf16
{
    const int z = blockIdx.z;
    const int m0 = blockIdx.y * 128;
    const int n0 = blockIdx.x * 64;
    const int tid = threadIdx.x;
    const int lane = tid & 63, wid = tid >> 6;
    const int wr = wid >> 1, wc = wid & 1;
    const int l15 = lane & 15, l4 = lane >> 4;

    const __hip_bfloat16* A = hnewb + z * 256;
    const __hip_bfloat16* BT = WmT + (long)z * 192 * 256;

    __shared__ __align__(16) char lds_raw[16384 + 8192];
    char* Alds = lds_raw;
    char* Blds = lds_raw + 16384;

    f32x4 acc[4][2] = {};

    for (int k0 = 0; k0 < 256; k0 += 64) {
#pragma unroll
        for (int ii = 0; ii < 4; ++ii) {
            int issue = ii * 4 + wid;
            int chunk = issue * 64 + lane;
            int r = chunk >> 3, cs = chunk & 7;
            int cl = cs ^ (r & 7);
            const __hip_bfloat16* g = A + (long)(m0 + r) * 2048 + k0 + cl * 8;
            GLDS16(g, Alds + issue * 1024);
        }
#pragma unroll
        for (int jj = 0; jj < 2; ++jj) {
            int issue = jj * 4 + wid;
            int chunk = issue * 64 + lane;
            int r = chunk >> 3, cs = chunk & 7;
            int cl = cs ^ (r & 7);
            const __hip_bfloat16* g = BT + (long)(n0 + r) * 256 + k0 + cl * 8;
            GLDS16(g, Blds + issue * 1024);
        }
        __syncthreads();
#pragma unroll
        for (int kk = 0; kk < 2; ++kk) {
            bf16x8 af[4], bfr[2];
#pragma unroll
            for (int im = 0; im < 4; ++im) {
                int r = wr * 64 + im * 16 + l15;
                int cl = (kk * 4 + l4) ^ (l15 & 7);
                af[im] = *(const bf16x8*)(Alds + r * 128 + cl * 16);
            }
#pragma unroll
            for (int jn = 0; jn < 2; ++jn) {
                int r = wc * 32 + jn * 16 + l15;
                int cl = (kk * 4 + l4) ^ (l15 & 7);
                bfr[jn] = *(const bf16x8*)(Blds + r * 128 + cl * 16);
            }
#pragma unroll
            for (int im = 0; im < 4; ++im)
#pragma unroll
                for (int jn = 0; jn < 2; ++jn)
                    acc[im][jn] = __builtin_amdgcn_mfma_f32_16x16x32_bf16(
                        af[im], bfr[jn], acc[im][jn], 0, 0, 0);
        }
        __syncthreads();
    }
#pragma unroll
    for (int jn = 0; jn < 2; ++jn) {
        int j = n0 + wc * 32 + jn * 16 + l15;   // [0,192)
        int g = j >> 6, d = j & 63;
        __hip_bfloat16* outp = qout + (long)g * 2097152 + (long)z * 64 + d;
#pragma unroll
        for (int im = 0; im < 4; ++im)
#pragma unroll
            for (int reg = 0; reg < 4; ++reg) {
                long m = m0 + wr * 64 + im * 16 + l4 * 4 + reg;
                outp[m * 512] = __float2bfloat16(acc[im][jn][reg]);
            }
    }
}

// ---------------------------------------------------------------------------
// MFMA big GEMM + fused GRU epilogue — R12/R14-verified 2-phase dbuf, hoisted
// addressing; phase-1 now uses the FOLDED weights W2T (K=512): 8+4 K-steps.
// 512 thr / 8 waves, wave 32m x 48n, XCD-pinned kblk = bid&7.
// ---------------------------------------------------------------------------
__global__ __launch_bounds__(512) void gru_fused_mfma(
    const __hip_bfloat16* __restrict__ inpb,   // (B,512)
    const __hip_bfloat16* __restrict__ hxb,    // (B,2048)
    const float* __restrict__ a_buf,           // (B,8)
    const float* __restrict__ cb,              // (8,768)
    const __hip_bfloat16* __restrict__ W2T,    // (8,768,512) folded Wih@WvF^T
    const __hip_bfloat16* __restrict__ Whhb,   // (8,768,256)
    const float* __restrict__ bhh,             // (8,768)
    __hip_bfloat16* __restrict__ hnewb)        // (B,2048)
{
    const int bid = blockIdx.x;
    const int kblk = bid & 7;
    const int r_ = bid >> 3;
    const int ol0 = (r_ & 7) * 32;
    const int m0 = (r_ >> 3) * 128;
    const int tid = threadIdx.x;
    const int lane = tid & 63, wid = tid >> 6;
    const int wr = wid >> 1;
    const int wc = wid & 1;
    const int l15 = lane & 15, l4 = lane >> 4;

    __shared__ __align__(16) char lds_raw[2 * 28672];

    f32x4 accx[2][3] = {};
    f32x4 acch[2][3] = {};

    const __hip_bfloat16* W2 = W2T + (long)kblk * 768 * 512;
    const __hip_bfloat16* Wh = Whhb + (long)kblk * 768 * 256;
    const __hip_bfloat16* hxk = hxb + kblk * 256;

    const int iiA0 = wid, iiA1 = wid + 8;
    const int cA0 = iiA0 * 64 + lane, rA0 = cA0 >> 3, clA0 = (cA0 & 7) ^ (rA0 & 7);
    const int cA1 = iiA1 * 64 + lane, rA1 = cA1 >> 3, clA1 = (cA1 & 7) ^ (rA1 & 7);
    const int jjB0 = wid, jjB1 = wid + 8;
    const int cB0 = jjB0 * 64 + lane, rB0 = cB0 >> 3, clB0 = (cB0 & 7) ^ (rB0 & 7);
    const int cB1 = jjB1 * 64 + lane, rB1 = cB1 >> 3, clB1 = (cB1 & 7) ^ (rB1 & 7);
    const bool hasB1 = (wid < 4);
    const int gg0 = rB0 >> 5, oll0 = rB0 & 31;
    const int gg1 = (rB1 >> 5) & 3, oll1 = rB1 & 31;
    const int dA0 = iiA0 * 1024, dA1 = iiA1 * 1024;
    const int dB0 = 16384 + jjB0 * 1024, dB1 = 16384 + jjB1 * 1024;

    // Phase-1 pointers: A = inpb (lda 512), B = W2T[k] (ld 512)
    const __hip_bfloat16* pA0 = inpb + (long)(m0 + rA0) * 512 + clA0 * 8;
    const __hip_bfloat16* pA1 = inpb + (long)(m0 + rA1) * 512 + clA1 * 8;
    const __hip_bfloat16* pB0 = W2 + (long)(gg0 * 256 + ol0 + oll0) * 512 + clB0 * 8;
    const __hip_bfloat16* pB1 = W2 + (long)(gg1 * 256 + ol0 + oll1) * 512 + clB1 * 8;

#define STAGE4(buf) do {                                                       \
    char* L = lds_raw + (buf) * 28672;                                         \
    GLDS16(pA0, L + dA0);                                                      \
    GLDS16(pA1, L + dA1);                                                      \
    GLDS16(pB0, L + dB0);                                                      \
    if (hasB1) GLDS16(pB1, L + dB1);                                           \
    pA0 += 64; pA1 += 64; pB0 += 64; pB1 += 64;                                \
} while (0)

    int offA[2][2], offB[2][3];
#pragma unroll
    for (int kk = 0; kk < 2; ++kk) {
        int cl = (kk * 4 + l4) ^ (l15 & 7);
#pragma unroll
        for (int im = 0; im < 2; ++im)
            offA[kk][im] = (wr * 32 + im * 16 + l15) * 128 + cl * 16;
#pragma unroll
        for (int g = 0; g < 3; ++g)
            offB[kk][g] = 16384 + (g * 32 + wc * 16 + l15) * 128 + cl * 16;
    }

#define COMPUTE(acc, buf) do {                                                 \
    char* L = lds_raw + (buf) * 28672;                                         \
    _Pragma("unroll") for (int kk = 0; kk < 2; ++kk) {                         \
        bf16x8 af[2], bfr[3];                                                  \
        _Pragma("unroll") for (int im = 0; im < 2; ++im)                       \
            af[im] = *(const bf16x8*)(L + offA[kk][im]);                       \
        _Pragma("unroll") for (int g = 0; g < 3; ++g)                          \
            bfr[g] = *(const bf16x8*)(L + offB[kk][g]);                        \
        _Pragma("unroll") for (int im = 0; im < 2; ++im)                       \
            _Pragma("unroll") for (int g = 0; g < 3; ++g)                      \
                acc[im][g] = __builtin_amdgcn_mfma_f32_16x16x32_bf16(          \
                    af[im], bfr[g], acc[im][g], 0, 0, 0);                      \
    }                                                                          \
} while (0)

    STAGE4(0);
    asm volatile("s_waitcnt vmcnt(0)" ::: "memory");
    __syncthreads();

    int cur = 0;
    // Phase 1: 8 K-steps (gx via folded weights, K=512)
    for (int t = 0; t < 8; ++t) {
        if (t < 7) {
            STAGE4(cur ^ 1);
        } else {
            pA0 = hxk + (long)(m0 + rA0) * 2048 + clA0 * 8;
            pA1 = hxk + (long)(m0 + rA1) * 2048 + clA1 * 8;
            pB0 = Wh + (long)(gg0 * 256 + ol0 + oll0) * 256 + clB0 * 8;
            pB1 = Wh + (long)(gg1 * 256 + ol0 + oll1) * 256 + clB1 * 8;
            STAGE4(cur ^ 1);
        }
        __builtin_amdgcn_s_setprio(1);
        COMPUTE(accx, cur);
        __builtin_amdgcn_s_setprio(0);
        asm volatile("s_waitcnt vmcnt(0)" ::: "memory");
        __syncthreads();
        cur ^= 1;
    }
    // Phase 2: 4 K-steps (gh, K=256)
    for (int t = 0; t < 4; ++t) {
        if (t < 3) STAGE4(cur ^ 1);
        __builtin_amdgcn_s_setprio(1);
        COMPUTE(acch, cur);
        __builtin_amdgcn_s_setprio(0);
        asm volatile("s_waitcnt vmcnt(0)" ::: "memory");
        __syncthreads();
        cur ^= 1;
    }
#undef STAGE4
#undef COMPUTE

    const int ol = ol0 + wc * 16 + l15;
    const float* cbk = cb + kblk * 768;
    const float cb0 = cbk[ol], cb1 = cbk[256 + ol], cb2 = cbk[512 + ol];
    const float* bhk = bhh + kblk * 768;
    const float bh0 = bhk[ol], bh1 = bhk[256 + ol], bh2 = bhk[512 + ol];
#pragma unroll
    for (int im = 0; im < 2; ++im) {
#pragma unroll
        for (int reg = 0; reg < 4; ++reg) {
            long m = m0 + wr * 32 + im * 16 + l4 * 4 + reg;
            float av = a_buf[m * 8 + kblk];
            float gx0 = av * accx[im][0][reg] + cb0;
            float gx1 = av * accx[im][1][reg] + cb1;
            float gx2 = av * accx[im][2][reg] + cb2;
            float gh0 = acch[im][0][reg] + bh0;
            float gh1 = acch[im][1][reg] + bh1;
            float gh2 = acch[im][2][reg] + bh2;
            float rr = sigmoidf_(gx0 + gh0);
            float zz = sigmoidf_(gx1 + gh1);
            float nn = tanhf(gx2 + rr * gh2);
            long idx = m * 2048 + kblk * 256 + ol;
            float hxv = __bfloat162float(hxb[idx]);
            hnewb[idx] = __float2bfloat16((1.f - zz) * nn + zz * hxv);
        }
    }
}

// ---------------------------------------------------------------------------
// Memory attention (bf16 in/out)
// ---------------------------------------------------------------------------
__global__ __launch_bounds__(256) void mattn_kernel(
    const __hip_bfloat16* __restrict__ qm, const __hip_bfloat16* __restrict__ km,
    const __hip_bfloat16* __restrict__ vm, __hip_bfloat16* __restrict__ omb)
{
    const int t = threadIdx.x;
    const int local = t & 31;
    const long b = (long)blockIdx.x * 8 + (t >> 5);
    const int h = local >> 3, qn = local & 7;
    const long base = b * 512 + h * 16;

    float qv[16];
#pragma unroll
    for (int i = 0; i < 2; ++i) {
        bf16x8 v = *(const bf16x8*)(qm + base + qn * 64 + i * 8);
#pragma unroll
        for (int j = 0; j < 8; ++j) qv[i * 8 + j] = (float)v[j];
    }
    float sc[8];
#pragma unroll
    for (int kn = 0; kn < 8; ++kn) {
        float s = 0.f;
#pragma unroll
        for (int i = 0; i < 2; ++i) {
            bf16x8 v = *(const bf16x8*)(km + base + kn * 64 + i * 8);
#pragma unroll
            for (int j = 0; j < 8; ++j) s += qv[i * 8 + j] * (float)v[j];
        }
        sc[kn] = s * 0.25f;
    }
    float mx = sc[0];
#pragma unroll
    for (int kn = 1; kn < 8; ++kn) mx = fmaxf(mx, sc[kn]);
    float ssum = 0.f;
#pragma unroll
    for (int kn = 0; kn < 8; ++kn) { sc[kn] = expf(sc[kn] - mx); ssum += sc[kn]; }
    float inv = 1.f / ssum;

    float acc[16] = {};
#pragma unroll
    for (int kn = 0; kn < 8; ++kn) {
        float w = sc[kn] * inv;
#pragma unroll
        for (int i = 0; i < 2; ++i) {
            bf16x8 v = *(const bf16x8*)(vm + base + kn * 64 + i * 8);
#pragma unroll
            for (int j = 0; j < 8; ++j) acc[i * 8 + j] += w * (float)v[j];
        }
    }
#pragma unroll
    for (int i = 0; i < 2; ++i) {
        bf16x8 o;
#pragma unroll
        for (int j = 0; j < 8; ++j) o[j] = (__bf16)acc[i * 8 + j];
        *(bf16x8*)(omb + base + qn * 64 + i * 8) = o;
    }
}

// ---------------------------------------------------------------------------
// Fused att GEMM + final (R12-verified).
// ---------------------------------------------------------------------------
__global__ __launch_bounds__(256) void att_final(
    const __hip_bfloat16* __restrict__ omb,    // (32768,64)
    const __hip_bfloat16* __restrict__ fcgT,   // (512,64)
    const float* __restrict__ fc_b, const float* __restrict__ gate_b,
    const __hip_bfloat16* __restrict__ hnewb,  // (32768,256)
    const float* __restrict__ maskb,           // (32768)
    const float* __restrict__ hx, const float* __restrict__ cx,
    float* __restrict__ hx_out, float* __restrict__ cx_out,
    float* __restrict__ mask_w)
{
    const int m0 = blockIdx.y * 128;
    const int n0 = blockIdx.x * 64;
    const int tid = threadIdx.x;
    const int lane = tid & 63, wid = tid >> 6;
    const int wr = wid >> 1, wc = wid & 1;
    const int l15 = lane & 15, l4 = lane >> 4;

    __shared__ __align__(16) char lds_raw[16384 + 8192];
    char* Alds = lds_raw;
    char* Blds = lds_raw + 16384;

    f32x4 acc[4][2] = {};
#pragma unroll
    for (int ii = 0; ii < 4; ++ii) {
        int issue = ii * 4 + wid;
        int chunk = issue * 64 + lane;
        int r = chunk >> 3, cs = chunk & 7;
        int cl = cs ^ (r & 7);
        const __hip_bfloat16* g = omb + (long)(m0 + r) * 64 + cl * 8;
        GLDS16(g, Alds + issue * 1024);
    }
#pragma unroll
    for (int jj = 0; jj < 2; ++jj) {
        int issue = jj * 4 + wid;
        int chunk = issue * 64 + lane;
        int r = chunk >> 3, cs = chunk & 7;
        int cl = cs ^ (r & 7);
        const __hip_bfloat16* g = fcgT + (long)(n0 + r) * 64 + cl * 8;
        GLDS16(g, Blds + issue * 1024);
    }
    __syncthreads();
#pragma unroll
    for (int kk = 0; kk < 2; ++kk) {
        bf16x8 af[4], bfr[2];
#pragma unroll
        for (int im = 0; im < 4; ++im) {
            int r = wr * 64 + im * 16 + l15;
            int cl = (kk * 4 + l4) ^ (l15 & 7);
            af[im] = *(const bf16x8*)(Alds + r * 128 + cl * 16);
        }
#pragma unroll
        for (int jn = 0; jn < 2; ++jn) {
            int r = wc * 32 + jn * 16 + l15;
            int cl = (kk * 4 + l4) ^ (l15 & 7);
            bfr[jn] = *(const bf16x8*)(Blds + r * 128 + cl * 16);
        }
#pragma unroll
        for (int im = 0; im < 4; ++im)
#pragma unroll
            for (int jn = 0; jn < 2; ++jn)
                acc[im][jn] = __builtin_amdgcn_mfma_f32_16x16x32_bf16(
                    af[im], bfr[jn], acc[im][jn], 0, 0, 0);
    }
    const int o = ((n0 + wc * 32) >> 1) + l15;
    const float fb = fc_b[o], gb = gate_b[o];
#pragma unroll
    for (int im = 0; im < 4; ++im)
#pragma unroll
        for (int reg = 0; reg < 4; ++reg) {
            long m = m0 + wr * 64 + im * 16 + l4 * 4 + reg;
            long idx = m * 256 + o;
            float mv = maskb[m];
            float att = sigmoidf_(acc[im][1][reg] + gb) * tanhf(acc[im][0][reg] + fb);
            float ho, co;
            if (mv != 0.f) {
                float h2 = __bfloat162float(hnewb[idx]) + att;
                ho = h2; co = h2;
            } else {
                ho = hx[idx]; co = cx[idx];
            }
            hx_out[idx] = ho;
            cx_out[idx] = co;
            mask_w[idx] = mv;
        }
}

// ---------------------------------------------------------------------------
extern "C" void kernel_launch(void* const* d_in, const int* in_sizes, int n_in,
                              void* d_out, int out_size, void* d_ws, size_t ws_size,
                              hipStream_t stream)
{
    const float* inp     = (const float*)d_in[0];
    const float* hx      = (const float*)d_in[1];
    const float* cx      = (const float*)d_in[2];
    const float* Wq_i    = (const float*)d_in[4];
    const float* Wk_i    = (const float*)d_in[5];
    const float* Wv_i    = (const float*)d_in[6];
    const float* fc_i_w  = (const float*)d_in[7];
    const float* fc_i_b  = (const float*)d_in[8];
    const float* Wq_m    = (const float*)d_in[9];
    const float* Wk_m    = (const float*)d_in[10];
    const float* Wv_m    = (const float*)d_in[11];
    const float* fc_m_w  = (const float*)d_in[12];
    const float* fc_m_b  = (const float*)d_in[13];
    const float* gate_m_w= (const float*)d_in[14];
    const float* gate_m_b= (const float*)d_in[15];
    const float* Wih     = (const float*)d_in[16];
    const float* Whh     = (const float*)d_in[17];
    const float* bih     = (const float*)d_in[18];
    const float* bhh     = (const float*)d_in[19];

    float* out = (float*)d_out;
    const long BH = (long)B_SZ * NHID_;   // 8388608
    float* hx_out = out;
    float* cx_out = out + BH;
    float* mask_w = out + 2 * BH;
    __hip_bfloat16* hxb = (__hip_bfloat16*)out;   // bf16 hx in hx_out region (dead after gru)
    __hip_bfloat16* qkvb = (__hip_bfloat16*)out;  // q|k|v bf16, written post-gru
    float* pbuf = cx_out;                         // (B,2048) f32 p, dead before att_final

    // Workspace layout (float offsets; lifetimes verified):
    float* w = (float*)d_ws;
    float* a_buf = w;                                        // [0, 32768)
    float* maskb = w + 32768;                                // [32768, 65536)
    float* cbuf  = w + 65536;                                // [65536, 71680)
    __hip_bfloat16* fcgT = (__hip_bfloat16*)(w + 73728);     // [73728, 90112)
    __hip_bfloat16* WmT  = (__hip_bfloat16*)(w + 90112);     // [90112, 286720)
    // pre-GRU dead pool [286720, 4481024) — reused by hnewb:
    __hip_bfloat16* Wihb = (__hip_bfloat16*)(w + 286720);    // 6291456 bf16 [286720, 3432448); dead after W2 gemm
    __hip_bfloat16* fcT  = (__hip_bfloat16*)(w + 3432448);   // 1048576 bf16 [3432448, 3956736); dead after WvFTt
    __hip_bfloat16* WvB  = (__hip_bfloat16*)(w + 3956736);   // 524288 bf16  [3956736, 4218880); dead after WvFTt
    float* krow = w + 4218880;                               // 262144 f     [4218880, 4481024); dead after p gemm
    __hip_bfloat16* hnewb= (__hip_bfloat16*)(w + 286720);    // 8388608 bf16 [286720, 4481024)  (post-pool overlay)
    // GRU-live buffers (outside the pool):
    __hip_bfloat16* WvFTt= (__hip_bfloat16*)(w + 4481024);   // 524288 bf16  [4481024, 4743168); dead after W2 gemm
    __hip_bfloat16* inpb = (__hip_bfloat16*)(w + 4743168);   // 2097152 bf16 [4743168, 5791744)
    __hip_bfloat16* W2T  = (__hip_bfloat16*)(w + 5791744);   // 3145728 bf16 [5791744, 7364608)
    __hip_bfloat16* Whhb = (__hip_bfloat16*)(w + 7364608);   // 1572864 bf16 [7364608, 8151040)
    // post-GRU overlay (W2T dead):
    __hip_bfloat16* omb  = (__hip_bfloat16*)(w + 5791744);   // 2097152 bf16 [5791744, 6840320)

    // ---- Phase A: merged prep ----
    prep_all<<<dim3(11776), dim3(256), 0, stream>>>(
        Wih, fc_i_b, bih, Wihb, cbuf,
        inp, inpb, Whh, Whhb, Wv_i + 512 * 1024, WvB,
        fc_i_w, fcT, Wq_m, Wk_m, Wv_m, WmT, fc_m_w, gate_m_w, fcgT);
    // ---- Phase B: mask path (fp32) + hxb emit ----
    gemm_nn<<<dim3(1, 64, 1), dim3(256), 0, stream>>>(
        inp, Wk_i + 512 * 64, krow, 4096, 64, 512, 512, 64, 64, 0, 0, 0);
    gemm_nt_f32<<<dim3(4, 64, 8), dim3(256), 0, stream>>>(
        krow, 64, Wq_i, 64, pbuf, 2048, 64, 16384, 256);
    s1_mask_fused<<<dim3(1024), dim3(256), 0, stream>>>(hx, pbuf, a_buf, maskb, hxb);
    // WvFTt(512x1024) = WvB(512x1024) @ fcT(1024x1024)^T  (== (fc@Wv)^T)
    gemm_mfma_obf16<<<dim3(16, 4, 1), dim3(256), 0, stream>>>(
        WvB, 1024, fcT, 1024, WvFTt, 1024, 1024, 0, 0, 0);
    // W2T[k](768x512) = Wihb[k](768x1024) @ WvFTt(512x1024)^T  (folded weights)
    gemm_mfma_obf16<<<dim3(8, 6, 8), dim3(256), 0, stream>>>(
        Wihb, 1024, WvFTt, 1024, W2T, 512, 1024,
        768L * 1024, 0, 768L * 512);
    // ---- Phase C: fused MFMA GEMM + GRU (K=512 folded phase-1) ----
    gru_fused_mfma<<<dim3(2048), dim3(512), 0, stream>>>(
        inpb, hxb, a_buf, cbuf, W2T, Whhb, bhh, hnewb);
    // ---- Phase D: q/k/v_m projections ----
    gemm_mfma_qkv<<<dim3(3, 32, 8), dim3(256), 0, stream>>>(hnewb, WmT, qkvb);
    // ---- Phase E: memory attention + fused att/final ----
    mattn_kernel<<<dim3(512), dim3(256), 0, stream>>>(
        qkvb, qkvb + 2097152, qkvb + 4194304, omb);
    att_final<<<dim3(8, 256, 1), dim3(256), 0, stream>>>(
        omb, fcgT, fc_m_b, gate_m_b, hnewb, maskb, hx, cx, hx_out, cx_out, mask_w);
}

// Round 16
// 229.211 us; speedup vs baseline: 1.2891x; 1.0106x over previous
//
#include <hip/hip_runtime.h>
#include <hip/hip_bf16.h>

#define B_SZ 4096
#define NHID_ 2048

typedef __bf16 bf16x8 __attribute__((ext_vector_type(8)));
typedef float f32x4 __attribute__((ext_vector_type(4)));

__device__ __forceinline__ float sigmoidf_(float x) { return 1.f / (1.f + expf(-x)); }

#define GLDS16(gp, lp) __builtin_amdgcn_global_load_lds( \
    (const __attribute__((address_space(1))) void*)(gp), \
    (__attribute__((address_space(3))) void*)(lp), 16, 0, 0)

// ---------------------------------------------------------------------------
// Merged prep: [0,6144) wih_prep | [6144,10240) f2b3 | [10240,11264) fcT tconv
// | [11264,11648) WmT tconv | [11648,11776) fcg_prep.
// ---------------------------------------------------------------------------
__global__ __launch_bounds__(256) void prep_all(
    const float* __restrict__ Wih, const float* __restrict__ fc_i_b,
    const float* __restrict__ bih, __hip_bfloat16* __restrict__ Wihb,
    float* __restrict__ cb,
    const float* __restrict__ inp, __hip_bfloat16* __restrict__ inpb,
    const float* __restrict__ Whh, __hip_bfloat16* __restrict__ Whhb,
    const float* __restrict__ WvBsrc, __hip_bfloat16* __restrict__ WvB,
    const float* __restrict__ fc_i_w, __hip_bfloat16* __restrict__ fcT,
    const float* __restrict__ Wq_m, const float* __restrict__ Wk_m,
    const float* __restrict__ Wv_m, __hip_bfloat16* __restrict__ WmT,
    const float* __restrict__ fc_m_w, const float* __restrict__ gate_m_w,
    __hip_bfloat16* __restrict__ fcgT)
{
    __shared__ float smem[32 * 33];
    const int bid = blockIdx.x;
    const int tid = threadIdx.x;

    if (bid < 6144) {
        long j = bid;
        const float* row = Wih + j * 1024;
        __hip_bfloat16* drow = Wihb + j * 1024;
        int i = tid * 4;
        float4 v = *(const float4*)(row + i);
        __hip_bfloat16 b0 = __float2bfloat16(v.x);
        __hip_bfloat16 b1 = __float2bfloat16(v.y);
        __hip_bfloat16 b2 = __float2bfloat16(v.z);
        __hip_bfloat16 b3 = __float2bfloat16(v.w);
        ushort4 u;
        u.x = *(unsigned short*)&b0; u.y = *(unsigned short*)&b1;
        u.z = *(unsigned short*)&b2; u.w = *(unsigned short*)&b3;
        *(ushort4*)(drow + i) = u;
        float s = fc_i_b[i] * v.x + fc_i_b[i + 1] * v.y +
                  fc_i_b[i + 2] * v.z + fc_i_b[i + 3] * v.w;
#pragma unroll
        for (int off = 32; off > 0; off >>= 1) s += __shfl_xor(s, off, 64);
        if ((tid & 63) == 0) smem[tid >> 6] = s;
        __syncthreads();
        if (tid == 0) cb[j] = smem[0] + smem[1] + smem[2] + smem[3] + bih[j];
    } else if (bid < 10240) {
        long i = (long)(bid - 6144) * 256 + tid;   // [0, 1048576)
        const float* src; __hip_bfloat16* dst; long off;
        if (i < 524288)       { src = inp;    dst = inpb; off = i; }
        else if (i < 917504)  { src = Whh;    dst = Whhb; off = i - 524288; }
        else                  { src = WvBsrc; dst = WvB;  off = i - 917504; }
        float4 v = ((const float4*)src)[off];
        __hip_bfloat16 b0 = __float2bfloat16(v.x);
        __hip_bfloat16 b1 = __float2bfloat16(v.y);
        __hip_bfloat16 b2 = __float2bfloat16(v.z);
        __hip_bfloat16 b3 = __float2bfloat16(v.w);
        ushort4 u;
        u.x = *(unsigned short*)&b0; u.y = *(unsigned short*)&b1;
        u.z = *(unsigned short*)&b2; u.w = *(unsigned short*)&b3;
        ((ushort4*)dst)[off] = u;
    } else if (bid < 11264) {
        int lb = bid - 10240;                 // [0,1024)
        int r0 = (lb >> 5) * 32, c0 = (lb & 31) * 32;
        int tx = tid & 31, ty = tid >> 5;
        float (*tile)[33] = (float(*)[33])smem;
#pragma unroll
        for (int i = 0; i < 4; ++i)
            tile[ty + i * 8][tx] = fc_i_w[(long)(r0 + ty + i * 8) * 1024 + c0 + tx];
        __syncthreads();
#pragma unroll
        for (int i = 0; i < 4; ++i)
            fcT[(long)(c0 + ty + i * 8) * 1024 + r0 + tx] =
                __float2bfloat16(tile[tx][ty + i * 8]);
    } else if (bid < 11648) {
        int lb = bid - 11264;                 // [0,384)
        int z = lb >> 4, rem = lb & 15;
        int by = rem >> 1, bx = rem & 1;
        int which = z >> 3, nb = z & 7;
        const float* src = (which == 0) ? Wq_m : (which == 1) ? Wk_m : Wv_m;
        src += (long)nb * 16384;
        __hip_bfloat16* dst = WmT + (long)nb * 49152 + which * 64 * 256;
        int r0 = by * 32, c0 = bx * 32;
        int tx = tid & 31, ty = tid >> 5;
        float (*tile)[33] = (float(*)[33])smem;
#pragma unroll
        for (int i = 0; i < 4; ++i)
            tile[ty + i * 8][tx] = src[(long)(r0 + ty + i * 8) * 64 + c0 + tx];
        __syncthreads();
#pragma unroll
        for (int i = 0; i < 4; ++i)
            dst[(long)(c0 + ty + i * 8) * 256 + r0 + tx] =
                __float2bfloat16(tile[tx][ty + i * 8]);
    } else {
        int t = (bid - 11648) * 256 + tid;    // [0,32768)
        int np = t >> 6, k = t & 63;
        int o = (np >> 5) * 16 + (np & 15);
        const float* src = ((np >> 4) & 1) ? gate_m_w : fc_m_w;
        fcgT[t] = __float2bfloat16(src[k * 256 + o]);
    }
}

// ---------------------------------------------------------------------------
// Generic fp32 tiled GEMM (krow + qbuf; z-batched)
// ---------------------------------------------------------------------------
#define GM_BM 64
#define GM_BN 64
#define GM_BK 16

__global__ __launch_bounds__(256) void gemm_nn(
    const float* __restrict__ A, const float* __restrict__ Bm, float* __restrict__ C,
    int M, int N, int K, int lda, int ldb, int ldc,
    long sA, long sB, long sC)
{
    const int z = blockIdx.z;
    A += (long)z * sA; Bm += (long)z * sB; C += (long)z * sC;
    const int m0 = blockIdx.y * GM_BM;
    const int n0 = blockIdx.x * GM_BN;
    const int tid = threadIdx.x;
    const int tx = tid & 15;
    const int ty = tid >> 4;

    __shared__ float As[GM_BK][GM_BM + 4];
    __shared__ float Bs[GM_BK][GM_BN + 4];

    float acc[4][4] = {};

    for (int k0 = 0; k0 < K; k0 += GM_BK) {
#pragma unroll
        for (int i = 0; i < 4; ++i) {
            int idx = tid + i * 256;
            int r = idx >> 4, c = idx & 15;
            As[c][r] = A[(long)(m0 + r) * lda + k0 + c];
        }
#pragma unroll
        for (int i = 0; i < 4; ++i) {
            int idx = tid + i * 256;
            int r = idx >> 6, c = idx & 63;
            Bs[r][c] = Bm[(long)(k0 + r) * ldb + n0 + c];
        }
        __syncthreads();
#pragma unroll
        for (int kk = 0; kk < GM_BK; ++kk) {
            float4 a4 = *(const float4*)&As[kk][ty * 4];
            float4 b4 = *(const float4*)&Bs[kk][tx * 4];
            float av[4] = {a4.x, a4.y, a4.z, a4.w};
            float bv[4] = {b4.x, b4.y, b4.z, b4.w};
#pragma unroll
            for (int i = 0; i < 4; ++i)
#pragma unroll
                for (int j = 0; j < 4; ++j)
                    acc[i][j] += av[i] * bv[j];
        }
        __syncthreads();
    }
#pragma unroll
    for (int i = 0; i < 4; ++i) {
        long m = m0 + ty * 4 + i;
#pragma unroll
        for (int j = 0; j < 4; ++j) {
            int n = n0 + tx * 4 + j;
            C[m * ldc + n] = acc[i][j];
        }
    }
}

// ---------------------------------------------------------------------------
// Fused s1 / sigmoid / top-k mask (q-form, R7-verified numerics) + hxb emit.
// s1[b,n] = (q[b,n,:] . krow[b,:]) / 8.
// ---------------------------------------------------------------------------
__global__ __launch_bounds__(256) void s1_mask_fused(
    const float* __restrict__ hx,    // (B,2048)  (for hxb emit only)
    const float* __restrict__ q,     // (B,8,64) f32
    const float* __restrict__ krow,  // (B,64) f32
    float* __restrict__ a_buf, float* __restrict__ mask_buf,
    __hip_bfloat16* __restrict__ hxb)   // (B,2048) bf16 out
{
    const int wave = threadIdx.x >> 6;
    const int lane = threadIdx.x & 63;
    const long b = (long)blockIdx.x * 4 + wave;
    const long base = b * 2048 + lane * 4;
    const float kr = krow[b * 64 + lane];
    float s1v[8];
#pragma unroll
    for (int n = 0; n < 8; ++n) {
        float4 hv = *(const float4*)(hx + base + n * 256);
        __hip_bfloat16 c0 = __float2bfloat16(hv.x);
        __hip_bfloat16 c1 = __float2bfloat16(hv.y);
        __hip_bfloat16 c2 = __float2bfloat16(hv.z);
        __hip_bfloat16 c3 = __float2bfloat16(hv.w);
        ushort4 u;
        u.x = *(unsigned short*)&c0; u.y = *(unsigned short*)&c1;
        u.z = *(unsigned short*)&c2; u.w = *(unsigned short*)&c3;
        *(ushort4*)(hxb + base + n * 256) = u;
        float p = q[b * 512 + n * 64 + lane] * kr;
#pragma unroll
        for (int off = 32; off > 0; off >>= 1) p += __shfl_xor(p, off, 64);
        s1v[n] = p * 0.125f;
    }
    unsigned maskbits = 0;
#pragma unroll
    for (int n = 0; n < 8; ++n) {
        int rank = 0;
#pragma unroll
        for (int m = 0; m < 8; ++m) {
            if (m == n) continue;
            if (s1v[m] < s1v[n] || (s1v[m] == s1v[n] && m < n)) rank++;
        }
        if (rank >= 4) maskbits |= (1u << n);
    }
    if (lane < 8) {
        float sv = s1v[0];
#pragma unroll
        for (int n = 1; n < 8; ++n)
            if (lane == n) sv = s1v[n];
        a_buf[b * 8 + lane] = sigmoidf_(sv);
        mask_buf[b * 8 + lane] = ((maskbits >> lane) & 1u) ? 1.0f : 0.0f;
    }
}

// ---------------------------------------------------------------------------
// MFMA GEMM: C(bf16, MxN) = A(bf16, MxK, lda) @ BT(bf16, NxK, ldb)^T
// z-batched with strides sA, sB, sC (element counts).
// ---------------------------------------------------------------------------
__global__ __launch_bounds__(256) void gemm_mfma_obf16(
    const __hip_bfloat16* __restrict__ A, int lda,
    const __hip_bfloat16* __restrict__ BT, int ldb,
    __hip_bfloat16* __restrict__ C, int ldc, int K,
    long sA, long sB, long sC)
{
    A  += (long)blockIdx.z * sA;
    BT += (long)blockIdx.z * sB;
    C  += (long)blockIdx.z * sC;
    const int m0 = blockIdx.y * 128;
    const int n0 = blockIdx.x * 64;
    const int tid = threadIdx.x;
    const int lane = tid & 63, wid = tid >> 6;
    const int wr = wid >> 1, wc = wid & 1;
    const int l15 = lane & 15, l4 = lane >> 4;

    __shared__ __align__(16) char lds_raw[16384 + 8192];
    char* Alds = lds_raw;
    char* Blds = lds_raw + 16384;

    f32x4 acc[4][2] = {};

    for (int k0 = 0; k0 < K; k0 += 64) {
#pragma unroll
        for (int ii = 0; ii < 4; ++ii) {
            int issue = ii * 4 + wid;
            int chunk = issue * 64 + lane;
            int r = chunk >> 3, cs = chunk & 7;
            int cl = cs ^ (r & 7);
            const __hip_bfloat16* g = A + (long)(m0 + r) * lda + k0 + cl * 8;
            GLDS16(g, Alds + issue * 1024);
        }
#pragma unroll
        for (int jj = 0; jj < 2; ++jj) {
            int issue = jj * 4 + wid;
            int chunk = issue * 64 + lane;
            int r = chunk >> 3, cs = chunk & 7;
            int cl = cs ^ (r & 7);
            const __hip_bfloat16* g = BT + (long)(n0 + r) * ldb + k0 + cl * 8;
            GLDS16(g, Blds + issue * 1024);
        }
        __syncthreads();
#pragma unroll
        for (int kk = 0; kk < 2; ++kk) {
            bf16x8 af[4], bfr[2];
#pragma unroll
            for (int im = 0; im < 4; ++im) {
                int r = wr * 64 + im * 16 + l15;
                int cl = (kk * 4 + l4) ^ (l15 & 7);
                af[im] = *(const bf16x8*)(Alds + r * 128 + cl * 16);
            }
#pragma unroll
            for (int jn = 0; jn < 2; ++jn) {
                int r = wc * 32 + jn * 16 + l15;
                int cl = (kk * 4 + l4) ^ (l15 & 7);
                bfr[jn] = *(const bf16x8*)(Blds + r * 128 + cl * 16);
            }
#pragma unroll
            for (int im = 0; im < 4; ++im)
#pragma unroll
                for (int jn = 0; jn < 2; ++jn)
                    acc[im][jn] = __builtin_amdgcn_mfma_f32_16x16x32_bf16(
                        af[im], bfr[jn], acc[im][jn], 0, 0, 0);
        }
        __syncthreads();
    }
#pragma unroll
    for (int im = 0; im < 4; ++im)
#pragma unroll
        for (int reg = 0; reg < 4; ++reg) {
            long m = m0 + wr * 64 + im * 16 + l4 * 4 + reg;
#pragma unroll
            for (int jn = 0; jn < 2; ++jn) {
                int n = n0 + wc * 32 + jn * 16 + l15;
                C[m * ldc + n] = __float2bfloat16(acc[im][jn][reg]);
            }
        }
}

// ---------------------------------------------------------------------------
// Fused q/k/v_m projections, widened: one block covers all N=192 cols.
// Block tile 128m x 192n, 4 waves (wave 64m x 96n), K=256.
// ---------------------------------------------------------------------------
__global__ __launch_bounds__(256) void gemm_mfma_qkv(
    const __hip_bfloat16* __restrict__ hnewb,  // (B,2048)
    const __hip_bfloat16* __restrict__ WmT,    // (8,192,256)
    __hip_bfloat16* __restrict__ qout)         // q|k|v, each 2097152 bf16
{
    const int z = blockIdx.z;
    const int m0 = blockIdx.y * 128;
    const int tid = threadIdx.x;
    const int lane = tid & 63, wid = tid >> 6;
    const int wr = wid >> 1, wc = wid & 1;
    const int l15 = lane & 15, l4 = lane >> 4;

    const __hip_bfloat16* A = hnewb + z * 256;
    const __hip_bfloat16* BT = WmT + (long)z * 192 * 256;

    __shared__ __align__(16) char lds_raw[16384 + 24576];
    char* Alds = lds_raw;
    char* Blds = lds_raw + 16384;

    f32x4 acc[4][6] = {};

    for (int k0 = 0; k0 < 256; k0 += 64) {
        for (int ii = wid; ii < 16; ii += 4) {
            int chunk = ii * 64 + lane;
            int r = chunk >> 3, cs = chunk & 7;
            int cl = cs ^ (r & 7);
            const __hip_bfloat16* g = A + (long)(m0 + r) * 2048 + k0 + cl * 8;
            GLDS16(g, Alds + ii * 1024);
        }
        for (int jj = wid; jj < 24; jj += 4) {
            int chunk = jj * 64 + lane;
            int r = chunk >> 3, cs = chunk & 7;
            int cl = cs ^ (r & 7);
            const __hip_bfloat16* g = BT + (long)r * 256 + k0 + cl * 8;
            GLDS16(g, Blds + jj * 1024);
        }
        __syncthreads();
#pragma unroll
        for (int kk = 0; kk < 2; ++kk) {
            int cl = (kk * 4 + l4) ^ (l15 & 7);
            bf16x8 af[4], bfr[6];
#pragma unroll
            for (int im = 0; im < 4; ++im) {
                int r = wr * 64 + im * 16 + l15;
                af[im] = *(const bf16x8*)(Alds + r * 128 + cl * 16);
            }
#pragma unroll
            for (int jn = 0; jn < 6; ++jn) {
                int r = wc * 96 + jn * 16 + l15;
                bfr[jn] = *(const bf16x8*)(Blds + r * 128 + cl * 16);
            }
#pragma unroll
            for (int im = 0; im < 4; ++im)
#pragma unroll
                for (int jn = 0; jn < 6; ++jn)
                    acc[im][jn] = __builtin_amdgcn_mfma_f32_16x16x32_bf16(
                        af[im], bfr[jn], acc[im][jn], 0, 0, 0);
        }
        __syncthreads();
    }
#pragma unroll
    for (int jn = 0; jn < 6; ++jn) {
        int j = wc * 96 + jn * 16 + l15;   // [0,192)
        int g = j >> 6, d = j & 63;
        __hip_bfloat16* outp = qout + (long)g * 2097152 + (long)z * 64 + d;
#pragma unroll
        for (int im = 0; im < 4; ++im)
#pragma unroll
            for (int reg = 0; reg < 4; ++reg) {
                long m = m0 + wr * 64 + im * 16 + l4 * 4 + reg;
                outp[m * 512] = __float2bfloat16(acc[im][jn][reg]);
            }
    }
}

// ---------------------------------------------------------------------------
// MFMA big GEMM + fused GRU epilogue — R15-verified (folded K=512 phase-1).
// ---------------------------------------------------------------------------
__global__ __launch_bounds__(512) void gru_fused_mfma(
    const __hip_bfloat16* __restrict__ inpb,   // (B,512)
    const __hip_bfloat16* __restrict__ hxb,    // (B,2048)
    const float* __restrict__ a_buf,           // (B,8)
    const float* __restrict__ cb,              // (8,768)
    const __hip_bfloat16* __restrict__ W2T,    // (8,768,512) folded Wih@WvF^T
    const __hip_bfloat16* __restrict__ Whhb,   // (8,768,256)
    const float* __restrict__ bhh,             // (8,768)
    __hip_bfloat16* __restrict__ hnewb)        // (B,2048)
{
    const int bid = blockIdx.x;
    const int kblk = bid & 7;
    const int r_ = bid >> 3;
    const int ol0 = (r_ & 7) * 32;
    const int m0 = (r_ >> 3) * 128;
    const int tid = threadIdx.x;
    const int lane = tid & 63, wid = tid >> 6;
    const int wr = wid >> 1;
    const int wc = wid & 1;
    const int l15 = lane & 15, l4 = lane >> 4;

    __shared__ __align__(16) char lds_raw[2 * 28672];

    f32x4 accx[2][3] = {};
    f32x4 acch[2][3] = {};

    const __hip_bfloat16* W2 = W2T + (long)kblk * 768 * 512;
    const __hip_bfloat16* Wh = Whhb + (long)kblk * 768 * 256;
    const __hip_bfloat16* hxk = hxb + kblk * 256;

    const int iiA0 = wid, iiA1 = wid + 8;
    const int cA0 = iiA0 * 64 + lane, rA0 = cA0 >> 3, clA0 = (cA0 & 7) ^ (rA0 & 7);
    const int cA1 = iiA1 * 64 + lane, rA1 = cA1 >> 3, clA1 = (cA1 & 7) ^ (rA1 & 7);
    const int jjB0 = wid, jjB1 = wid + 8;
    const int cB0 = jjB0 * 64 + lane, rB0 = cB0 >> 3, clB0 = (cB0 & 7) ^ (rB0 & 7);
    const int cB1 = jjB1 * 64 + lane, rB1 = cB1 >> 3, clB1 = (cB1 & 7) ^ (rB1 & 7);
    const bool hasB1 = (wid < 4);
    const int gg0 = rB0 >> 5, oll0 = rB0 & 31;
    const int gg1 = (rB1 >> 5) & 3, oll1 = rB1 & 31;
    const int dA0 = iiA0 * 1024, dA1 = iiA1 * 1024;
    const int dB0 = 16384 + jjB0 * 1024, dB1 = 16384 + jjB1 * 1024;

    const __hip_bfloat16* pA0 = inpb + (long)(m0 + rA0) * 512 + clA0 * 8;
    const __hip_bfloat16* pA1 = inpb + (long)(m0 + rA1) * 512 + clA1 * 8;
    const __hip_bfloat16* pB0 = W2 + (long)(gg0 * 256 + ol0 + oll0) * 512 + clB0 * 8;
    const __hip_bfloat16* pB1 = W2 + (long)(gg1 * 256 + ol0 + oll1) * 512 + clB1 * 8;

#define STAGE4(buf) do {                                                       \
    char* L = lds_raw + (buf) * 28672;                                         \
    GLDS16(pA0, L + dA0);                                                      \
    GLDS16(pA1, L + dA1);                                                      \
    GLDS16(pB0, L + dB0);                                                      \
    if (hasB1) GLDS16(pB1, L + dB1);                                           \
    pA0 += 64; pA1 += 64; pB0 += 64; pB1 += 64;                                \
} while (0)

    int offA[2][2], offB[2][3];
#pragma unroll
    for (int kk = 0; kk < 2; ++kk) {
        int cl = (kk * 4 + l4) ^ (l15 & 7);
#pragma unroll
        for (int im = 0; im < 2; ++im)
            offA[kk][im] = (wr * 32 + im * 16 + l15) * 128 + cl * 16;
#pragma unroll
        for (int g = 0; g < 3; ++g)
            offB[kk][g] = 16384 + (g * 32 + wc * 16 + l15) * 128 + cl * 16;
    }

#define COMPUTE(acc, buf) do {                                                 \
    char* L = lds_raw + (buf) * 28672;                                         \
    _Pragma("unroll") for (int kk = 0; kk < 2; ++kk) {                         \
        bf16x8 af[2], bfr[3];                                                  \
        _Pragma("unroll") for (int im = 0; im < 2; ++im)                       \
            af[im] = *(const bf16x8*)(L + offA[kk][im]);                       \
        _Pragma("unroll") for (int g = 0; g < 3; ++g)                          \
            bfr[g] = *(const bf16x8*)(L + offB[kk][g]);                        \
        _Pragma("unroll") for (int im = 0; im < 2; ++im)                       \
            _Pragma("unroll") for (int g = 0; g < 3; ++g)                      \
                acc[im][g] = __builtin_amdgcn_mfma_f32_16x16x32_bf16(          \
                    af[im], bfr[g], acc[im][g], 0, 0, 0);                      \
    }                                                                          \
} while (0)

    STAGE4(0);
    asm volatile("s_waitcnt vmcnt(0)" ::: "memory");
    __syncthreads();

    int cur = 0;
    for (int t = 0; t < 8; ++t) {
        if (t < 7) {
            STAGE4(cur ^ 1);
        } else {
            pA0 = hxk + (long)(m0 + rA0) * 2048 + clA0 * 8;
            pA1 = hxk + (long)(m0 + rA1) * 2048 + clA1 * 8;
            pB0 = Wh + (long)(gg0 * 256 + ol0 + oll0) * 256 + clB0 * 8;
            pB1 = Wh + (long)(gg1 * 256 + ol0 + oll1) * 256 + clB1 * 8;
            STAGE4(cur ^ 1);
        }
        __builtin_amdgcn_s_setprio(1);
        COMPUTE(accx, cur);
        __builtin_amdgcn_s_setprio(0);
        asm volatile("s_waitcnt vmcnt(0)" ::: "memory");
        __syncthreads();
        cur ^= 1;
    }
    for (int t = 0; t < 4; ++t) {
        if (t < 3) STAGE4(cur ^ 1);
        __builtin_amdgcn_s_setprio(1);
        COMPUTE(acch, cur);
        __builtin_amdgcn_s_setprio(0);
        asm volatile("s_waitcnt vmcnt(0)" ::: "memory");
        __syncthreads();
        cur ^= 1;
    }
#undef STAGE4
#undef COMPUTE

    const int ol = ol0 + wc * 16 + l15;
    const float* cbk = cb + kblk * 768;
    const float cb0 = cbk[ol], cb1 = cbk[256 + ol], cb2 = cbk[512 + ol];
    const float* bhk = bhh + kblk * 768;
    const float bh0 = bhk[ol], bh1 = bhk[256 + ol], bh2 = bhk[512 + ol];
#pragma unroll
    for (int im = 0; im < 2; ++im) {
#pragma unroll
        for (int reg = 0; reg < 4; ++reg) {
            long m = m0 + wr * 32 + im * 16 + l4 * 4 + reg;
            float av = a_buf[m * 8 + kblk];
            float gx0 = av * accx[im][0][reg] + cb0;
            float gx1 = av * accx[im][1][reg] + cb1;
            float gx2 = av * accx[im][2][reg] + cb2;
            float gh0 = acch[im][0][reg] + bh0;
            float gh1 = acch[im][1][reg] + bh1;
            float gh2 = acch[im][2][reg] + bh2;
            float rr = sigmoidf_(gx0 + gh0);
            float zz = sigmoidf_(gx1 + gh1);
            float nn = tanhf(gx2 + rr * gh2);
            long idx = m * 2048 + kblk * 256 + ol;
            float hxv = __bfloat162float(hxb[idx]);
            hnewb[idx] = __float2bfloat16((1.f - zz) * nn + zz * hxv);
        }
    }
}

// ---------------------------------------------------------------------------
// Memory attention (bf16 in/out)
// ---------------------------------------------------------------------------
__global__ __launch_bounds__(256) void mattn_kernel(
    const __hip_bfloat16* __restrict__ qm, const __hip_bfloat16* __restrict__ km,
    const __hip_bfloat16* __restrict__ vm, __hip_bfloat16* __restrict__ omb)
{
    const int t = threadIdx.x;
    const int local = t & 31;
    const long b = (long)blockIdx.x * 8 + (t >> 5);
    const int h = local >> 3, qn = local & 7;
    const long base = b * 512 + h * 16;

    float qv[16];
#pragma unroll
    for (int i = 0; i < 2; ++i) {
        bf16x8 v = *(const bf16x8*)(qm + base + qn * 64 + i * 8);
#pragma unroll
        for (int j = 0; j < 8; ++j) qv[i * 8 + j] = (float)v[j];
    }
    float sc[8];
#pragma unroll
    for (int kn = 0; kn < 8; ++kn) {
        float s = 0.f;
#pragma unroll
        for (int i = 0; i < 2; ++i) {
            bf16x8 v = *(const bf16x8*)(km + base + kn * 64 + i * 8);
#pragma unroll
            for (int j = 0; j < 8; ++j) s += qv[i * 8 + j] * (float)v[j];
        }
        sc[kn] = s * 0.25f;
    }
    float mx = sc[0];
#pragma unroll
    for (int kn = 1; kn < 8; ++kn) mx = fmaxf(mx, sc[kn]);
    float ssum = 0.f;
#pragma unroll
    for (int kn = 0; kn < 8; ++kn) { sc[kn] = expf(sc[kn] - mx); ssum += sc[kn]; }
    float inv = 1.f / ssum;

    float acc[16] = {};
#pragma unroll
    for (int kn = 0; kn < 8; ++kn) {
        float w = sc[kn] * inv;
#pragma unroll
        for (int i = 0; i < 2; ++i) {
            bf16x8 v = *(const bf16x8*)(vm + base + kn * 64 + i * 8);
#pragma unroll
            for (int j = 0; j < 8; ++j) acc[i * 8 + j] += w * (float)v[j];
        }
    }
#pragma unroll
    for (int i = 0; i < 2; ++i) {
        bf16x8 o;
#pragma unroll
        for (int j = 0; j < 8; ++j) o[j] = (__bf16)acc[i * 8 + j];
        *(bf16x8*)(omb + base + qn * 64 + i * 8) = o;
    }
}

// ---------------------------------------------------------------------------
// Fused att GEMM + final (R12-verified).
// ---------------------------------------------------------------------------
__global__ __launch_bounds__(256) void att_final(
    const __hip_bfloat16* __restrict__ omb,    // (32768,64)
    const __hip_bfloat16* __restrict__ fcgT,   // (512,64)
    const float* __restrict__ fc_b, const float* __restrict__ gate_b,
    const __hip_bfloat16* __restrict__ hnewb,  // (32768,256)
    const float* __restrict__ maskb,           // (32768)
    const float* __restrict__ hx, const float* __restrict__ cx,
    float* __restrict__ hx_out, float* __restrict__ cx_out,
    float* __restrict__ mask_w)
{
    const int m0 = blockIdx.y * 128;
    const int n0 = blockIdx.x * 64;
    const int tid = threadIdx.x;
    const int lane = tid & 63, wid = tid >> 6;
    const int wr = wid >> 1, wc = wid & 1;
    const int l15 = lane & 15, l4 = lane >> 4;

    __shared__ __align__(16) char lds_raw[16384 + 8192];
    char* Alds = lds_raw;
    char* Blds = lds_raw + 16384;

    f32x4 acc[4][2] = {};
#pragma unroll
    for (int ii = 0; ii < 4; ++ii) {
        int issue = ii * 4 + wid;
        int chunk = issue * 64 + lane;
        int r = chunk >> 3, cs = chunk & 7;
        int cl = cs ^ (r & 7);
        const __hip_bfloat16* g = omb + (long)(m0 + r) * 64 + cl * 8;
        GLDS16(g, Alds + issue * 1024);
    }
#pragma unroll
    for (int jj = 0; jj < 2; ++jj) {
        int issue = jj * 4 + wid;
        int chunk = issue * 64 + lane;
        int r = chunk >> 3, cs = chunk & 7;
        int cl = cs ^ (r & 7);
        const __hip_bfloat16* g = fcgT + (long)(n0 + r) * 64 + cl * 8;
        GLDS16(g, Blds + issue * 1024);
    }
    __syncthreads();
#pragma unroll
    for (int kk = 0; kk < 2; ++kk) {
        bf16x8 af[4], bfr[2];
#pragma unroll
        for (int im = 0; im < 4; ++im) {
            int r = wr * 64 + im * 16 + l15;
            int cl = (kk * 4 + l4) ^ (l15 & 7);
            af[im] = *(const bf16x8*)(Alds + r * 128 + cl * 16);
        }
#pragma unroll
        for (int jn = 0; jn < 2; ++jn) {
            int r = wc * 32 + jn * 16 + l15;
            int cl = (kk * 4 + l4) ^ (l15 & 7);
            bfr[jn] = *(const bf16x8*)(Blds + r * 128 + cl * 16);
        }
#pragma unroll
        for (int im = 0; im < 4; ++im)
#pragma unroll
            for (int jn = 0; jn < 2; ++jn)
                acc[im][jn] = __builtin_amdgcn_mfma_f32_16x16x32_bf16(
                    af[im], bfr[jn], acc[im][jn], 0, 0, 0);
    }
    const int o = ((n0 + wc * 32) >> 1) + l15;
    const float fb = fc_b[o], gb = gate_b[o];
#pragma unroll
    for (int im = 0; im < 4; ++im)
#pragma unroll
        for (int reg = 0; reg < 4; ++reg) {
            long m = m0 + wr * 64 + im * 16 + l4 * 4 + reg;
            long idx = m * 256 + o;
            float mv = maskb[m];
            float att = sigmoidf_(acc[im][1][reg] + gb) * tanhf(acc[im][0][reg] + fb);
            float ho, co;
            if (mv != 0.f) {
                float h2 = __bfloat162float(hnewb[idx]) + att;
                ho = h2; co = h2;
            } else {
                ho = hx[idx]; co = cx[idx];
            }
            hx_out[idx] = ho;
            cx_out[idx] = co;
            mask_w[idx] = mv;
        }
}

// ---------------------------------------------------------------------------
extern "C" void kernel_launch(void* const* d_in, const int* in_sizes, int n_in,
                              void* d_out, int out_size, void* d_ws, size_t ws_size,
                              hipStream_t stream)
{
    const float* inp     = (const float*)d_in[0];
    const float* hx      = (const float*)d_in[1];
    const float* cx      = (const float*)d_in[2];
    const float* Wq_i    = (const float*)d_in[4];
    const float* Wk_i    = (const float*)d_in[5];
    const float* Wv_i    = (const float*)d_in[6];
    const float* fc_i_w  = (const float*)d_in[7];
    const float* fc_i_b  = (const float*)d_in[8];
    const float* Wq_m    = (const float*)d_in[9];
    const float* Wk_m    = (const float*)d_in[10];
    const float* Wv_m    = (const float*)d_in[11];
    const float* fc_m_w  = (const float*)d_in[12];
    const float* fc_m_b  = (const float*)d_in[13];
    const float* gate_m_w= (const float*)d_in[14];
    const float* gate_m_b= (const float*)d_in[15];
    const float* Wih     = (const float*)d_in[16];
    const float* Whh     = (const float*)d_in[17];
    const float* bih     = (const float*)d_in[18];
    const float* bhh     = (const float*)d_in[19];

    float* out = (float*)d_out;
    const long BH = (long)B_SZ * NHID_;   // 8388608
    float* hx_out = out;
    float* cx_out = out + BH;
    float* mask_w = out + 2 * BH;
    __hip_bfloat16* hxb = (__hip_bfloat16*)out;   // bf16 hx in hx_out region (dead after gru)
    __hip_bfloat16* qkvb = (__hip_bfloat16*)out;  // q|k|v bf16, written post-gru
    float* qbuf = cx_out;                         // (B,8,64) f32 q, dead before att_final

    // Workspace layout (float offsets; lifetimes verified):
    float* w = (float*)d_ws;
    float* a_buf = w;                                        // [0, 32768)
    float* maskb = w + 32768;                                // [32768, 65536)
    float* cbuf  = w + 65536;                                // [65536, 71680)
    __hip_bfloat16* fcgT = (__hip_bfloat16*)(w + 73728);     // [73728, 90112)
    __hip_bfloat16* WmT  = (__hip_bfloat16*)(w + 90112);     // [90112, 286720)
    // pre-GRU dead pool [286720, 4481024) — reused by hnewb:
    __hip_bfloat16* Wihb = (__hip_bfloat16*)(w + 286720);    // [286720, 3432448); dead after W2 gemm
    __hip_bfloat16* fcT  = (__hip_bfloat16*)(w + 3432448);   // [3432448, 3956736); dead after WvFTt
    __hip_bfloat16* WvB  = (__hip_bfloat16*)(w + 3956736);   // [3956736, 4218880); dead after WvFTt
    float* krow = w + 4218880;                               // [4218880, 4481024); dead after s1_mask
    __hip_bfloat16* hnewb= (__hip_bfloat16*)(w + 286720);    // [286720, 4481024)  (post-pool overlay)
    // GRU-live buffers (outside the pool):
    __hip_bfloat16* WvFTt= (__hip_bfloat16*)(w + 4481024);   // [4481024, 4743168); dead after W2 gemm
    __hip_bfloat16* inpb = (__hip_bfloat16*)(w + 4743168);   // [4743168, 5791744)
    __hip_bfloat16* W2T  = (__hip_bfloat16*)(w + 5791744);   // [5791744, 7364608)
    __hip_bfloat16* Whhb = (__hip_bfloat16*)(w + 7364608);   // [7364608, 8151040)
    // post-GRU overlay (W2T dead):
    __hip_bfloat16* omb  = (__hip_bfloat16*)(w + 5791744);   // [5791744, 6840320)

    // ---- Phase A: merged prep ----
    prep_all<<<dim3(11776), dim3(256), 0, stream>>>(
        Wih, fc_i_b, bih, Wihb, cbuf,
        inp, inpb, Whh, Whhb, Wv_i + 512 * 1024, WvB,
        fc_i_w, fcT, Wq_m, Wk_m, Wv_m, WmT, fc_m_w, gate_m_w, fcgT);
    // ---- Phase B: mask path (fp32, q-form) + hxb emit ----
    gemm_nn<<<dim3(1, 64, 1), dim3(256), 0, stream>>>(
        inp, Wk_i + 512 * 64, krow, 4096, 64, 512, 512, 64, 64, 0, 0, 0);
    gemm_nn<<<dim3(1, 64, 8), dim3(256), 0, stream>>>(
        hx, Wq_i, qbuf, 4096, 64, 256, 2048, 64, 512, 256, 16384, 64);
    s1_mask_fused<<<dim3(1024), dim3(256), 0, stream>>>(
        hx, qbuf, krow, a_buf, maskb, hxb);
    // WvFTt(512x1024) = WvB(512x1024) @ fcT(1024x1024)^T
    gemm_mfma_obf16<<<dim3(16, 4, 1), dim3(256), 0, stream>>>(
        WvB, 1024, fcT, 1024, WvFTt, 1024, 1024, 0, 0, 0);
    // W2T[k](768x512) = Wihb[k](768x1024) @ WvFTt(512x1024)^T
    gemm_mfma_obf16<<<dim3(8, 6, 8), dim3(256), 0, stream>>>(
        Wihb, 1024, WvFTt, 1024, W2T, 512, 1024,
        768L * 1024, 0, 768L * 512);
    // ---- Phase C: fused MFMA GEMM + GRU (K=512 folded phase-1) ----
    gru_fused_mfma<<<dim3(2048), dim3(512), 0, stream>>>(
        inpb, hxb, a_buf, cbuf, W2T, Whhb, bhh, hnewb);
    // ---- Phase D: q/k/v_m projections (widened, N=192/block) ----
    gemm_mfma_qkv<<<dim3(1, 32, 8), dim3(256), 0, stream>>>(hnewb, WmT, qkvb);
    // ---- Phase E: memory attention + fused att/final ----
    mattn_kernel<<<dim3(512), dim3(256), 0, stream>>>(
        qkvb, qkvb + 2097152, qkvb + 4194304, omb);
    att_final<<<dim3(8, 256, 1), dim3(256), 0, stream>>>(
        omb, fcgT, fc_m_b, gate_m_b, hnewb, maskb, hx, cx, hx_out, cx_out, mask_w);
}

// Round 17
// 228.950 us; speedup vs baseline: 1.2906x; 1.0011x over previous
//
#include <hip/hip_runtime.h>
#include <hip/hip_bf16.h>

#define B_SZ 4096
#define NHID_ 2048

typedef __bf16 bf16x8 __attribute__((ext_vector_type(8)));
typedef float f32x4 __attribute__((ext_vector_type(4)));

__device__ __forceinline__ float sigmoidf_(float x) { return 1.f / (1.f + expf(-x)); }
__device__ __forceinline__ float b2f_(unsigned short u) {
    unsigned v = (unsigned)u << 16;
    return __builtin_bit_cast(float, v);
}

#define GLDS16(gp, lp) __builtin_amdgcn_global_load_lds( \
    (const __attribute__((address_space(1))) void*)(gp), \
    (__attribute__((address_space(3))) void*)(lp), 16, 0, 0)

// ---------------------------------------------------------------------------
// Merged prep: [0,6144) wih_prep | [6144,10240) f2b3 | [10240,11264) fcT tconv
// | [11264,11648) WmT tconv | [11648,11776) fcg_prep.
// ---------------------------------------------------------------------------
__global__ __launch_bounds__(256) void prep_all(
    const float* __restrict__ Wih, const float* __restrict__ fc_i_b,
    const float* __restrict__ bih, __hip_bfloat16* __restrict__ Wihb,
    float* __restrict__ cb,
    const float* __restrict__ inp, __hip_bfloat16* __restrict__ inpb,
    const float* __restrict__ Whh, __hip_bfloat16* __restrict__ Whhb,
    const float* __restrict__ WvBsrc, __hip_bfloat16* __restrict__ WvB,
    const float* __restrict__ fc_i_w, __hip_bfloat16* __restrict__ fcT,
    const float* __restrict__ Wq_m, const float* __restrict__ Wk_m,
    const float* __restrict__ Wv_m, __hip_bfloat16* __restrict__ WmT,
    const float* __restrict__ fc_m_w, const float* __restrict__ gate_m_w,
    __hip_bfloat16* __restrict__ fcgT)
{
    __shared__ float smem[32 * 33];
    const int bid = blockIdx.x;
    const int tid = threadIdx.x;

    if (bid < 6144) {
        long j = bid;
        const float* row = Wih + j * 1024;
        __hip_bfloat16* drow = Wihb + j * 1024;
        int i = tid * 4;
        float4 v = *(const float4*)(row + i);
        __hip_bfloat16 b0 = __float2bfloat16(v.x);
        __hip_bfloat16 b1 = __float2bfloat16(v.y);
        __hip_bfloat16 b2 = __float2bfloat16(v.z);
        __hip_bfloat16 b3 = __float2bfloat16(v.w);
        ushort4 u;
        u.x = *(unsigned short*)&b0; u.y = *(unsigned short*)&b1;
        u.z = *(unsigned short*)&b2; u.w = *(unsigned short*)&b3;
        *(ushort4*)(drow + i) = u;
        float s = fc_i_b[i] * v.x + fc_i_b[i + 1] * v.y +
                  fc_i_b[i + 2] * v.z + fc_i_b[i + 3] * v.w;
#pragma unroll
        for (int off = 32; off > 0; off >>= 1) s += __shfl_xor(s, off, 64);
        if ((tid & 63) == 0) smem[tid >> 6] = s;
        __syncthreads();
        if (tid == 0) cb[j] = smem[0] + smem[1] + smem[2] + smem[3] + bih[j];
    } else if (bid < 10240) {
        long i = (long)(bid - 6144) * 256 + tid;   // [0, 1048576)
        const float* src; __hip_bfloat16* dst; long off;
        if (i < 524288)       { src = inp;    dst = inpb; off = i; }
        else if (i < 917504)  { src = Whh;    dst = Whhb; off = i - 524288; }
        else                  { src = WvBsrc; dst = WvB;  off = i - 917504; }
        float4 v = ((const float4*)src)[off];
        __hip_bfloat16 b0 = __float2bfloat16(v.x);
        __hip_bfloat16 b1 = __float2bfloat16(v.y);
        __hip_bfloat16 b2 = __float2bfloat16(v.z);
        __hip_bfloat16 b3 = __float2bfloat16(v.w);
        ushort4 u;
        u.x = *(unsigned short*)&b0; u.y = *(unsigned short*)&b1;
        u.z = *(unsigned short*)&b2; u.w = *(unsigned short*)&b3;
        ((ushort4*)dst)[off] = u;
    } else if (bid < 11264) {
        int lb = bid - 10240;                 // [0,1024)
        int r0 = (lb >> 5) * 32, c0 = (lb & 31) * 32;
        int tx = tid & 31, ty = tid >> 5;
        float (*tile)[33] = (float(*)[33])smem;
#pragma unroll
        for (int i = 0; i < 4; ++i)
            tile[ty + i * 8][tx] = fc_i_w[(long)(r0 + ty + i * 8) * 1024 + c0 + tx];
        __syncthreads();
#pragma unroll
        for (int i = 0; i < 4; ++i)
            fcT[(long)(c0 + ty + i * 8) * 1024 + r0 + tx] =
                __float2bfloat16(tile[tx][ty + i * 8]);
    } else if (bid < 11648) {
        int lb = bid - 11264;                 // [0,384)
        int z = lb >> 4, rem = lb & 15;
        int by = rem >> 1, bx = rem & 1;
        int which = z >> 3, nb = z & 7;
        const float* src = (which == 0) ? Wq_m : (which == 1) ? Wk_m : Wv_m;
        src += (long)nb * 16384;
        __hip_bfloat16* dst = WmT + (long)nb * 49152 + which * 64 * 256;
        int r0 = by * 32, c0 = bx * 32;
        int tx = tid & 31, ty = tid >> 5;
        float (*tile)[33] = (float(*)[33])smem;
#pragma unroll
        for (int i = 0; i < 4; ++i)
            tile[ty + i * 8][tx] = src[(long)(r0 + ty + i * 8) * 64 + c0 + tx];
        __syncthreads();
#pragma unroll
        for (int i = 0; i < 4; ++i)
            dst[(long)(c0 + ty + i * 8) * 256 + r0 + tx] =
                __float2bfloat16(tile[tx][ty + i * 8]);
    } else {
        int t = (bid - 11648) * 256 + tid;    // [0,32768)
        int np = t >> 6, k = t & 63;
        int o = (np >> 5) * 16 + (np & 15);
        const float* src = ((np >> 4) & 1) ? gate_m_w : fc_m_w;
        fcgT[t] = __float2bfloat16(src[k * 256 + o]);
    }
}

// ---------------------------------------------------------------------------
// Generic fp32 tiled GEMM (krow + qbuf; z-batched)
// ---------------------------------------------------------------------------
#define GM_BM 64
#define GM_BN 64
#define GM_BK 16

__global__ __launch_bounds__(256) void gemm_nn(
    const float* __restrict__ A, const float* __restrict__ Bm, float* __restrict__ C,
    int M, int N, int K, int lda, int ldb, int ldc,
    long sA, long sB, long sC)
{
    const int z = blockIdx.z;
    A += (long)z * sA; Bm += (long)z * sB; C += (long)z * sC;
    const int m0 = blockIdx.y * GM_BM;
    const int n0 = blockIdx.x * GM_BN;
    const int tid = threadIdx.x;
    const int tx = tid & 15;
    const int ty = tid >> 4;

    __shared__ float As[GM_BK][GM_BM + 4];
    __shared__ float Bs[GM_BK][GM_BN + 4];

    float acc[4][4] = {};

    for (int k0 = 0; k0 < K; k0 += GM_BK) {
#pragma unroll
        for (int i = 0; i < 4; ++i) {
            int idx = tid + i * 256;
            int r = idx >> 4, c = idx & 15;
            As[c][r] = A[(long)(m0 + r) * lda + k0 + c];
        }
#pragma unroll
        for (int i = 0; i < 4; ++i) {
            int idx = tid + i * 256;
            int r = idx >> 6, c = idx & 63;
            Bs[r][c] = Bm[(long)(k0 + r) * ldb + n0 + c];
        }
        __syncthreads();
#pragma unroll
        for (int kk = 0; kk < GM_BK; ++kk) {
            float4 a4 = *(const float4*)&As[kk][ty * 4];
            float4 b4 = *(const float4*)&Bs[kk][tx * 4];
            float av[4] = {a4.x, a4.y, a4.z, a4.w};
            float bv[4] = {b4.x, b4.y, b4.z, b4.w};
#pragma unroll
            for (int i = 0; i < 4; ++i)
#pragma unroll
                for (int j = 0; j < 4; ++j)
                    acc[i][j] += av[i] * bv[j];
        }
        __syncthreads();
    }
#pragma unroll
    for (int i = 0; i < 4; ++i) {
        long m = m0 + ty * 4 + i;
#pragma unroll
        for (int j = 0; j < 4; ++j) {
            int n = n0 + tx * 4 + j;
            C[m * ldc + n] = acc[i][j];
        }
    }
}

// ---------------------------------------------------------------------------
// Fused s1 / sigmoid / top-k mask (q-form, R7-verified numerics) + hxb emit.
// ---------------------------------------------------------------------------
__global__ __launch_bounds__(256) void s1_mask_fused(
    const float* __restrict__ hx,    // (B,2048)  (for hxb emit only)
    const float* __restrict__ q,     // (B,8,64) f32
    const float* __restrict__ krow,  // (B,64) f32
    float* __restrict__ a_buf, float* __restrict__ mask_buf,
    __hip_bfloat16* __restrict__ hxb)   // (B,2048) bf16 out
{
    const int wave = threadIdx.x >> 6;
    const int lane = threadIdx.x & 63;
    const long b = (long)blockIdx.x * 4 + wave;
    const long base = b * 2048 + lane * 4;
    const float kr = krow[b * 64 + lane];
    float s1v[8];
#pragma unroll
    for (int n = 0; n < 8; ++n) {
        float4 hv = *(const float4*)(hx + base + n * 256);
        __hip_bfloat16 c0 = __float2bfloat16(hv.x);
        __hip_bfloat16 c1 = __float2bfloat16(hv.y);
        __hip_bfloat16 c2 = __float2bfloat16(hv.z);
        __hip_bfloat16 c3 = __float2bfloat16(hv.w);
        ushort4 u;
        u.x = *(unsigned short*)&c0; u.y = *(unsigned short*)&c1;
        u.z = *(unsigned short*)&c2; u.w = *(unsigned short*)&c3;
        *(ushort4*)(hxb + base + n * 256) = u;
        float p = q[b * 512 + n * 64 + lane] * kr;
#pragma unroll
        for (int off = 32; off > 0; off >>= 1) p += __shfl_xor(p, off, 64);
        s1v[n] = p * 0.125f;
    }
    unsigned maskbits = 0;
#pragma unroll
    for (int n = 0; n < 8; ++n) {
        int rank = 0;
#pragma unroll
        for (int m = 0; m < 8; ++m) {
            if (m == n) continue;
            if (s1v[m] < s1v[n] || (s1v[m] == s1v[n] && m < n)) rank++;
        }
        if (rank >= 4) maskbits |= (1u << n);
    }
    if (lane < 8) {
        float sv = s1v[0];
#pragma unroll
        for (int n = 1; n < 8; ++n)
            if (lane == n) sv = s1v[n];
        a_buf[b * 8 + lane] = sigmoidf_(sv);
        mask_buf[b * 8 + lane] = ((maskbits >> lane) & 1u) ? 1.0f : 0.0f;
    }
}

// ---------------------------------------------------------------------------
// MFMA GEMM: C(bf16, MxN) = A(bf16, MxK, lda) @ BT(bf16, NxK, ldb)^T
// z-batched with strides sA, sB, sC (element counts).
// ---------------------------------------------------------------------------
__global__ __launch_bounds__(256) void gemm_mfma_obf16(
    const __hip_bfloat16* __restrict__ A, int lda,
    const __hip_bfloat16* __restrict__ BT, int ldb,
    __hip_bfloat16* __restrict__ C, int ldc, int K,
    long sA, long sB, long sC)
{
    A  += (long)blockIdx.z * sA;
    BT += (long)blockIdx.z * sB;
    C  += (long)blockIdx.z * sC;
    const int m0 = blockIdx.y * 128;
    const int n0 = blockIdx.x * 64;
    const int tid = threadIdx.x;
    const int lane = tid & 63, wid = tid >> 6;
    const int wr = wid >> 1, wc = wid & 1;
    const int l15 = lane & 15, l4 = lane >> 4;

    __shared__ __align__(16) char lds_raw[16384 + 8192];
    char* Alds = lds_raw;
    char* Blds = lds_raw + 16384;

    f32x4 acc[4][2] = {};

    for (int k0 = 0; k0 < K; k0 += 64) {
#pragma unroll
        for (int ii = 0; ii < 4; ++ii) {
            int issue = ii * 4 + wid;
            int chunk = issue * 64 + lane;
            int r = chunk >> 3, cs = chunk & 7;
            int cl = cs ^ (r & 7);
            const __hip_bfloat16* g = A + (long)(m0 + r) * lda + k0 + cl * 8;
            GLDS16(g, Alds + issue * 1024);
        }
#pragma unroll
        for (int jj = 0; jj < 2; ++jj) {
            int issue = jj * 4 + wid;
            int chunk = issue * 64 + lane;
            int r = chunk >> 3, cs = chunk & 7;
            int cl = cs ^ (r & 7);
            const __hip_bfloat16* g = BT + (long)(n0 + r) * ldb + k0 + cl * 8;
            GLDS16(g, Blds + issue * 1024);
        }
        __syncthreads();
#pragma unroll
        for (int kk = 0; kk < 2; ++kk) {
            bf16x8 af[4], bfr[2];
#pragma unroll
            for (int im = 0; im < 4; ++im) {
                int r = wr * 64 + im * 16 + l15;
                int cl = (kk * 4 + l4) ^ (l15 & 7);
                af[im] = *(const bf16x8*)(Alds + r * 128 + cl * 16);
            }
#pragma unroll
            for (int jn = 0; jn < 2; ++jn) {
                int r = wc * 32 + jn * 16 + l15;
                int cl = (kk * 4 + l4) ^ (l15 & 7);
                bfr[jn] = *(const bf16x8*)(Blds + r * 128 + cl * 16);
            }
#pragma unroll
            for (int im = 0; im < 4; ++im)
#pragma unroll
                for (int jn = 0; jn < 2; ++jn)
                    acc[im][jn] = __builtin_amdgcn_mfma_f32_16x16x32_bf16(
                        af[im], bfr[jn], acc[im][jn], 0, 0, 0);
        }
        __syncthreads();
    }
#pragma unroll
    for (int im = 0; im < 4; ++im)
#pragma unroll
        for (int reg = 0; reg < 4; ++reg) {
            long m = m0 + wr * 64 + im * 16 + l4 * 4 + reg;
#pragma unroll
            for (int jn = 0; jn < 2; ++jn) {
                int n = n0 + wc * 32 + jn * 16 + l15;
                C[m * ldc + n] = __float2bfloat16(acc[im][jn][reg]);
            }
        }
}

// ---------------------------------------------------------------------------
// Fused q/k/v_m projections, widened: one block covers all N=192 cols.
// ---------------------------------------------------------------------------
__global__ __launch_bounds__(256) void gemm_mfma_qkv(
    const __hip_bfloat16* __restrict__ hnewb,  // (B,2048)
    const __hip_bfloat16* __restrict__ WmT,    // (8,192,256)
    __hip_bfloat16* __restrict__ qout)         // q|k|v, each 2097152 bf16
{
    const int z = blockIdx.z;
    const int m0 = blockIdx.y * 128;
    const int tid = threadIdx.x;
    const int lane = tid & 63, wid = tid >> 6;
    const int wr = wid >> 1, wc = wid & 1;
    const int l15 = lane & 15, l4 = lane >> 4;

    const __hip_bfloat16* A = hnewb + z * 256;
    const __hip_bfloat16* BT = WmT + (long)z * 192 * 256;

    __shared__ __align__(16) char lds_raw[16384 + 24576];
    char* Alds = lds_raw;
    char* Blds = lds_raw + 16384;

    f32x4 acc[4][6] = {};

    for (int k0 = 0; k0 < 256; k0 += 64) {
        for (int ii = wid; ii < 16; ii += 4) {
            int chunk = ii * 64 + lane;
            int r = chunk >> 3, cs = chunk & 7;
            int cl = cs ^ (r & 7);
            const __hip_bfloat16* g = A + (long)(m0 + r) * 2048 + k0 + cl * 8;
            GLDS16(g, Alds + ii * 1024);
        }
        for (int jj = wid; jj < 24; jj += 4) {
            int chunk = jj * 64 + lane;
            int r = chunk >> 3, cs = chunk & 7;
            int cl = cs ^ (r & 7);
            const __hip_bfloat16* g = BT + (long)r * 256 + k0 + cl * 8;
            GLDS16(g, Blds + jj * 1024);
        }
        __syncthreads();
#pragma unroll
        for (int kk = 0; kk < 2; ++kk) {
            int cl = (kk * 4 + l4) ^ (l15 & 7);
            bf16x8 af[4], bfr[6];
#pragma unroll
            for (int im = 0; im < 4; ++im) {
                int r = wr * 64 + im * 16 + l15;
                af[im] = *(const bf16x8*)(Alds + r * 128 + cl * 16);
            }
#pragma unroll
            for (int jn = 0; jn < 6; ++jn) {
                int r = wc * 96 + jn * 16 + l15;
                bfr[jn] = *(const bf16x8*)(Blds + r * 128 + cl * 16);
            }
#pragma unroll
            for (int im = 0; im < 4; ++im)
#pragma unroll
                for (int jn = 0; jn < 6; ++jn)
                    acc[im][jn] = __builtin_amdgcn_mfma_f32_16x16x32_bf16(
                        af[im], bfr[jn], acc[im][jn], 0, 0, 0);
        }
        __syncthreads();
    }
#pragma unroll
    for (int jn = 0; jn < 6; ++jn) {
        int j = wc * 96 + jn * 16 + l15;   // [0,192)
        int g = j >> 6, d = j & 63;
        __hip_bfloat16* outp = qout + (long)g * 2097152 + (long)z * 64 + d;
#pragma unroll
        for (int im = 0; im < 4; ++im)
#pragma unroll
            for (int reg = 0; reg < 4; ++reg) {
                long m = m0 + wr * 64 + im * 16 + l4 * 4 + reg;
                outp[m * 512] = __float2bfloat16(acc[im][jn][reg]);
            }
    }
}

// ---------------------------------------------------------------------------
// MFMA big GEMM + fused GRU epilogue — R15-verified (folded K=512 phase-1).
// ---------------------------------------------------------------------------
__global__ __launch_bounds__(512) void gru_fused_mfma(
    const __hip_bfloat16* __restrict__ inpb,   // (B,512)
    const __hip_bfloat16* __restrict__ hxb,    // (B,2048)
    const float* __restrict__ a_buf,           // (B,8)
    const float* __restrict__ cb,              // (8,768)
    const __hip_bfloat16* __restrict__ W2T,    // (8,768,512) folded Wih@WvF^T
    const __hip_bfloat16* __restrict__ Whhb,   // (8,768,256)
    const float* __restrict__ bhh,             // (8,768)
    __hip_bfloat16* __restrict__ hnewb)        // (B,2048)
{
    const int bid = blockIdx.x;
    const int kblk = bid & 7;
    const int r_ = bid >> 3;
    const int ol0 = (r_ & 7) * 32;
    const int m0 = (r_ >> 3) * 128;
    const int tid = threadIdx.x;
    const int lane = tid & 63, wid = tid >> 6;
    const int wr = wid >> 1;
    const int wc = wid & 1;
    const int l15 = lane & 15, l4 = lane >> 4;

    __shared__ __align__(16) char lds_raw[2 * 28672];

    f32x4 accx[2][3] = {};
    f32x4 acch[2][3] = {};

    const __hip_bfloat16* W2 = W2T + (long)kblk * 768 * 512;
    const __hip_bfloat16* Wh = Whhb + (long)kblk * 768 * 256;
    const __hip_bfloat16* hxk = hxb + kblk * 256;

    const int iiA0 = wid, iiA1 = wid + 8;
    const int cA0 = iiA0 * 64 + lane, rA0 = cA0 >> 3, clA0 = (cA0 & 7) ^ (rA0 & 7);
    const int cA1 = iiA1 * 64 + lane, rA1 = cA1 >> 3, clA1 = (cA1 & 7) ^ (rA1 & 7);
    const int jjB0 = wid, jjB1 = wid + 8;
    const int cB0 = jjB0 * 64 + lane, rB0 = cB0 >> 3, clB0 = (cB0 & 7) ^ (rB0 & 7);
    const int cB1 = jjB1 * 64 + lane, rB1 = cB1 >> 3, clB1 = (cB1 & 7) ^ (rB1 & 7);
    const bool hasB1 = (wid < 4);
    const int gg0 = rB0 >> 5, oll0 = rB0 & 31;
    const int gg1 = (rB1 >> 5) & 3, oll1 = rB1 & 31;
    const int dA0 = iiA0 * 1024, dA1 = iiA1 * 1024;
    const int dB0 = 16384 + jjB0 * 1024, dB1 = 16384 + jjB1 * 1024;

    const __hip_bfloat16* pA0 = inpb + (long)(m0 + rA0) * 512 + clA0 * 8;
    const __hip_bfloat16* pA1 = inpb + (long)(m0 + rA1) * 512 + clA1 * 8;
    const __hip_bfloat16* pB0 = W2 + (long)(gg0 * 256 + ol0 + oll0) * 512 + clB0 * 8;
    const __hip_bfloat16* pB1 = W2 + (long)(gg1 * 256 + ol0 + oll1) * 512 + clB1 * 8;

#define STAGE4(buf) do {                                                       \
    char* L = lds_raw + (buf) * 28672;                                         \
    GLDS16(pA0, L + dA0);                                                      \
    GLDS16(pA1, L + dA1);                                                      \
    GLDS16(pB0, L + dB0);                                                      \
    if (hasB1) GLDS16(pB1, L + dB1);                                           \
    pA0 += 64; pA1 += 64; pB0 += 64; pB1 += 64;                                \
} while (0)

    int offA[2][2], offB[2][3];
#pragma unroll
    for (int kk = 0; kk < 2; ++kk) {
        int cl = (kk * 4 + l4) ^ (l15 & 7);
#pragma unroll
        for (int im = 0; im < 2; ++im)
            offA[kk][im] = (wr * 32 + im * 16 + l15) * 128 + cl * 16;
#pragma unroll
        for (int g = 0; g < 3; ++g)
            offB[kk][g] = 16384 + (g * 32 + wc * 16 + l15) * 128 + cl * 16;
    }

#define COMPUTE(acc, buf) do {                                                 \
    char* L = lds_raw + (buf) * 28672;                                         \
    _Pragma("unroll") for (int kk = 0; kk < 2; ++kk) {                         \
        bf16x8 af[2], bfr[3];                                                  \
        _Pragma("unroll") for (int im = 0; im < 2; ++im)                       \
            af[im] = *(const bf16x8*)(L + offA[kk][im]);                       \
        _Pragma("unroll") for (int g = 0; g < 3; ++g)                          \
            bfr[g] = *(const bf16x8*)(L + offB[kk][g]);                        \
        _Pragma("unroll") for (int im = 0; im < 2; ++im)                       \
            _Pragma("unroll") for (int g = 0; g < 3; ++g)                      \
                acc[im][g] = __builtin_amdgcn_mfma_f32_16x16x32_bf16(          \
                    af[im], bfr[g], acc[im][g], 0, 0, 0);                      \
    }                                                                          \
} while (0)

    STAGE4(0);
    asm volatile("s_waitcnt vmcnt(0)" ::: "memory");
    __syncthreads();

    int cur = 0;
    for (int t = 0; t < 8; ++t) {
        if (t < 7) {
            STAGE4(cur ^ 1);
        } else {
            pA0 = hxk + (long)(m0 + rA0) * 2048 + clA0 * 8;
            pA1 = hxk + (long)(m0 + rA1) * 2048 + clA1 * 8;
            pB0 = Wh + (long)(gg0 * 256 + ol0 + oll0) * 256 + clB0 * 8;
            pB1 = Wh + (long)(gg1 * 256 + ol0 + oll1) * 256 + clB1 * 8;
            STAGE4(cur ^ 1);
        }
        __builtin_amdgcn_s_setprio(1);
        COMPUTE(accx, cur);
        __builtin_amdgcn_s_setprio(0);
        asm volatile("s_waitcnt vmcnt(0)" ::: "memory");
        __syncthreads();
        cur ^= 1;
    }
    for (int t = 0; t < 4; ++t) {
        if (t < 3) STAGE4(cur ^ 1);
        __builtin_amdgcn_s_setprio(1);
        COMPUTE(acch, cur);
        __builtin_amdgcn_s_setprio(0);
        asm volatile("s_waitcnt vmcnt(0)" ::: "memory");
        __syncthreads();
        cur ^= 1;
    }
#undef STAGE4
#undef COMPUTE

    const int ol = ol0 + wc * 16 + l15;
    const float* cbk = cb + kblk * 768;
    const float cb0 = cbk[ol], cb1 = cbk[256 + ol], cb2 = cbk[512 + ol];
    const float* bhk = bhh + kblk * 768;
    const float bh0 = bhk[ol], bh1 = bhk[256 + ol], bh2 = bhk[512 + ol];
#pragma unroll
    for (int im = 0; im < 2; ++im) {
#pragma unroll
        for (int reg = 0; reg < 4; ++reg) {
            long m = m0 + wr * 32 + im * 16 + l4 * 4 + reg;
            float av = a_buf[m * 8 + kblk];
            float gx0 = av * accx[im][0][reg] + cb0;
            float gx1 = av * accx[im][1][reg] + cb1;
            float gx2 = av * accx[im][2][reg] + cb2;
            float gh0 = acch[im][0][reg] + bh0;
            float gh1 = acch[im][1][reg] + bh1;
            float gh2 = acch[im][2][reg] + bh2;
            float rr = sigmoidf_(gx0 + gh0);
            float zz = sigmoidf_(gx1 + gh1);
            float nn = tanhf(gx2 + rr * gh2);
            long idx = m * 2048 + kblk * 256 + ol;
            float hxv = __bfloat162float(hxb[idx]);
            hnewb[idx] = __float2bfloat16((1.f - zz) * nn + zz * hxv);
        }
    }
}

// ---------------------------------------------------------------------------
// Memory attention (bf16 in/out)
// ---------------------------------------------------------------------------
__global__ __launch_bounds__(256) void mattn_kernel(
    const __hip_bfloat16* __restrict__ qm, const __hip_bfloat16* __restrict__ km,
    const __hip_bfloat16* __restrict__ vm, __hip_bfloat16* __restrict__ omb)
{
    const int t = threadIdx.x;
    const int local = t & 31;
    const long b = (long)blockIdx.x * 8 + (t >> 5);
    const int h = local >> 3, qn = local & 7;
    const long base = b * 512 + h * 16;

    float qv[16];
#pragma unroll
    for (int i = 0; i < 2; ++i) {
        bf16x8 v = *(const bf16x8*)(qm + base + qn * 64 + i * 8);
#pragma unroll
        for (int j = 0; j < 8; ++j) qv[i * 8 + j] = (float)v[j];
    }
    float sc[8];
#pragma unroll
    for (int kn = 0; kn < 8; ++kn) {
        float s = 0.f;
#pragma unroll
        for (int i = 0; i < 2; ++i) {
            bf16x8 v = *(const bf16x8*)(km + base + kn * 64 + i * 8);
#pragma unroll
            for (int j = 0; j < 8; ++j) s += qv[i * 8 + j] * (float)v[j];
        }
        sc[kn] = s * 0.25f;
    }
    float mx = sc[0];
#pragma unroll
    for (int kn = 1; kn < 8; ++kn) mx = fmaxf(mx, sc[kn]);
    float ssum = 0.f;
#pragma unroll
    for (int kn = 0; kn < 8; ++kn) { sc[kn] = expf(sc[kn] - mx); ssum += sc[kn]; }
    float inv = 1.f / ssum;

    float acc[16] = {};
#pragma unroll
    for (int kn = 0; kn < 8; ++kn) {
        float w = sc[kn] * inv;
#pragma unroll
        for (int i = 0; i < 2; ++i) {
            bf16x8 v = *(const bf16x8*)(vm + base + kn * 64 + i * 8);
#pragma unroll
            for (int j = 0; j < 8; ++j) acc[i * 8 + j] += w * (float)v[j];
        }
    }
#pragma unroll
    for (int i = 0; i < 2; ++i) {
        bf16x8 o;
#pragma unroll
        for (int j = 0; j < 8; ++j) o[j] = (__bf16)acc[i * 8 + j];
        *(bf16x8*)(omb + base + qn * 64 + i * 8) = o;
    }
}

// ---------------------------------------------------------------------------
// Fused att GEMM + final — LDS-staged epilogue for coalesced float4 output.
// Block output tile: rows [m0, m0+128) x o-cols [o0, o0+32).
// ---------------------------------------------------------------------------
__global__ __launch_bounds__(256) void att_final(
    const __hip_bfloat16* __restrict__ omb,    // (32768,64)
    const __hip_bfloat16* __restrict__ fcgT,   // (512,64)
    const float* __restrict__ fc_b, const float* __restrict__ gate_b,
    const __hip_bfloat16* __restrict__ hnewb,  // (32768,256)
    const float* __restrict__ maskb,           // (32768)
    const float* __restrict__ hx, const float* __restrict__ cx,
    float* __restrict__ hx_out, float* __restrict__ cx_out,
    float* __restrict__ mask_w)
{
    const int m0 = blockIdx.y * 128;
    const int n0 = blockIdx.x * 64;
    const int tid = threadIdx.x;
    const int lane = tid & 63, wid = tid >> 6;
    const int wr = wid >> 1, wc = wid & 1;
    const int l15 = lane & 15, l4 = lane >> 4;

    __shared__ __align__(16) char lds_raw[16384 + 8192];
    char* Alds = lds_raw;
    char* Blds = lds_raw + 16384;
    float* att_t = (float*)lds_raw;            // 128x32 f32 tile (16KB), reused after MFMA

    f32x4 acc[4][2] = {};
#pragma unroll
    for (int ii = 0; ii < 4; ++ii) {
        int issue = ii * 4 + wid;
        int chunk = issue * 64 + lane;
        int r = chunk >> 3, cs = chunk & 7;
        int cl = cs ^ (r & 7);
        const __hip_bfloat16* g = omb + (long)(m0 + r) * 64 + cl * 8;
        GLDS16(g, Alds + issue * 1024);
    }
#pragma unroll
    for (int jj = 0; jj < 2; ++jj) {
        int issue = jj * 4 + wid;
        int chunk = issue * 64 + lane;
        int r = chunk >> 3, cs = chunk & 7;
        int cl = cs ^ (r & 7);
        const __hip_bfloat16* g = fcgT + (long)(n0 + r) * 64 + cl * 8;
        GLDS16(g, Blds + issue * 1024);
    }
    __syncthreads();
#pragma unroll
    for (int kk = 0; kk < 2; ++kk) {
        bf16x8 af[4], bfr[2];
#pragma unroll
        for (int im = 0; im < 4; ++im) {
            int r = wr * 64 + im * 16 + l15;
            int cl = (kk * 4 + l4) ^ (l15 & 7);
            af[im] = *(const bf16x8*)(Alds + r * 128 + cl * 16);
        }
#pragma unroll
        for (int jn = 0; jn < 2; ++jn) {
            int r = wc * 32 + jn * 16 + l15;
            int cl = (kk * 4 + l4) ^ (l15 & 7);
            bfr[jn] = *(const bf16x8*)(Blds + r * 128 + cl * 16);
        }
#pragma unroll
        for (int im = 0; im < 4; ++im)
#pragma unroll
            for (int jn = 0; jn < 2; ++jn)
                acc[im][jn] = __builtin_amdgcn_mfma_f32_16x16x32_bf16(
                    af[im], bfr[jn], acc[im][jn], 0, 0, 0);
    }
    // Stage att values into LDS [128][32] (f32), after all LDS reads are done.
    __syncthreads();
    {
        const int o_l = wc * 16 + l15;     // local o in [0,32)
        const float fb = fc_b[(n0 >> 1) + o_l], gb = gate_b[(n0 >> 1) + o_l];
#pragma unroll
        for (int im = 0; im < 4; ++im)
#pragma unroll
            for (int reg = 0; reg < 4; ++reg) {
                int ml = wr * 64 + im * 16 + l4 * 4 + reg;
                float att = sigmoidf_(acc[im][1][reg] + gb) * tanhf(acc[im][0][reg] + fb);
                att_t[ml * 32 + o_l] = att;
            }
    }
    __syncthreads();
    // Coalesced output pass: thread -> (row, col4); float4 everywhere.
    const int o0 = n0 >> 1;
#pragma unroll
    for (int it = 0; it < 4; ++it) {
        int idx = it * 256 + tid;          // [0,1024)
        int rl = idx >> 3, c4 = idx & 7;   // row local, float4-col
        long m = m0 + rl;
        float mv = maskb[m];
        float4 av = *(const float4*)&att_t[rl * 32 + c4 * 4];
        long gidx = m * 256 + o0 + c4 * 4;
        ushort4 hn = *(const ushort4*)(hnewb + gidx);
        float4 hxv = *(const float4*)(hx + gidx);
        float4 cxv = *(const float4*)(cx + gidx);
        bool k = (mv != 0.f);
        float4 ho, co;
        float h0 = b2f_(hn.x) + av.x, h1 = b2f_(hn.y) + av.y;
        float h2 = b2f_(hn.z) + av.z, h3 = b2f_(hn.w) + av.w;
        ho.x = k ? h0 : hxv.x; ho.y = k ? h1 : hxv.y;
        ho.z = k ? h2 : hxv.z; ho.w = k ? h3 : hxv.w;
        co.x = k ? h0 : cxv.x; co.y = k ? h1 : cxv.y;
        co.z = k ? h2 : cxv.z; co.w = k ? h3 : cxv.w;
        *(float4*)(hx_out + gidx) = ho;
        *(float4*)(cx_out + gidx) = co;
        *(float4*)(mask_w + gidx) = make_float4(mv, mv, mv, mv);
    }
}

// ---------------------------------------------------------------------------
extern "C" void kernel_launch(void* const* d_in, const int* in_sizes, int n_in,
                              void* d_out, int out_size, void* d_ws, size_t ws_size,
                              hipStream_t stream)
{
    const float* inp     = (const float*)d_in[0];
    const float* hx      = (const float*)d_in[1];
    const float* cx      = (const float*)d_in[2];
    const float* Wq_i    = (const float*)d_in[4];
    const float* Wk_i    = (const float*)d_in[5];
    const float* Wv_i    = (const float*)d_in[6];
    const float* fc_i_w  = (const float*)d_in[7];
    const float* fc_i_b  = (const float*)d_in[8];
    const float* Wq_m    = (const float*)d_in[9];
    const float* Wk_m    = (const float*)d_in[10];
    const float* Wv_m    = (const float*)d_in[11];
    const float* fc_m_w  = (const float*)d_in[12];
    const float* fc_m_b  = (const float*)d_in[13];
    const float* gate_m_w= (const float*)d_in[14];
    const float* gate_m_b= (const float*)d_in[15];
    const float* Wih     = (const float*)d_in[16];
    const float* Whh     = (const float*)d_in[17];
    const float* bih     = (const float*)d_in[18];
    const float* bhh     = (const float*)d_in[19];

    float* out = (float*)d_out;
    const long BH = (long)B_SZ * NHID_;   // 8388608
    float* hx_out = out;
    float* cx_out = out + BH;
    float* mask_w = out + 2 * BH;
    __hip_bfloat16* hxb = (__hip_bfloat16*)out;   // bf16 hx in hx_out region (dead after gru)
    __hip_bfloat16* qkvb = (__hip_bfloat16*)out;  // q|k|v bf16, written post-gru
    float* qbuf = cx_out;                         // (B,8,64) f32 q, dead before att_final

    // Workspace layout (float offsets; lifetimes verified):
    float* w = (float*)d_ws;
    float* a_buf = w;                                        // [0, 32768)
    float* maskb = w + 32768;                                // [32768, 65536)
    float* cbuf  = w + 65536;                                // [65536, 71680)
    __hip_bfloat16* fcgT = (__hip_bfloat16*)(w + 73728);     // [73728, 90112)
    __hip_bfloat16* WmT  = (__hip_bfloat16*)(w + 90112);     // [90112, 286720)
    // pre-GRU dead pool [286720, 4481024) — reused by hnewb:
    __hip_bfloat16* Wihb = (__hip_bfloat16*)(w + 286720);    // [286720, 3432448); dead after W2 gemm
    __hip_bfloat16* fcT  = (__hip_bfloat16*)(w + 3432448);   // [3432448, 3956736); dead after WvFTt
    __hip_bfloat16* WvB  = (__hip_bfloat16*)(w + 3956736);   // [3956736, 4218880); dead after WvFTt
    float* krow = w + 4218880;                               // [4218880, 4481024); dead after s1_mask
    __hip_bfloat16* hnewb= (__hip_bfloat16*)(w + 286720);    // [286720, 4481024)  (post-pool overlay)
    // GRU-live buffers (outside the pool):
    __hip_bfloat16* WvFTt= (__hip_bfloat16*)(w + 4481024);   // [4481024, 4743168); dead after W2 gemm
    __hip_bfloat16* inpb = (__hip_bfloat16*)(w + 4743168);   // [4743168, 5791744)
    __hip_bfloat16* W2T  = (__hip_bfloat16*)(w + 5791744);   // [5791744, 7364608)
    __hip_bfloat16* Whhb = (__hip_bfloat16*)(w + 7364608);   // [7364608, 8151040)
    // post-GRU overlay (W2T dead):
    __hip_bfloat16* omb  = (__hip_bfloat16*)(w + 5791744);   // [5791744, 6840320)

    // ---- Phase A: merged prep ----
    prep_all<<<dim3(11776), dim3(256), 0, stream>>>(
        Wih, fc_i_b, bih, Wihb, cbuf,
        inp, inpb, Whh, Whhb, Wv_i + 512 * 1024, WvB,
        fc_i_w, fcT, Wq_m, Wk_m, Wv_m, WmT, fc_m_w, gate_m_w, fcgT);
    // ---- Phase B: mask path (fp32, q-form) + hxb emit ----
    gemm_nn<<<dim3(1, 64, 1), dim3(256), 0, stream>>>(
        inp, Wk_i + 512 * 64, krow, 4096, 64, 512, 512, 64, 64, 0, 0, 0);
    gemm_nn<<<dim3(1, 64, 8), dim3(256), 0, stream>>>(
        hx, Wq_i, qbuf, 4096, 64, 256, 2048, 64, 512, 256, 16384, 64);
    s1_mask_fused<<<dim3(1024), dim3(256), 0, stream>>>(
        hx, qbuf, krow, a_buf, maskb, hxb);
    // WvFTt(512x1024) = WvB(512x1024) @ fcT(1024x1024)^T
    gemm_mfma_obf16<<<dim3(16, 4, 1), dim3(256), 0, stream>>>(
        WvB, 1024, fcT, 1024, WvFTt, 1024, 1024, 0, 0, 0);
    // W2T[k](768x512) = Wihb[k](768x1024) @ WvFTt(512x1024)^T
    gemm_mfma_obf16<<<dim3(8, 6, 8), dim3(256), 0, stream>>>(
        Wihb, 1024, WvFTt, 1024, W2T, 512, 1024,
        768L * 1024, 0, 768L * 512);
    // ---- Phase C: fused MFMA GEMM + GRU (K=512 folded phase-1) ----
    gru_fused_mfma<<<dim3(2048), dim3(512), 0, stream>>>(
        inpb, hxb, a_buf, cbuf, W2T, Whhb, bhh, hnewb);
    // ---- Phase D: q/k/v_m projections (widened, N=192/block) ----
    gemm_mfma_qkv<<<dim3(1, 32, 8), dim3(256), 0, stream>>>(hnewb, WmT, qkvb);
    // ---- Phase E: memory attention + fused att/final (coalesced epilogue) ----
    mattn_kernel<<<dim3(512), dim3(256), 0, stream>>>(
        qkvb, qkvb + 2097152, qkvb + 4194304, omb);
    att_final<<<dim3(8, 256, 1), dim3(256), 0, stream>>>(
        omb, fcgT, fc_m_b, gate_m_b, hnewb, maskb, hx, cx, hx_out, cx_out, mask_w);
}

// Round 18
// 224.166 us; speedup vs baseline: 1.3181x; 1.0213x over previous
//
#include <hip/hip_runtime.h>
#include <hip/hip_bf16.h>

#define B_SZ 4096
#define NHID_ 2048

typedef __bf16 bf16x8 __attribute__((ext_vector_type(8)));
typedef float f32x4 __attribute__((ext_vector_type(4)));

__device__ __forceinline__ float sigmoidf_(float x) { return 1.f / (1.f + expf(-x)); }
__device__ __forceinline__ float b2f_(unsigned short u) {
    unsigned v = (unsigned)u << 16;
    return __builtin_bit_cast(float, v);
}

#define GLDS16(gp, lp) __builtin_amdgcn_global_load_lds( \
    (const __attribute__((address_space(1))) void*)(gp), \
    (__attribute__((address_space(3))) void*)(lp), 16, 0, 0)

// ---------------------------------------------------------------------------
// Merged prep: [0,6144) wih_prep | [6144,10240) f2b3 | [10240,11264) fcT tconv
// | [11264,11648) WmT tconv | [11648,11776) fcg_prep.
// ---------------------------------------------------------------------------
__global__ __launch_bounds__(256) void prep_all(
    const float* __restrict__ Wih, const float* __restrict__ fc_i_b,
    const float* __restrict__ bih, __hip_bfloat16* __restrict__ Wihb,
    float* __restrict__ cb,
    const float* __restrict__ inp, __hip_bfloat16* __restrict__ inpb,
    const float* __restrict__ Whh, __hip_bfloat16* __restrict__ Whhb,
    const float* __restrict__ WvBsrc, __hip_bfloat16* __restrict__ WvB,
    const float* __restrict__ fc_i_w, __hip_bfloat16* __restrict__ fcT,
    const float* __restrict__ Wq_m, const float* __restrict__ Wk_m,
    const float* __restrict__ Wv_m, __hip_bfloat16* __restrict__ WmT,
    const float* __restrict__ fc_m_w, const float* __restrict__ gate_m_w,
    __hip_bfloat16* __restrict__ fcgT)
{
    __shared__ float smem[32 * 33];
    const int bid = blockIdx.x;
    const int tid = threadIdx.x;

    if (bid < 6144) {
        long j = bid;
        const float* row = Wih + j * 1024;
        __hip_bfloat16* drow = Wihb + j * 1024;
        int i = tid * 4;
        float4 v = *(const float4*)(row + i);
        __hip_bfloat16 b0 = __float2bfloat16(v.x);
        __hip_bfloat16 b1 = __float2bfloat16(v.y);
        __hip_bfloat16 b2 = __float2bfloat16(v.z);
        __hip_bfloat16 b3 = __float2bfloat16(v.w);
        ushort4 u;
        u.x = *(unsigned short*)&b0; u.y = *(unsigned short*)&b1;
        u.z = *(unsigned short*)&b2; u.w = *(unsigned short*)&b3;
        *(ushort4*)(drow + i) = u;
        float s = fc_i_b[i] * v.x + fc_i_b[i + 1] * v.y +
                  fc_i_b[i + 2] * v.z + fc_i_b[i + 3] * v.w;
#pragma unroll
        for (int off = 32; off > 0; off >>= 1) s += __shfl_xor(s, off, 64);
        if ((tid & 63) == 0) smem[tid >> 6] = s;
        __syncthreads();
        if (tid == 0) cb[j] = smem[0] + smem[1] + smem[2] + smem[3] + bih[j];
    } else if (bid < 10240) {
        long i = (long)(bid - 6144) * 256 + tid;   // [0, 1048576)
        const float* src; __hip_bfloat16* dst; long off;
        if (i < 524288)       { src = inp;    dst = inpb; off = i; }
        else if (i < 917504)  { src = Whh;    dst = Whhb; off = i - 524288; }
        else                  { src = WvBsrc; dst = WvB;  off = i - 917504; }
        float4 v = ((const float4*)src)[off];
        __hip_bfloat16 b0 = __float2bfloat16(v.x);
        __hip_bfloat16 b1 = __float2bfloat16(v.y);
        __hip_bfloat16 b2 = __float2bfloat16(v.z);
        __hip_bfloat16 b3 = __float2bfloat16(v.w);
        ushort4 u;
        u.x = *(unsigned short*)&b0; u.y = *(unsigned short*)&b1;
        u.z = *(unsigned short*)&b2; u.w = *(unsigned short*)&b3;
        ((ushort4*)dst)[off] = u;
    } else if (bid < 11264) {
        int lb = bid - 10240;                 // [0,1024)
        int r0 = (lb >> 5) * 32, c0 = (lb & 31) * 32;
        int tx = tid & 31, ty = tid >> 5;
        float (*tile)[33] = (float(*)[33])smem;
#pragma unroll
        for (int i = 0; i < 4; ++i)
            tile[ty + i * 8][tx] = fc_i_w[(long)(r0 + ty + i * 8) * 1024 + c0 + tx];
        __syncthreads();
#pragma unroll
        for (int i = 0; i < 4; ++i)
            fcT[(long)(c0 + ty + i * 8) * 1024 + r0 + tx] =
                __float2bfloat16(tile[tx][ty + i * 8]);
    } else if (bid < 11648) {
        int lb = bid - 11264;                 // [0,384)
        int z = lb >> 4, rem = lb & 15;
        int by = rem >> 1, bx = rem & 1;
        int which = z >> 3, nb = z & 7;
        const float* src = (which == 0) ? Wq_m : (which == 1) ? Wk_m : Wv_m;
        src += (long)nb * 16384;
        __hip_bfloat16* dst = WmT + (long)nb * 49152 + which * 64 * 256;
        int r0 = by * 32, c0 = bx * 32;
        int tx = tid & 31, ty = tid >> 5;
        float (*tile)[33] = (float(*)[33])smem;
#pragma unroll
        for (int i = 0; i < 4; ++i)
            tile[ty + i * 8][tx] = src[(long)(r0 + ty + i * 8) * 64 + c0 + tx];
        __syncthreads();
#pragma unroll
        for (int i = 0; i < 4; ++i)
            dst[(long)(c0 + ty + i * 8) * 256 + r0 + tx] =
                __float2bfloat16(tile[tx][ty + i * 8]);
    } else {
        int t = (bid - 11648) * 256 + tid;    // [0,32768)
        int np = t >> 6, k = t & 63;
        int o = (np >> 5) * 16 + (np & 15);
        const float* src = ((np >> 4) & 1) ? gate_m_w : fc_m_w;
        fcgT[t] = __float2bfloat16(src[k * 256 + o]);
    }
}

// ---------------------------------------------------------------------------
// Generic fp32 tiled GEMM (krow + qbuf; z-batched)
// ---------------------------------------------------------------------------
#define GM_BM 64
#define GM_BN 64
#define GM_BK 16

__global__ __launch_bounds__(256) void gemm_nn(
    const float* __restrict__ A, const float* __restrict__ Bm, float* __restrict__ C,
    int M, int N, int K, int lda, int ldb, int ldc,
    long sA, long sB, long sC)
{
    const int z = blockIdx.z;
    A += (long)z * sA; Bm += (long)z * sB; C += (long)z * sC;
    const int m0 = blockIdx.y * GM_BM;
    const int n0 = blockIdx.x * GM_BN;
    const int tid = threadIdx.x;
    const int tx = tid & 15;
    const int ty = tid >> 4;

    __shared__ float As[GM_BK][GM_BM + 4];
    __shared__ float Bs[GM_BK][GM_BN + 4];

    float acc[4][4] = {};

    for (int k0 = 0; k0 < K; k0 += GM_BK) {
#pragma unroll
        for (int i = 0; i < 4; ++i) {
            int idx = tid + i * 256;
            int r = idx >> 4, c = idx & 15;
            As[c][r] = A[(long)(m0 + r) * lda + k0 + c];
        }
#pragma unroll
        for (int i = 0; i < 4; ++i) {
            int idx = tid + i * 256;
            int r = idx >> 6, c = idx & 63;
            Bs[r][c] = Bm[(long)(k0 + r) * ldb + n0 + c];
        }
        __syncthreads();
#pragma unroll
        for (int kk = 0; kk < GM_BK; ++kk) {
            float4 a4 = *(const float4*)&As[kk][ty * 4];
            float4 b4 = *(const float4*)&Bs[kk][tx * 4];
            float av[4] = {a4.x, a4.y, a4.z, a4.w};
            float bv[4] = {b4.x, b4.y, b4.z, b4.w};
#pragma unroll
            for (int i = 0; i < 4; ++i)
#pragma unroll
                for (int j = 0; j < 4; ++j)
                    acc[i][j] += av[i] * bv[j];
        }
        __syncthreads();
    }
#pragma unroll
    for (int i = 0; i < 4; ++i) {
        long m = m0 + ty * 4 + i;
#pragma unroll
        for (int j = 0; j < 4; ++j) {
            int n = n0 + tx * 4 + j;
            C[m * ldc + n] = acc[i][j];
        }
    }
}

// ---------------------------------------------------------------------------
// Fused s1 / sigmoid / top-k mask (q-form, R7-verified numerics) + hxb emit.
// ---------------------------------------------------------------------------
__global__ __launch_bounds__(256) void s1_mask_fused(
    const float* __restrict__ hx,    // (B,2048)  (for hxb emit only)
    const float* __restrict__ q,     // (B,8,64) f32
    const float* __restrict__ krow,  // (B,64) f32
    float* __restrict__ a_buf, float* __restrict__ mask_buf,
    __hip_bfloat16* __restrict__ hxb)   // (B,2048) bf16 out
{
    const int wave = threadIdx.x >> 6;
    const int lane = threadIdx.x & 63;
    const long b = (long)blockIdx.x * 4 + wave;
    const long base = b * 2048 + lane * 4;
    const float kr = krow[b * 64 + lane];
    float s1v[8];
#pragma unroll
    for (int n = 0; n < 8; ++n) {
        float4 hv = *(const float4*)(hx + base + n * 256);
        __hip_bfloat16 c0 = __float2bfloat16(hv.x);
        __hip_bfloat16 c1 = __float2bfloat16(hv.y);
        __hip_bfloat16 c2 = __float2bfloat16(hv.z);
        __hip_bfloat16 c3 = __float2bfloat16(hv.w);
        ushort4 u;
        u.x = *(unsigned short*)&c0; u.y = *(unsigned short*)&c1;
        u.z = *(unsigned short*)&c2; u.w = *(unsigned short*)&c3;
        *(ushort4*)(hxb + base + n * 256) = u;
        float p = q[b * 512 + n * 64 + lane] * kr;
#pragma unroll
        for (int off = 32; off > 0; off >>= 1) p += __shfl_xor(p, off, 64);
        s1v[n] = p * 0.125f;
    }
    unsigned maskbits = 0;
#pragma unroll
    for (int n = 0; n < 8; ++n) {
        int rank = 0;
#pragma unroll
        for (int m = 0; m < 8; ++m) {
            if (m == n) continue;
            if (s1v[m] < s1v[n] || (s1v[m] == s1v[n] && m < n)) rank++;
        }
        if (rank >= 4) maskbits |= (1u << n);
    }
    if (lane < 8) {
        float sv = s1v[0];
#pragma unroll
        for (int n = 1; n < 8; ++n)
            if (lane == n) sv = s1v[n];
        a_buf[b * 8 + lane] = sigmoidf_(sv);
        mask_buf[b * 8 + lane] = ((maskbits >> lane) & 1u) ? 1.0f : 0.0f;
    }
}

// ---------------------------------------------------------------------------
// MFMA GEMM: C(bf16, MxN) = A(bf16, MxK, lda) @ BT(bf16, NxK, ldb)^T
// z-batched with strides sA, sB, sC (element counts).
// ---------------------------------------------------------------------------
__global__ __launch_bounds__(256) void gemm_mfma_obf16(
    const __hip_bfloat16* __restrict__ A, int lda,
    const __hip_bfloat16* __restrict__ BT, int ldb,
    __hip_bfloat16* __restrict__ C, int ldc, int K,
    long sA, long sB, long sC)
{
    A  += (long)blockIdx.z * sA;
    BT += (long)blockIdx.z * sB;
    C  += (long)blockIdx.z * sC;
    const int m0 = blockIdx.y * 128;
    const int n0 = blockIdx.x * 64;
    const int tid = threadIdx.x;
    const int lane = tid & 63, wid = tid >> 6;
    const int wr = wid >> 1, wc = wid & 1;
    const int l15 = lane & 15, l4 = lane >> 4;

    __shared__ __align__(16) char lds_raw[16384 + 8192];
    char* Alds = lds_raw;
    char* Blds = lds_raw + 16384;

    f32x4 acc[4][2] = {};

    for (int k0 = 0; k0 < K; k0 += 64) {
#pragma unroll
        for (int ii = 0; ii < 4; ++ii) {
            int issue = ii * 4 + wid;
            int chunk = issue * 64 + lane;
            int r = chunk >> 3, cs = chunk & 7;
            int cl = cs ^ (r & 7);
            const __hip_bfloat16* g = A + (long)(m0 + r) * lda + k0 + cl * 8;
            GLDS16(g, Alds + issue * 1024);
        }
#pragma unroll
        for (int jj = 0; jj < 2; ++jj) {
            int issue = jj * 4 + wid;
            int chunk = issue * 64 + lane;
            int r = chunk >> 3, cs = chunk & 7;
            int cl = cs ^ (r & 7);
            const __hip_bfloat16* g = BT + (long)(n0 + r) * ldb + k0 + cl * 8;
            GLDS16(g, Blds + issue * 1024);
        }
        __syncthreads();
#pragma unroll
        for (int kk = 0; kk < 2; ++kk) {
            bf16x8 af[4], bfr[2];
#pragma unroll
            for (int im = 0; im < 4; ++im) {
                int r = wr * 64 + im * 16 + l15;
                int cl = (kk * 4 + l4) ^ (l15 & 7);
                af[im] = *(const bf16x8*)(Alds + r * 128 + cl * 16);
            }
#pragma unroll
            for (int jn = 0; jn < 2; ++jn) {
                int r = wc * 32 + jn * 16 + l15;
                int cl = (kk * 4 + l4) ^ (l15 & 7);
                bfr[jn] = *(const bf16x8*)(Blds + r * 128 + cl * 16);
            }
#pragma unroll
            for (int im = 0; im < 4; ++im)
#pragma unroll
                for (int jn = 0; jn < 2; ++jn)
                    acc[im][jn] = __builtin_amdgcn_mfma_f32_16x16x32_bf16(
                        af[im], bfr[jn], acc[im][jn], 0, 0, 0);
        }
        __syncthreads();
    }
#pragma unroll
    for (int im = 0; im < 4; ++im)
#pragma unroll
        for (int reg = 0; reg < 4; ++reg) {
            long m = m0 + wr * 64 + im * 16 + l4 * 4 + reg;
#pragma unroll
            for (int jn = 0; jn < 2; ++jn) {
                int n = n0 + wc * 32 + jn * 16 + l15;
                C[m * ldc + n] = __float2bfloat16(acc[im][jn][reg]);
            }
        }
}

// ---------------------------------------------------------------------------
// Fused q/k/v_m projections, widened: one block covers all N=192 cols.
// ---------------------------------------------------------------------------
__global__ __launch_bounds__(256) void gemm_mfma_qkv(
    const __hip_bfloat16* __restrict__ hnewb,  // (B,2048)
    const __hip_bfloat16* __restrict__ WmT,    // (8,192,256)
    __hip_bfloat16* __restrict__ qout)         // q|k|v, each 2097152 bf16
{
    const int z = blockIdx.z;
    const int m0 = blockIdx.y * 128;
    const int tid = threadIdx.x;
    const int lane = tid & 63, wid = tid >> 6;
    const int wr = wid >> 1, wc = wid & 1;
    const int l15 = lane & 15, l4 = lane >> 4;

    const __hip_bfloat16* A = hnewb + z * 256;
    const __hip_bfloat16* BT = WmT + (long)z * 192 * 256;

    __shared__ __align__(16) char lds_raw[16384 + 24576];
    char* Alds = lds_raw;
    char* Blds = lds_raw + 16384;

    f32x4 acc[4][6] = {};

    for (int k0 = 0; k0 < 256; k0 += 64) {
        for (int ii = wid; ii < 16; ii += 4) {
            int chunk = ii * 64 + lane;
            int r = chunk >> 3, cs = chunk & 7;
            int cl = cs ^ (r & 7);
            const __hip_bfloat16* g = A + (long)(m0 + r) * 2048 + k0 + cl * 8;
            GLDS16(g, Alds + ii * 1024);
        }
        for (int jj = wid; jj < 24; jj += 4) {
            int chunk = jj * 64 + lane;
            int r = chunk >> 3, cs = chunk & 7;
            int cl = cs ^ (r & 7);
            const __hip_bfloat16* g = BT + (long)r * 256 + k0 + cl * 8;
            GLDS16(g, Blds + jj * 1024);
        }
        __syncthreads();
#pragma unroll
        for (int kk = 0; kk < 2; ++kk) {
            int cl = (kk * 4 + l4) ^ (l15 & 7);
            bf16x8 af[4], bfr[6];
#pragma unroll
            for (int im = 0; im < 4; ++im) {
                int r = wr * 64 + im * 16 + l15;
                af[im] = *(const bf16x8*)(Alds + r * 128 + cl * 16);
            }
#pragma unroll
            for (int jn = 0; jn < 6; ++jn) {
                int r = wc * 96 + jn * 16 + l15;
                bfr[jn] = *(const bf16x8*)(Blds + r * 128 + cl * 16);
            }
#pragma unroll
            for (int im = 0; im < 4; ++im)
#pragma unroll
                for (int jn = 0; jn < 6; ++jn)
                    acc[im][jn] = __builtin_amdgcn_mfma_f32_16x16x32_bf16(
                        af[im], bfr[jn], acc[im][jn], 0, 0, 0);
        }
        __syncthreads();
    }
#pragma unroll
    for (int jn = 0; jn < 6; ++jn) {
        int j = wc * 96 + jn * 16 + l15;   // [0,192)
        int g = j >> 6, d = j & 63;
        __hip_bfloat16* outp = qout + (long)g * 2097152 + (long)z * 64 + d;
#pragma unroll
        for (int im = 0; im < 4; ++im)
#pragma unroll
            for (int reg = 0; reg < 4; ++reg) {
                long m = m0 + wr * 64 + im * 16 + l4 * 4 + reg;
                outp[m * 512] = __float2bfloat16(acc[im][jn][reg]);
            }
    }
}

// ---------------------------------------------------------------------------
// MFMA big GEMM + fused GRU epilogue — R15-verified (folded K=512 phase-1).
// ---------------------------------------------------------------------------
__global__ __launch_bounds__(512) void gru_fused_mfma(
    const __hip_bfloat16* __restrict__ inpb,   // (B,512)
    const __hip_bfloat16* __restrict__ hxb,    // (B,2048)
    const float* __restrict__ a_buf,           // (B,8)
    const float* __restrict__ cb,              // (8,768)
    const __hip_bfloat16* __restrict__ W2T,    // (8,768,512) folded Wih@WvF^T
    const __hip_bfloat16* __restrict__ Whhb,   // (8,768,256)
    const float* __restrict__ bhh,             // (8,768)
    __hip_bfloat16* __restrict__ hnewb)        // (B,2048)
{
    const int bid = blockIdx.x;
    const int kblk = bid & 7;
    const int r_ = bid >> 3;
    const int ol0 = (r_ & 7) * 32;
    const int m0 = (r_ >> 3) * 128;
    const int tid = threadIdx.x;
    const int lane = tid & 63, wid = tid >> 6;
    const int wr = wid >> 1;
    const int wc = wid & 1;
    const int l15 = lane & 15, l4 = lane >> 4;

    __shared__ __align__(16) char lds_raw[2 * 28672];

    f32x4 accx[2][3] = {};
    f32x4 acch[2][3] = {};

    const __hip_bfloat16* W2 = W2T + (long)kblk * 768 * 512;
    const __hip_bfloat16* Wh = Whhb + (long)kblk * 768 * 256;
    const __hip_bfloat16* hxk = hxb + kblk * 256;

    const int iiA0 = wid, iiA1 = wid + 8;
    const int cA0 = iiA0 * 64 + lane, rA0 = cA0 >> 3, clA0 = (cA0 & 7) ^ (rA0 & 7);
    const int cA1 = iiA1 * 64 + lane, rA1 = cA1 >> 3, clA1 = (cA1 & 7) ^ (rA1 & 7);
    const int jjB0 = wid, jjB1 = wid + 8;
    const int cB0 = jjB0 * 64 + lane, rB0 = cB0 >> 3, clB0 = (cB0 & 7) ^ (rB0 & 7);
    const int cB1 = jjB1 * 64 + lane, rB1 = cB1 >> 3, clB1 = (cB1 & 7) ^ (rB1 & 7);
    const bool hasB1 = (wid < 4);
    const int gg0 = rB0 >> 5, oll0 = rB0 & 31;
    const int gg1 = (rB1 >> 5) & 3, oll1 = rB1 & 31;
    const int dA0 = iiA0 * 1024, dA1 = iiA1 * 1024;
    const int dB0 = 16384 + jjB0 * 1024, dB1 = 16384 + jjB1 * 1024;

    const __hip_bfloat16* pA0 = inpb + (long)(m0 + rA0) * 512 + clA0 * 8;
    const __hip_bfloat16* pA1 = inpb + (long)(m0 + rA1) * 512 + clA1 * 8;
    const __hip_bfloat16* pB0 = W2 + (long)(gg0 * 256 + ol0 + oll0) * 512 + clB0 * 8;
    const __hip_bfloat16* pB1 = W2 + (long)(gg1 * 256 + ol0 + oll1) * 512 + clB1 * 8;

#define STAGE4(buf) do {                                                       \
    char* L = lds_raw + (buf) * 28672;                                         \
    GLDS16(pA0, L + dA0);                                                      \
    GLDS16(pA1, L + dA1);                                                      \
    GLDS16(pB0, L + dB0);                                                      \
    if (hasB1) GLDS16(pB1, L + dB1);                                           \
    pA0 += 64; pA1 += 64; pB0 += 64; pB1 += 64;                                \
} while (0)

    int offA[2][2], offB[2][3];
#pragma unroll
    for (int kk = 0; kk < 2; ++kk) {
        int cl = (kk * 4 + l4) ^ (l15 & 7);
#pragma unroll
        for (int im = 0; im < 2; ++im)
            offA[kk][im] = (wr * 32 + im * 16 + l15) * 128 + cl * 16;
#pragma unroll
        for (int g = 0; g < 3; ++g)
            offB[kk][g] = 16384 + (g * 32 + wc * 16 + l15) * 128 + cl * 16;
    }

#define COMPUTE(acc, buf) do {                                                 \
    char* L = lds_raw + (buf) * 28672;                                         \
    _Pragma("unroll") for (int kk = 0; kk < 2; ++kk) {                         \
        bf16x8 af[2], bfr[3];                                                  \
        _Pragma("unroll") for (int im = 0; im < 2; ++im)                       \
            af[im] = *(const bf16x8*)(L + offA[kk][im]);                       \
        _Pragma("unroll") for (int g = 0; g < 3; ++g)                          \
            bfr[g] = *(const bf16x8*)(L + offB[kk][g]);                        \
        _Pragma("unroll") for (int im = 0; im < 2; ++im)                       \
            _Pragma("unroll") for (int g = 0; g < 3; ++g)                      \
                acc[im][g] = __builtin_amdgcn_mfma_f32_16x16x32_bf16(          \
                    af[im], bfr[g], acc[im][g], 0, 0, 0);                      \
    }                                                                          \
} while (0)

    STAGE4(0);
    asm volatile("s_waitcnt vmcnt(0)" ::: "memory");
    __syncthreads();

    int cur = 0;
    for (int t = 0; t < 8; ++t) {
        if (t < 7) {
            STAGE4(cur ^ 1);
        } else {
            pA0 = hxk + (long)(m0 + rA0) * 2048 + clA0 * 8;
            pA1 = hxk + (long)(m0 + rA1) * 2048 + clA1 * 8;
            pB0 = Wh + (long)(gg0 * 256 + ol0 + oll0) * 256 + clB0 * 8;
            pB1 = Wh + (long)(gg1 * 256 + ol0 + oll1) * 256 + clB1 * 8;
            STAGE4(cur ^ 1);
        }
        __builtin_amdgcn_s_setprio(1);
        COMPUTE(accx, cur);
        __builtin_amdgcn_s_setprio(0);
        asm volatile("s_waitcnt vmcnt(0)" ::: "memory");
        __syncthreads();
        cur ^= 1;
    }
    for (int t = 0; t < 4; ++t) {
        if (t < 3) STAGE4(cur ^ 1);
        __builtin_amdgcn_s_setprio(1);
        COMPUTE(acch, cur);
        __builtin_amdgcn_s_setprio(0);
        asm volatile("s_waitcnt vmcnt(0)" ::: "memory");
        __syncthreads();
        cur ^= 1;
    }
#undef STAGE4
#undef COMPUTE

    const int ol = ol0 + wc * 16 + l15;
    const float* cbk = cb + kblk * 768;
    const float cb0 = cbk[ol], cb1 = cbk[256 + ol], cb2 = cbk[512 + ol];
    const float* bhk = bhh + kblk * 768;
    const float bh0 = bhk[ol], bh1 = bhk[256 + ol], bh2 = bhk[512 + ol];
#pragma unroll
    for (int im = 0; im < 2; ++im) {
#pragma unroll
        for (int reg = 0; reg < 4; ++reg) {
            long m = m0 + wr * 32 + im * 16 + l4 * 4 + reg;
            float av = a_buf[m * 8 + kblk];
            float gx0 = av * accx[im][0][reg] + cb0;
            float gx1 = av * accx[im][1][reg] + cb1;
            float gx2 = av * accx[im][2][reg] + cb2;
            float gh0 = acch[im][0][reg] + bh0;
            float gh1 = acch[im][1][reg] + bh1;
            float gh2 = acch[im][2][reg] + bh2;
            float rr = sigmoidf_(gx0 + gh0);
            float zz = sigmoidf_(gx1 + gh1);
            float nn = tanhf(gx2 + rr * gh2);
            long idx = m * 2048 + kblk * 256 + ol;
            float hxv = __bfloat162float(hxb[idx]);
            hnewb[idx] = __float2bfloat16((1.f - zz) * nn + zz * hxv);
        }
    }
}

// ---------------------------------------------------------------------------
// Memory attention (bf16 in/out)
// ---------------------------------------------------------------------------
__global__ __launch_bounds__(256) void mattn_kernel(
    const __hip_bfloat16* __restrict__ qm, const __hip_bfloat16* __restrict__ km,
    const __hip_bfloat16* __restrict__ vm, __hip_bfloat16* __restrict__ omb)
{
    const int t = threadIdx.x;
    const int local = t & 31;
    const long b = (long)blockIdx.x * 8 + (t >> 5);
    const int h = local >> 3, qn = local & 7;
    const long base = b * 512 + h * 16;

    float qv[16];
#pragma unroll
    for (int i = 0; i < 2; ++i) {
        bf16x8 v = *(const bf16x8*)(qm + base + qn * 64 + i * 8);
#pragma unroll
        for (int j = 0; j < 8; ++j) qv[i * 8 + j] = (float)v[j];
    }
    float sc[8];
#pragma unroll
    for (int kn = 0; kn < 8; ++kn) {
        float s = 0.f;
#pragma unroll
        for (int i = 0; i < 2; ++i) {
            bf16x8 v = *(const bf16x8*)(km + base + kn * 64 + i * 8);
#pragma unroll
            for (int j = 0; j < 8; ++j) s += qv[i * 8 + j] * (float)v[j];
        }
        sc[kn] = s * 0.25f;
    }
    float mx = sc[0];
#pragma unroll
    for (int kn = 1; kn < 8; ++kn) mx = fmaxf(mx, sc[kn]);
    float ssum = 0.f;
#pragma unroll
    for (int kn = 0; kn < 8; ++kn) { sc[kn] = expf(sc[kn] - mx); ssum += sc[kn]; }
    float inv = 1.f / ssum;

    float acc[16] = {};
#pragma unroll
    for (int kn = 0; kn < 8; ++kn) {
        float w = sc[kn] * inv;
#pragma unroll
        for (int i = 0; i < 2; ++i) {
            bf16x8 v = *(const bf16x8*)(vm + base + kn * 64 + i * 8);
#pragma unroll
            for (int j = 0; j < 8; ++j) acc[i * 8 + j] += w * (float)v[j];
        }
    }
#pragma unroll
    for (int i = 0; i < 2; ++i) {
        bf16x8 o;
#pragma unroll
        for (int j = 0; j < 8; ++j) o[j] = (__bf16)acc[i * 8 + j];
        *(bf16x8*)(omb + base + qn * 64 + i * 8) = o;
    }
}

// ---------------------------------------------------------------------------
// Fused att GEMM + final — LDS-staged epilogue, coalesced float4 output,
// branch (exec-masked) loads so only the selected side is fetched.
// ---------------------------------------------------------------------------
__global__ __launch_bounds__(256) void att_final(
    const __hip_bfloat16* __restrict__ omb,    // (32768,64)
    const __hip_bfloat16* __restrict__ fcgT,   // (512,64)
    const float* __restrict__ fc_b, const float* __restrict__ gate_b,
    const __hip_bfloat16* __restrict__ hnewb,  // (32768,256)
    const float* __restrict__ maskb,           // (32768)
    const float* __restrict__ hx, const float* __restrict__ cx,
    float* __restrict__ hx_out, float* __restrict__ cx_out,
    float* __restrict__ mask_w)
{
    const int m0 = blockIdx.y * 128;
    const int n0 = blockIdx.x * 64;
    const int tid = threadIdx.x;
    const int lane = tid & 63, wid = tid >> 6;
    const int wr = wid >> 1, wc = wid & 1;
    const int l15 = lane & 15, l4 = lane >> 4;

    __shared__ __align__(16) char lds_raw[16384 + 8192];
    char* Alds = lds_raw;
    char* Blds = lds_raw + 16384;
    float* att_t = (float*)lds_raw;            // 128x32 f32 tile (16KB), reused after MFMA

    f32x4 acc[4][2] = {};
#pragma unroll
    for (int ii = 0; ii < 4; ++ii) {
        int issue = ii * 4 + wid;
        int chunk = issue * 64 + lane;
        int r = chunk >> 3, cs = chunk & 7;
        int cl = cs ^ (r & 7);
        const __hip_bfloat16* g = omb + (long)(m0 + r) * 64 + cl * 8;
        GLDS16(g, Alds + issue * 1024);
    }
#pragma unroll
    for (int jj = 0; jj < 2; ++jj) {
        int issue = jj * 4 + wid;
        int chunk = issue * 64 + lane;
        int r = chunk >> 3, cs = chunk & 7;
        int cl = cs ^ (r & 7);
        const __hip_bfloat16* g = fcgT + (long)(n0 + r) * 64 + cl * 8;
        GLDS16(g, Blds + issue * 1024);
    }
    __syncthreads();
#pragma unroll
    for (int kk = 0; kk < 2; ++kk) {
        bf16x8 af[4], bfr[2];
#pragma unroll
        for (int im = 0; im < 4; ++im) {
            int r = wr * 64 + im * 16 + l15;
            int cl = (kk * 4 + l4) ^ (l15 & 7);
            af[im] = *(const bf16x8*)(Alds + r * 128 + cl * 16);
        }
#pragma unroll
        for (int jn = 0; jn < 2; ++jn) {
            int r = wc * 32 + jn * 16 + l15;
            int cl = (kk * 4 + l4) ^ (l15 & 7);
            bfr[jn] = *(const bf16x8*)(Blds + r * 128 + cl * 16);
        }
#pragma unroll
        for (int im = 0; im < 4; ++im)
#pragma unroll
            for (int jn = 0; jn < 2; ++jn)
                acc[im][jn] = __builtin_amdgcn_mfma_f32_16x16x32_bf16(
                    af[im], bfr[jn], acc[im][jn], 0, 0, 0);
    }
    // Stage att values into LDS [128][32] (f32), after all LDS reads are done.
    __syncthreads();
    {
        const int o_l = wc * 16 + l15;     // local o in [0,32)
        const float fb = fc_b[(n0 >> 1) + o_l], gb = gate_b[(n0 >> 1) + o_l];
#pragma unroll
        for (int im = 0; im < 4; ++im)
#pragma unroll
            for (int reg = 0; reg < 4; ++reg) {
                int ml = wr * 64 + im * 16 + l4 * 4 + reg;
                float att = sigmoidf_(acc[im][1][reg] + gb) * tanhf(acc[im][0][reg] + fb);
                att_t[ml * 32 + o_l] = att;
            }
    }
    __syncthreads();
    // Coalesced output pass: thread -> (row, col4); float4 everywhere; the
    // branch keeps fetch to ONE side per row (exec-masked loads).
    const int o0 = n0 >> 1;
#pragma unroll
    for (int it = 0; it < 4; ++it) {
        int idx = it * 256 + tid;          // [0,1024)
        int rl = idx >> 3, c4 = idx & 7;   // row local, float4-col
        long m = m0 + rl;
        float mv = maskb[m];
        long gidx = m * 256 + o0 + c4 * 4;
        float4 ho, co;
        if (mv != 0.f) {
            float4 av = *(const float4*)&att_t[rl * 32 + c4 * 4];
            ushort4 hn = *(const ushort4*)(hnewb + gidx);
            ho.x = b2f_(hn.x) + av.x; ho.y = b2f_(hn.y) + av.y;
            ho.z = b2f_(hn.z) + av.z; ho.w = b2f_(hn.w) + av.w;
            co = ho;
        } else {
            ho = *(const float4*)(hx + gidx);
            co = *(const float4*)(cx + gidx);
        }
        *(float4*)(hx_out + gidx) = ho;
        *(float4*)(cx_out + gidx) = co;
        *(float4*)(mask_w + gidx) = make_float4(mv, mv, mv, mv);
    }
}

// ---------------------------------------------------------------------------
extern "C" void kernel_launch(void* const* d_in, const int* in_sizes, int n_in,
                              void* d_out, int out_size, void* d_ws, size_t ws_size,
                              hipStream_t stream)
{
    const float* inp     = (const float*)d_in[0];
    const float* hx      = (const float*)d_in[1];
    const float* cx      = (const float*)d_in[2];
    const float* Wq_i    = (const float*)d_in[4];
    const float* Wk_i    = (const float*)d_in[5];
    const float* Wv_i    = (const float*)d_in[6];
    const float* fc_i_w  = (const float*)d_in[7];
    const float* fc_i_b  = (const float*)d_in[8];
    const float* Wq_m    = (const float*)d_in[9];
    const float* Wk_m    = (const float*)d_in[10];
    const float* Wv_m    = (const float*)d_in[11];
    const float* fc_m_w  = (const float*)d_in[12];
    const float* fc_m_b  = (const float*)d_in[13];
    const float* gate_m_w= (const float*)d_in[14];
    const float* gate_m_b= (const float*)d_in[15];
    const float* Wih     = (const float*)d_in[16];
    const float* Whh     = (const float*)d_in[17];
    const float* bih     = (const float*)d_in[18];
    const float* bhh     = (const float*)d_in[19];

    float* out = (float*)d_out;
    const long BH = (long)B_SZ * NHID_;   // 8388608
    float* hx_out = out;
    float* cx_out = out + BH;
    float* mask_w = out + 2 * BH;
    __hip_bfloat16* hxb = (__hip_bfloat16*)out;   // bf16 hx in hx_out region (dead after gru)
    __hip_bfloat16* qkvb = (__hip_bfloat16*)out;  // q|k|v bf16, written post-gru
    float* qbuf = cx_out;                         // (B,8,64) f32 q, dead before att_final

    // Workspace layout (float offsets; lifetimes verified):
    float* w = (float*)d_ws;
    float* a_buf = w;                                        // [0, 32768)
    float* maskb = w + 32768;                                // [32768, 65536)
    float* cbuf  = w + 65536;                                // [65536, 71680)
    __hip_bfloat16* fcgT = (__hip_bfloat16*)(w + 73728);     // [73728, 90112)
    __hip_bfloat16* WmT  = (__hip_bfloat16*)(w + 90112);     // [90112, 286720)
    // pre-GRU dead pool [286720, 4481024) — reused by hnewb:
    __hip_bfloat16* Wihb = (__hip_bfloat16*)(w + 286720);    // [286720, 3432448); dead after W2 gemm
    __hip_bfloat16* fcT  = (__hip_bfloat16*)(w + 3432448);   // [3432448, 3956736); dead after WvFTt
    __hip_bfloat16* WvB  = (__hip_bfloat16*)(w + 3956736);   // [3956736, 4218880); dead after WvFTt
    float* krow = w + 4218880;                               // [4218880, 4481024); dead after s1_mask
    __hip_bfloat16* hnewb= (__hip_bfloat16*)(w + 286720);    // [286720, 4481024)  (post-pool overlay)
    // GRU-live buffers (outside the pool):
    __hip_bfloat16* WvFTt= (__hip_bfloat16*)(w + 4481024);   // [4481024, 4743168); dead after W2 gemm
    __hip_bfloat16* inpb = (__hip_bfloat16*)(w + 4743168);   // [4743168, 5791744)
    __hip_bfloat16* W2T  = (__hip_bfloat16*)(w + 5791744);   // [5791744, 7364608)
    __hip_bfloat16* Whhb = (__hip_bfloat16*)(w + 7364608);   // [7364608, 8151040)
    // post-GRU overlay (W2T dead):
    __hip_bfloat16* omb  = (__hip_bfloat16*)(w + 5791744);   // [5791744, 6840320)

    // ---- Phase A: merged prep ----
    prep_all<<<dim3(11776), dim3(256), 0, stream>>>(
        Wih, fc_i_b, bih, Wihb, cbuf,
        inp, inpb, Whh, Whhb, Wv_i + 512 * 1024, WvB,
        fc_i_w, fcT, Wq_m, Wk_m, Wv_m, WmT, fc_m_w, gate_m_w, fcgT);
    // ---- Phase B: mask path (fp32, q-form) + hxb emit ----
    gemm_nn<<<dim3(1, 64, 1), dim3(256), 0, stream>>>(
        inp, Wk_i + 512 * 64, krow, 4096, 64, 512, 512, 64, 64, 0, 0, 0);
    gemm_nn<<<dim3(1, 64, 8), dim3(256), 0, stream>>>(
        hx, Wq_i, qbuf, 4096, 64, 256, 2048, 64, 512, 256, 16384, 64);
    s1_mask_fused<<<dim3(1024), dim3(256), 0, stream>>>(
        hx, qbuf, krow, a_buf, maskb, hxb);
    // WvFTt(512x1024) = WvB(512x1024) @ fcT(1024x1024)^T
    gemm_mfma_obf16<<<dim3(16, 4, 1), dim3(256), 0, stream>>>(
        WvB, 1024, fcT, 1024, WvFTt, 1024, 1024, 0, 0, 0);
    // W2T[k](768x512) = Wihb[k](768x1024) @ WvFTt(512x1024)^T
    gemm_mfma_obf16<<<dim3(8, 6, 8), dim3(256), 0, stream>>>(
        Wihb, 1024, WvFTt, 1024, W2T, 512, 1024,
        768L * 1024, 0, 768L * 512);
    // ---- Phase C: fused MFMA GEMM + GRU (K=512 folded phase-1) ----
    gru_fused_mfma<<<dim3(2048), dim3(512), 0, stream>>>(
        inpb, hxb, a_buf, cbuf, W2T, Whhb, bhh, hnewb);
    // ---- Phase D: q/k/v_m projections (widened, N=192/block) ----
    gemm_mfma_qkv<<<dim3(1, 32, 8), dim3(256), 0, stream>>>(hnewb, WmT, qkvb);
    // ---- Phase E: memory attention + fused att/final (coalesced epilogue) ----
    mattn_kernel<<<dim3(512), dim3(256), 0, stream>>>(
        qkvb, qkvb + 2097152, qkvb + 4194304, omb);
    att_final<<<dim3(8, 256, 1), dim3(256), 0, stream>>>(
        omb, fcgT, fc_m_b, gate_m_b, hnewb, maskb, hx, cx, hx_out, cx_out, mask_w);
}